// Round 3
// baseline (45176.373 us; speedup 1.0000x reference)
//
#include <hip/hip_runtime.h>
#include <cmath>

#define DM 512
#define DH 64

// ---------------- Threefry-2x32-20 (matches jax.random) ----------------
__host__ __device__ inline void tf2x32(unsigned k0, unsigned k1, unsigned& x0, unsigned& x1){
  const unsigned ks0=k0, ks1=k1, ks2=k0^k1^0x1BD11BDAu;
  x0 += ks0; x1 += ks1;
#define TF_ROT(r) { x0 += x1; x1 = (x1<<(r))|(x1>>(32-(r))); x1 ^= x0; }
  TF_ROT(13) TF_ROT(15) TF_ROT(26) TF_ROT(6)
  x0 += ks1; x1 += ks2 + 1u;
  TF_ROT(17) TF_ROT(29) TF_ROT(16) TF_ROT(24)
  x0 += ks2; x1 += ks0 + 2u;
  TF_ROT(13) TF_ROT(15) TF_ROT(26) TF_ROT(6)
  x0 += ks0; x1 += ks1 + 3u;
  TF_ROT(17) TF_ROT(29) TF_ROT(16) TF_ROT(24)
  x0 += ks1; x1 += ks2 + 4u;
  TF_ROT(13) TF_ROT(15) TF_ROT(26) TF_ROT(6)
  x0 += ks2; x1 += ks0 + 5u;
#undef TF_ROT
}

// idx = random_bits(lower_key) & (L-1); counts = iota(L*u) split in halves
__global__ __launch_bounds__(256) void idx_kernel(int* __restrict__ idx, unsigned k2a, unsigned k2b,
                                                  int S2, int Lmask){
  int j = blockIdx.x*256 + threadIdx.x;
  if (j >= S2) return;
  unsigned x0 = (unsigned)j, x1 = (unsigned)(S2 + j);
  tf2x32(k2a, k2b, x0, x1);
  idx[j]      = (int)(x0 & (unsigned)Lmask);
  idx[S2 + j] = (int)(x1 & (unsigned)Lmask);
}

// ---------------- token embed: circular conv (7ch->512) + sinusoid PE ----------------
__global__ __launch_bounds__(256) void embed_kernel(const float* __restrict__ x, const float* __restrict__ tcw,
                                                    float* __restrict__ h, int L){
  size_t i = (size_t)blockIdx.x*256 + threadIdx.x;
  int d = (int)(i % DM);
  size_t r = i / DM;
  int l = (int)(r % L);
  int b = (int)(r / L);
  const float* xb = x + (size_t)b*L*7;
  float acc = 0.f;
#pragma unroll
  for (int kk=0; kk<3; kk++){
    int ls = l + kk - 1;
    ls = (ls < 0) ? ls + L : (ls >= L ? ls - L : ls);
    const float* xe = xb + (size_t)ls*7;
    const float* wp = tcw + (size_t)d*21 + kk;   // tcw[d][c][k]
#pragma unroll
    for (int c=0;c<7;c++) acc += xe[c]*wp[3*c];
  }
  const float scale = -0.017988946f;  // -ln(10000)/512
  float arg  = (float)(d & ~1) * scale;
  float freq = expf(arg);
  float ang  = (float)l * freq;
  float pe   = (d & 1) ? cosf(ang) : sinf(ang);
  h[i] = acc + pe;
}

// ---------------- generic fp32 GEMM: C = act(A@W^T + bias) [+ C] ----------------
#define BM 128
#define BN 128
#define BK 16
__global__ __launch_bounds__(256) void gemm_kernel(const float* __restrict__ A, const float* __restrict__ W,
    const float* __restrict__ bias, float* __restrict__ C,
    int M, int N, int K, int wn, int wk, int L, int shift, int beta, int act){
  __shared__ float As[BK][BM+4];
  __shared__ float Bs[BK][BN+4];
  int tid = threadIdx.x;
  int row0 = blockIdx.y*BM, col0 = blockIdx.x*BN;
  int tr = tid >> 4, tc = tid & 15;
  float acc[8][8] = {};
  int lr = tid >> 1;
  int lk = (tid & 1) * 8;
  int gr = row0 + lr;
  const float* arow;
  if (shift == 0) arow = A + (size_t)gr * K;
  else {
    int b = gr / L, l = gr % L;
    int ls = l + shift; if (ls < 0) ls += L; if (ls >= L) ls -= L;
    arow = A + ((size_t)b * L + ls) * K;
  }
  const float* wrow = W + (size_t)(col0 + lr) * wn;
  for (int k0 = 0; k0 < K; k0 += BK){
#pragma unroll
    for (int i=0;i<8;i++) As[lk+i][lr] = arow[k0+lk+i];
#pragma unroll
    for (int i=0;i<8;i++) Bs[lk+i][lr] = wrow[(size_t)(k0+lk+i)*wk];
    __syncthreads();
#pragma unroll
    for (int k=0;k<BK;k++){
      float a[8], b[8];
#pragma unroll
      for (int i=0;i<8;i++) a[i] = As[k][tr*8+i];
#pragma unroll
      for (int j=0;j<8;j++) b[j] = Bs[k][tc*8+j];
#pragma unroll
      for (int i=0;i<8;i++)
#pragma unroll
        for (int j=0;j<8;j++) acc[i][j] += a[i]*b[j];
    }
    __syncthreads();
  }
#pragma unroll
  for (int i=0;i<8;i++){
    int rr = row0 + tr*8 + i;
    size_t off = (size_t)rr * N + col0 + tc*8;
#pragma unroll
    for (int j=0;j<8;j++){
      float v = acc[i][j];
      if (bias) v += bias[col0 + tc*8 + j];
      if (act == 1) v = 0.5f * v * (1.0f + erff(v * 0.70710678f));   // exact GELU
      if (beta) v += C[off + j];
      C[off + j] = v;
    }
  }
}

// ---------------- m = max_s(q.k_idx) - mean_s(q.k_idx), one wave per (b_local,h,l) ----------------
__global__ __launch_bounds__(256) void sample_m(const float* __restrict__ q, const float* __restrict__ k,
    const int* __restrict__ idx, float* __restrict__ m, int L, int u){
  int w = (int)(((size_t)blockIdx.x*256 + threadIdx.x) >> 6);
  int lane = threadIdx.x & 63;
  int l = w % L; int hh = (w / L) & 7; int b = w / (L * 8);
  float qv = q[((size_t)b*L + l)*DM + hh*DH + lane];
  const float* kb = k + (size_t)b*L*DM + hh*DH + lane;
  float mx = -1e30f, sum = 0.f;
  for (int s=0; s<u; s++){
    int kp = idx[l*u + s];
    float p = qv * kb[(size_t)kp*DM];
#pragma unroll
    for (int off=32; off; off>>=1) p += __shfl_xor(p, off);
    mx = fmaxf(mx, p); sum += p;
  }
  if (lane == 0) m[((size_t)b*8 + hh)*L + l] = mx - sum/(float)u;
}

// ---------------- iterative top-u argmax per (b,h), min-index tie-break ----------------
__global__ __launch_bounds__(256) void topk_kernel(const float* __restrict__ m, int* __restrict__ top, int L, int u){
  int bh = blockIdx.x;
  const float* mm = m + (size_t)bh*L;
  __shared__ float vals[2048];
  __shared__ float rv[256];
  __shared__ int   ri[256];
  for (int i=threadIdx.x; i<L; i+=256) vals[i] = mm[i];
  __syncthreads();
  for (int it=0; it<u; it++){
    float bv = -1e30f; int bi = 0x7fffffff;
    for (int i=threadIdx.x; i<L; i+=256){
      float v = vals[i];
      if (v > bv || (v == bv && i < bi)) { bv = v; bi = i; }
    }
    rv[threadIdx.x] = bv; ri[threadIdx.x] = bi;
    __syncthreads();
    for (int s=128; s; s>>=1){
      if (threadIdx.x < s){
        float v = rv[threadIdx.x+s]; int i2 = ri[threadIdx.x+s];
        if (v > rv[threadIdx.x] || (v == rv[threadIdx.x] && i2 < ri[threadIdx.x])){
          rv[threadIdx.x] = v; ri[threadIdx.x] = i2;
        }
      }
      __syncthreads();
    }
    if (threadIdx.x == 0){ top[bh*u + it] = ri[0]; vals[ri[0]] = -1e31f; }
    __syncthreads();
  }
}

// ---------------- column mean over L rows per batch ----------------
__global__ __launch_bounds__(256) void colmean_kernel(const float* __restrict__ src, float* __restrict__ dst, int L){
  int i = blockIdx.x*256 + threadIdx.x;   // B*DM
  int d = i % DM, b = i / DM;
  const float* p = src + (size_t)b*L*DM + d;
  float s = 0.f;
  for (int l=0; l<L; l++) s += p[(size_t)l*DM];
  dst[i] = s / (float)L;
}

// ---------------- tiny GEMM: C[row] = A[row]@W^T + bias, one block per row ----------------
__global__ __launch_bounds__(256) void tiny_gemm(const float* __restrict__ A, const float* __restrict__ W,
    const float* __restrict__ bias, float* __restrict__ C, int N, int K){
  int row = blockIdx.x;
  const float* ar = A + (size_t)row*K;
  __shared__ float as[DM];
  for (int k=threadIdx.x; k<K; k+=256) as[k] = ar[k];
  __syncthreads();
  for (int n = threadIdx.x; n < N; n += 256){
    float acc = bias ? bias[n] : 0.f;
    const float* wr = W + (size_t)n*K;
    for (int k=0; k<K; k++) acc += as[k]*wr[k];
    C[(size_t)row*N + n] = acc;
  }
}

// ---------------- gather q rows for top queries (group-local) ----------------
__global__ __launch_bounds__(256) void qred_kernel(const float* __restrict__ q, const int* __restrict__ top,
    float* __restrict__ qred, int L, int u, int n){
  int i = blockIdx.x*256 + threadIdx.x;
  if (i >= n) return;
  int d = i & 63; int rest = i >> 6; int j = rest % u; int bh = rest / u;
  int hh = bh & 7; int b = bh >> 3;
  int pos = top[bh*u + j];
  qred[i] = q[((size_t)b*L + pos)*DM + hh*DH + d];
}

// ---------------- full attention for the u selected queries -> ctxt ----------------
__global__ __launch_bounds__(256) void attn_topq(const float* __restrict__ qred, const float* __restrict__ k,
    const float* __restrict__ v, float* __restrict__ ctxt, int L, int u){
  int bid = blockIdx.x;
  int j = bid % u; int bh = bid / u; int hh = bh & 7; int b = bh >> 3;
  extern __shared__ float sc[];       // L scores
  __shared__ float red[16];
  __shared__ float comb[4][DH];
  int t = threadIdx.x, lane = t & 63, w = t >> 6;
  float qv = qred[(size_t)(bh*u + j)*DH + lane];
  const float* kb = k + (size_t)b*L*DM + hh*DH;
  float lmax = -1e30f;
  for (int key=w; key<L; key+=4){
    float p = qv * kb[(size_t)key*DM + lane];
#pragma unroll
    for (int off=32; off; off>>=1) p += __shfl_xor(p, off);
    p *= 0.125f;                      // 1/sqrt(64)
    if (lane == 0) sc[key] = p;
    lmax = fmaxf(lmax, p);
  }
  if (lane == 0) red[w] = lmax;
  __syncthreads();
  float gmax = fmaxf(fmaxf(red[0],red[1]), fmaxf(red[2],red[3]));
  float lsum = 0.f;
  for (int i2=t; i2<L; i2+=256){ float e = expf(sc[i2]-gmax); sc[i2] = e; lsum += e; }
#pragma unroll
  for (int off=32; off; off>>=1) lsum += __shfl_xor(lsum, off);
  if (lane == 0) red[8+w] = lsum;
  __syncthreads();
  float gsum = red[8]+red[9]+red[10]+red[11];
  const float* vb = v + (size_t)b*L*DM + hh*DH;
  float acc = 0.f;
  for (int key=w; key<L; key+=4) acc += sc[key] * vb[(size_t)key*DM + lane];
  comb[w][lane] = acc;
  __syncthreads();
  if (w == 0){
    ctxt[(size_t)(bh*u + j)*DH + lane] = (comb[0][lane]+comb[1][lane]+comb[2][lane]+comb[3][lane]) / gsum;
  }
}

// ---------------- h[b,l,:] += cw[b,:] ----------------
__global__ __launch_bounds__(256) void addcw_kernel(float* __restrict__ h, const float* __restrict__ cw, int L){
  size_t i = (size_t)blockIdx.x*256 + threadIdx.x;
  int d = (int)(i % DM);
  int b = (int)(i / ((size_t)DM*L));
  h[i] += cw[b*DM + d];
}

// ---------------- sparse correction: h[b,pos] += (ctxt - vmean_slice)@wo_slice^T ----------------
__global__ __launch_bounds__(256) void scatter_delta(const float* __restrict__ ctxt, const float* __restrict__ vmean,
    const float* __restrict__ wo, const int* __restrict__ top, float* __restrict__ h, int L, int u){
  int bid = blockIdx.x;
  int j = bid % u; int bh = bid / u; int hh = bh & 7; int b = bh >> 3;
  int pos = top[bh*u + j];
  __shared__ float delta[DH];
  int t = threadIdx.x;
  if (t < DH) delta[t] = ctxt[(size_t)(bh*u + j)*DH + t] - vmean[b*DM + hh*DH + t];
  __syncthreads();
  float* hrow = h + ((size_t)b*L + pos)*DM;
  const float* wbase = wo + hh*DH;
  for (int n = t; n < DM; n += 256){
    float acc = 0.f;
    const float* wr = wbase + (size_t)n*DM;
#pragma unroll
    for (int dd=0; dd<DH; dd++) acc += delta[dd] * wr[dd];
    atomicAdd(&hrow[n], acc);
  }
}

// ---------------- LayerNorm over D=512; optional fused residual-add; in-place safe ----------------
__global__ __launch_bounds__(256) void ln_kernel(const float* __restrict__ X, const float* __restrict__ Yadd,
    const float* __restrict__ g, const float* __restrict__ bta, float* __restrict__ Out){
  size_t row = blockIdx.x;
  const float* xr = X + row*DM;
  int t = threadIdx.x;
  float v0 = xr[t], v1 = xr[t+256];
  if (Yadd){ const float* yr = Yadd + row*DM; v0 += yr[t]; v1 += yr[t+256]; }
  float s = v0+v1, q = v0*v0+v1*v1;
#pragma unroll
  for (int off=32; off; off>>=1){ s += __shfl_xor(s,off); q += __shfl_xor(q,off); }
  __shared__ float ss[4], qq[4];
  int w = t >> 6;
  if ((t & 63) == 0){ ss[w] = s; qq[w] = q; }
  __syncthreads();
  s = ss[0]+ss[1]+ss[2]+ss[3]; q = qq[0]+qq[1]+qq[2]+qq[3];
  float mu  = s * (1.0f/DM);
  float var = q * (1.0f/DM) - mu*mu;
  float r = rsqrtf(var + 1e-5f);
  Out[row*DM + t]     = (v0 - mu)*r*g[t]     + bta[t];
  Out[row*DM + t+256] = (v1 - mu)*r*g[t+256] + bta[t+256];
}

// ---------------- BN partial sums over a group's rows (grid: 8 x 32) ----------------
__global__ __launch_bounds__(256) void bnstat1(const float* __restrict__ C, float* __restrict__ partS,
                                               float* __restrict__ partQ, int rpb){
  int chb = blockIdx.x;   // 8
  int mb  = blockIdx.y;   // 32
  int g = threadIdx.x >> 6, c = threadIdx.x & 63;
  int ch = chb*64 + c;
  float s = 0.f, q = 0.f;
  int r0 = mb * rpb;
  for (int r = r0 + g; r < r0 + rpb; r += 4){
    float v = C[(size_t)r*DM + ch]; s += v; q += v*v;
  }
  __shared__ float ls[4][64], lq[4][64];
  ls[g][c] = s; lq[g][c] = q;
  __syncthreads();
  if (g == 0){
    s = ls[0][c]+ls[1][c]+ls[2][c]+ls[3][c];
    q = lq[0][c]+lq[1][c]+lq[2][c]+lq[3][c];
    partS[(size_t)mb*DM + ch] = s;
    partQ[(size_t)mb*DM + ch] = q;
  }
}
__global__ __launch_bounds__(256) void bnstat2(const float* __restrict__ partS, const float* __restrict__ partQ,
                                               float* __restrict__ stats, int NB, int M){
  int ch = blockIdx.x*256 + threadIdx.x;
  if (ch >= DM) return;
  float s = 0.f, q = 0.f;
  for (int mb=0; mb<NB; mb++){
    s += partS[(size_t)mb*DM + ch];
    q += partQ[(size_t)mb*DM + ch];
  }
  float mu = s / (float)M;
  stats[ch] = mu;
  stats[DM + ch] = q / (float)M - mu*mu;
}

// ---------------- BN-normalize + ELU + maxpool(3, stride2); group-local C, global Out ----------------
__global__ __launch_bounds__(256) void bnpool(const float* __restrict__ C, const float* __restrict__ stats,
    const float* __restrict__ g, const float* __restrict__ bta, float* __restrict__ Out,
    int L, int Lo, int gbase){
  size_t i = (size_t)blockIdx.x*256 + threadIdx.x;
  int ch = (int)(i % DM);
  size_t r = i / DM;
  int lo = (int)(r % Lo);
  int bl = (int)(r / Lo);           // local batch in group
  float mu = stats[ch];
  float rstd = rsqrtf(stats[DM+ch] + 1e-5f);
  float gg = g[ch], bb = bta[ch];
  float best = -1e30f;
#pragma unroll
  for (int t=-1; t<=1; t++){
    int li = 2*lo + t;
    if (li >= 0 && li < L){
      float v = (C[((size_t)bl*L + li)*DM + ch] - mu)*rstd*gg + bb;
      v = v > 0.f ? v : expm1f(v);       // ELU
      best = fmaxf(best, v);
    }
  }
  Out[((size_t)(gbase + bl)*Lo + lo)*DM + ch] = best;
}

// ---------------- final: LN(last row) @ proj^T + proj_b + skip ----------------
__global__ __launch_bounds__(128) void final_kernel(const float* __restrict__ h, const float* __restrict__ x,
    const float* __restrict__ fg, const float* __restrict__ fb, const float* __restrict__ pw,
    const float* __restrict__ pb, const float* __restrict__ sw, const float* __restrict__ sb,
    float* __restrict__ out, int Lf, int L0){
  int b = blockIdx.x;
  const float* row = h + ((size_t)b*Lf + (Lf-1))*DM;
  __shared__ float xn[DM];
  __shared__ float rs[2], rq[2];
  int t = threadIdx.x;
  float v[4]; float s = 0.f, q = 0.f;
#pragma unroll
  for (int i=0;i<4;i++){ v[i] = row[t + i*128]; s += v[i]; q += v[i]*v[i]; }
#pragma unroll
  for (int off=32; off; off>>=1){ s += __shfl_xor(s,off); q += __shfl_xor(q,off); }
  if ((t & 63) == 0){ rs[t>>6] = s; rq[t>>6] = q; }
  __syncthreads();
  s = rs[0]+rs[1]; q = rq[0]+rq[1];
  float mu = s*(1.0f/DM), var = q*(1.0f/DM) - mu*mu;
  float r = rsqrtf(var + 1e-5f);
#pragma unroll
  for (int i=0;i<4;i++){ int d = t + i*128; xn[d] = (v[i]-mu)*r*fg[d] + fb[d]; }
  __syncthreads();
  if (t < 96){
    float acc = pb[t] + sb[t];
    const float* xr = x + ((size_t)b*L0 + (L0-1))*7;
#pragma unroll
    for (int c=0;c<7;c++) acc += xr[c]*sw[t*7+c];
    for (int d=0; d<DM; d++) acc += xn[d]*pw[(size_t)t*DM + d];
    out[b*96 + t] = acc;
  }
}

// =======================================================================
extern "C" void kernel_launch(void* const* d_in, const int* in_sizes, int n_in,
                              void* d_out, int out_size, void* d_ws, size_t ws_size,
                              hipStream_t stream){
  const float* x    = (const float*)d_in[0];
  const float* skw  = (const float*)d_in[1];
  const float* skb  = (const float*)d_in[2];
  const float* tcw  = (const float*)d_in[3];
  const float* wq   = (const float*)d_in[4];
  const float* bq   = (const float*)d_in[5];
  const float* wk   = (const float*)d_in[6];
  const float* bk   = (const float*)d_in[7];
  const float* wv   = (const float*)d_in[8];
  const float* bv   = (const float*)d_in[9];
  const float* wo   = (const float*)d_in[10];
  const float* bo   = (const float*)d_in[11];
  const float* w1   = (const float*)d_in[12];
  const float* b1   = (const float*)d_in[13];
  const float* w2   = (const float*)d_in[14];
  const float* b2   = (const float*)d_in[15];
  const float* ln1g = (const float*)d_in[16];
  const float* ln1b = (const float*)d_in[17];
  const float* ln2g = (const float*)d_in[18];
  const float* ln2b = (const float*)d_in[19];
  const float* dcw  = (const float*)d_in[20];
  const float* dcb  = (const float*)d_in[21];
  const float* bng  = (const float*)d_in[22];
  const float* bnb  = (const float*)d_in[23];
  const float* flg  = (const float*)d_in[24];
  const float* flb  = (const float*)d_in[25];
  const float* pw   = (const float*)d_in[26];
  const float* pb   = (const float*)d_in[27];

  const int B = 32, L0 = 2048, DFF = 2048;
  const int RG = 8192;                 // rows per attention/conv group
  const int RF = 4096;                 // rows per FFN chunk
  char* ws = (char*)d_ws;
  const size_t SZH  = (size_t)B*L0*DM*sizeof(float);   // 134.2 MB
  const size_t SLOT = (size_t)RG*DM*sizeof(float);     // 16.78 MB

  // ---- workspace budget check: clean no-op fail (absmax) instead of fault if too small ----
  size_t small_bytes = (size_t)L0*40*4      // idx_buf
                     + (size_t)RG*8*4       // m_buf
                     + (size_t)B*8*40*4     // top_all
                     + (size_t)16*8*40*64*4 // qred_loc
                     + (size_t)B*8*40*64*4  // ctxt_all
                     + 3*(size_t)B*DM*4     // hm, vmean, cw
                     + 2*(size_t)8*32*DM*4  // partS, partQ
                     + (size_t)2*DM*4;      // stats
  if (ws_size < SZH + 3*SLOT + small_bytes) return;

  float* h     = (float*)(ws);
  float* slot0 = (float*)(ws + SZH);
  float* slot1 = (float*)(ws + SZH + SLOT);
  float* slot2 = (float*)(ws + SZH + 2*SLOT);
  char*  sm    = ws + SZH + 3*SLOT;
  int*   idx_buf  = (int*)sm;                                       // L0*40
  float* m_buf    = (float*)((char*)idx_buf + (size_t)L0*40*4);     // RG*8
  int*   top_all  = (int*)((char*)m_buf + (size_t)RG*8*4);          // B*8*40
  float* qred_loc = (float*)((char*)top_all + (size_t)B*8*40*4);    // 16*8*40*64
  float* ctxt_all = qred_loc + (size_t)16*8*40*64;                  // B*8*40*64
  float* hm       = ctxt_all + (size_t)B*8*40*64;                   // B*DM
  float* vmean    = hm + (size_t)B*DM;
  float* cw       = vmean + (size_t)B*DM;
  float* partS    = cw + (size_t)B*DM;                              // 8*32*DM
  float* partQ    = partS + (size_t)8*32*DM;
  float* stats    = partQ + (size_t)8*32*DM;                        // 2*DM

  auto gemm = [&](const float* A, const float* W, const float* bias, float* C,
                  int M, int N, int K, int wn, int wk_, int L, int shift, int beta, int act){
    dim3 g(N/BN, M/BM);
    gemm_kernel<<<g, 256, 0, stream>>>(A, W, bias, C, M, N, K, wn, wk_, L, shift, beta, act);
  };

  // 1. token conv + positional embedding
  embed_kernel<<<(int)(((size_t)B*L0*DM)/256), 256, 0, stream>>>(x, tcw, h, L0);

  int L = L0;
  for (int layer = 0; layer < 3; layer++){
    int M = B * L;
    int u = (int)(5.0 * log((double)L + 1.0));   // 38 / 34 / 31
    int G = RG / L;                              // batches per group: 4 / 8 / 16
    int nG = M / RG;                             // groups: 8 / 4 / 2
    const float* wq_i = wq + (size_t)layer*DM*DM;  const float* bq_i = bq + (size_t)layer*DM;
    const float* wk_i = wk + (size_t)layer*DM*DM;  const float* bk_i = bk + (size_t)layer*DM;
    const float* wv_i = wv + (size_t)layer*DM*DM;  const float* bv_i = bv + (size_t)layer*DM;
    const float* wo_i = wo + (size_t)layer*DM*DM;  const float* bo_i = bo + (size_t)layer*DM;
    const float* w1_i = w1 + (size_t)layer*DFF*DM; const float* b1_i = b1 + (size_t)layer*DFF;
    const float* w2_i = w2 + (size_t)layer*DM*DFF; const float* b2_i = b2 + (size_t)layer*DM;

    // jax PRNG chain: key(42) -> fold_in(layer) -> split -> lower_key bits & (L-1)
    unsigned ka = 0u, kb2 = (unsigned)layer;
    tf2x32(0u, 42u, ka, kb2);
    unsigned a0 = 0u, a1 = 2u;  tf2x32(ka, kb2, a0, a1);
    unsigned c0 = 1u, c1 = 3u;  tf2x32(ka, kb2, c0, c1);
    int S2 = L * u / 2;
    idx_kernel<<<(S2 + 255)/256, 256, 0, stream>>>(idx_buf, a1, c1, S2, L-1);

    // ---- attention, processed in groups of G batches (q/k/v in the 3 slots) ----
    for (int g = 0; g < nG; g++){
      const float* hg = h + (size_t)g*RG*DM;
      gemm(hg, wq_i, bq_i, slot0, RG, DM, DM, DM, 1, L, 0, 0, 0);
      gemm(hg, wk_i, bk_i, slot1, RG, DM, DM, DM, 1, L, 0, 0, 0);
      gemm(hg, wv_i, bv_i, slot2, RG, DM, DM, DM, 1, L, 0, 0, 0);
      sample_m<<<(int)(((size_t)RG*8*64)/256), 256, 0, stream>>>(slot0, slot1, idx_buf, m_buf, L, u);
      int* top_g = top_all + (size_t)g*G*8*u;
      topk_kernel<<<G*8, 256, 0, stream>>>(m_buf, top_g, L, u);
      int nqr = G*8*u*DH;
      qred_kernel<<<(nqr + 255)/256, 256, 0, stream>>>(slot0, top_g, qred_loc, L, u, nqr);
      attn_topq<<<G*8*u, 256, (size_t)L*sizeof(float), stream>>>(qred_loc, slot1, slot2,
          ctxt_all + (size_t)g*G*8*u*DH, L, u);
    }

    // vmean = (mean_L h) @ wv^T + bv ; cw = vmean @ wo^T + bo  (exact linear identity)
    colmean_kernel<<<B*DM/256, 256, 0, stream>>>(h, hm, L);
    tiny_gemm<<<B, 256, 0, stream>>>(hm, wv_i, bv_i, vmean, DM, DM);
    tiny_gemm<<<B, 256, 0, stream>>>(vmean, wo_i, bo_i, cw, DM, DM);

    // h += ctx@wo^T + bo: broadcast part + sparse deltas at selected rows
    addcw_kernel<<<(int)(((size_t)M*DM)/256), 256, 0, stream>>>(h, cw, L);
    scatter_delta<<<B*8*u, 256, 0, stream>>>(ctxt_all, vmean, wo_i, top_all, h, L, u);

    // ---- FFN, chunked at RF rows: y(slot0 lo) -> mid(slot1+slot2) -> y2(slot0 hi) ----
    float* yb  = slot0;
    float* mid = slot1;                        // RF*DFF fp32 = 33.5 MB spans slot1+slot2
    float* y2  = slot0 + (size_t)RF*DM;
    for (int r0 = 0; r0 < M; r0 += RF){
      ln_kernel<<<RF, 256, 0, stream>>>(h + (size_t)r0*DM, nullptr,
          ln1g + (size_t)layer*DM, ln1b + (size_t)layer*DM, yb);
      gemm(yb, w1_i, b1_i, mid, RF, DFF, DM, DM, 1, L, 0, 0, 1);
      gemm(mid, w2_i, b2_i, y2, RF, DM, DFF, DFF, 1, L, 0, 0, 0);
      ln_kernel<<<RF, 256, 0, stream>>>(h + (size_t)r0*DM, y2,
          ln2g + (size_t)layer*DM, ln2b + (size_t)layer*DM, h + (size_t)r0*DM);
    }

    // ---- conv + BN + ELU + pool (two passes per group; conv recomputed in pass B) ----
    if (layer < 2){
      const float* dw = dcw + (size_t)layer*DM*DM*3;
      const float* db = dcb + (size_t)layer*DM;
      for (int g = 0; g < nG; g++){
        const float* hg = h + (size_t)g*RG*DM;
        gemm(hg, dw + 0, db,      slot0, RG, DM, DM, DM*3, 3, L, -1, 0, 0);
        gemm(hg, dw + 1, nullptr, slot0, RG, DM, DM, DM*3, 3, L,  0, 1, 0);
        gemm(hg, dw + 2, nullptr, slot0, RG, DM, DM, DM*3, 3, L, +1, 1, 0);
        bnstat1<<<dim3(8, 32), 256, 0, stream>>>(slot0, partS + (size_t)g*32*DM,
                                                 partQ + (size_t)g*32*DM, RG/32);
      }
      bnstat2<<<2, 256, 0, stream>>>(partS, partQ, stats, nG*32, M);
      int Lo = L/2;
      for (int g = 0; g < nG; g++){
        const float* hg = h + (size_t)g*RG*DM;
        gemm(hg, dw + 0, db,      slot0, RG, DM, DM, DM*3, 3, L, -1, 0, 0);
        gemm(hg, dw + 1, nullptr, slot0, RG, DM, DM, DM*3, 3, L,  0, 1, 0);
        gemm(hg, dw + 2, nullptr, slot0, RG, DM, DM, DM*3, 3, L, +1, 1, 0);
        bnpool<<<(int)(((size_t)G*Lo*DM)/256), 256, 0, stream>>>(slot0, stats,
            bng + (size_t)layer*DM, bnb + (size_t)layer*DM, h, L, Lo, g*G);
      }
      L = Lo;
    }
  }

  final_kernel<<<B, 128, 0, stream>>>(h, x, flg, flb, pw, pb, skw, skb, (float*)d_out, L, L0);
}

// Round 4
// 13999.147 us; speedup vs baseline: 3.2271x; 3.2271x over previous
//
#include <hip/hip_runtime.h>
#include <cmath>

#define DM 512
#define DH 64

typedef __attribute__((ext_vector_type(8))) short short8;
typedef __attribute__((ext_vector_type(4))) float float4v;

__device__ inline float b2f(unsigned short u){
  union{unsigned int i; float f;} z; z.i = ((unsigned)u)<<16; return z.f;
}
__device__ inline unsigned short f2b(float f){
  unsigned int x = __float_as_uint(f);
  return (unsigned short)((x + 0x7fffu + ((x>>16)&1u)) >> 16);   // RNE
}

#define GLL(gp, lp) __builtin_amdgcn_global_load_lds((const __attribute__((address_space(1))) void*)(gp), \
    (__attribute__((address_space(3))) void*)(lp), 16, 0, 0)

// ---------------- Threefry-2x32-20 (matches jax.random) ----------------
__host__ __device__ inline void tf2x32(unsigned k0, unsigned k1, unsigned& x0, unsigned& x1){
  const unsigned ks0=k0, ks1=k1, ks2=k0^k1^0x1BD11BDAu;
  x0 += ks0; x1 += ks1;
#define TF_ROT(r) { x0 += x1; x1 = (x1<<(r))|(x1>>(32-(r))); x1 ^= x0; }
  TF_ROT(13) TF_ROT(15) TF_ROT(26) TF_ROT(6)
  x0 += ks1; x1 += ks2 + 1u;
  TF_ROT(17) TF_ROT(29) TF_ROT(16) TF_ROT(24)
  x0 += ks2; x1 += ks0 + 2u;
  TF_ROT(13) TF_ROT(15) TF_ROT(26) TF_ROT(6)
  x0 += ks0; x1 += ks1 + 3u;
  TF_ROT(17) TF_ROT(29) TF_ROT(16) TF_ROT(24)
  x0 += ks1; x1 += ks2 + 4u;
  TF_ROT(13) TF_ROT(15) TF_ROT(26) TF_ROT(6)
  x0 += ks2; x1 += ks0 + 5u;
#undef TF_ROT
}

__global__ __launch_bounds__(256) void idx_kernel(int* __restrict__ idx, unsigned k2a, unsigned k2b,
                                                  int S2, int Lmask){
  int j = blockIdx.x*256 + threadIdx.x;
  if (j >= S2) return;
  unsigned x0 = (unsigned)j, x1 = (unsigned)(S2 + j);
  tf2x32(k2a, k2b, x0, x1);
  idx[j]      = (int)(x0 & (unsigned)Lmask);
  idx[S2 + j] = (int)(x1 & (unsigned)Lmask);
}

// ---------------- token embed: circular conv (7ch->512) + sinusoid PE ----------------
__global__ __launch_bounds__(256) void embed_kernel(const float* __restrict__ x, const float* __restrict__ tcw,
                                                    float* __restrict__ h, int L){
  size_t i = (size_t)blockIdx.x*256 + threadIdx.x;
  int d = (int)(i % DM);
  size_t r = i / DM;
  int l = (int)(r % L);
  int b = (int)(r / L);
  const float* xb = x + (size_t)b*L*7;
  float acc = 0.f;
#pragma unroll
  for (int kk=0; kk<3; kk++){
    int ls = l + kk - 1;
    ls = (ls < 0) ? ls + L : (ls >= L ? ls - L : ls);
    const float* xe = xb + (size_t)ls*7;
    const float* wp = tcw + (size_t)d*21 + kk;
#pragma unroll
    for (int c=0;c<7;c++) acc += xe[c]*wp[3*c];
  }
  const float scale = -0.017988946f;  // -ln(10000)/512
  float freq = expf((float)(d & ~1) * scale);
  float ang  = (float)l * freq;
  float pe   = (d & 1) ? cosf(ang) : sinf(ang);
  h[i] = acc + pe;
}

// ---------------- fp32 -> bf16 conversion (vectorized) ----------------
__global__ __launch_bounds__(256) void f2b_vec(const float* __restrict__ src, unsigned short* __restrict__ dst, int n4){
  int i = blockIdx.x*256 + threadIdx.x;
  if (i >= n4) return;
  float4 v = ((const float4*)src)[i];
  ushort4 o; o.x = f2b(v.x); o.y = f2b(v.y); o.z = f2b(v.z); o.w = f2b(v.w);
  ((ushort4*)dst)[i] = o;
}

// ---------------- pack conv weights: wtap[k][n][c] = dcw[n][c][k] (bf16) ----------------
__global__ __launch_bounds__(256) void packconv(const float* __restrict__ dcw, unsigned short* __restrict__ wtap){
  int i = blockIdx.x*256 + threadIdx.x;
  if (i >= 3*DM*DM) return;
  int k = i / (DM*DM); int rem = i % (DM*DM); int n = rem / DM; int c = rem % DM;
  wtap[i] = f2b(dcw[(size_t)n*(DM*3) + c*3 + k]);
}

// =======================================================================
// bf16 MFMA GEMM: C = act(A@W^T + bias) [+C].  A: MxK bf16 row-major.
// Wb: NxK bf16 row-major. 128x128 tile, BK=32, global_load_lds staging
// with XOR chunk swizzle (2-way LDS conflicts only).
// =======================================================================
#define GBM 128
#define GBN 128
#define GBK 32
__global__ __launch_bounds__(256) void bgemm(const unsigned short* __restrict__ A,
    const unsigned short* __restrict__ Wb, const float* __restrict__ bias, void* __restrict__ C,
    int N, int K, int L, int shift, int beta, int act, int outbf){
  __shared__ unsigned short As[GBM*GBK];   // 8 KB
  __shared__ unsigned short Bs[GBN*GBK];   // 8 KB
  int tid = threadIdx.x;
  int w = tid >> 6, ln = tid & 63;
  int row0 = blockIdx.y*GBM, col0 = blockIdx.x*GBN;

  // staging source pointers (chunk idx = q*256 + tid -> r = idx>>2, c = idx&3)
  const unsigned short* agp[2];
  const unsigned short* bgp[2];
#pragma unroll
  for (int q=0;q<2;q++){
    int ch = q*256 + tid;
    int r = ch >> 2, c = ch & 3;
    int gc = c ^ ((r>>1)&3);
    int gr = row0 + r;
    if (shift != 0){
      int b = gr / L, l = gr % L;
      int ls = l + shift; if (ls < 0) ls += L; if (ls >= L) ls -= L;
      gr = b*L + ls;
    }
    agp[q] = A  + (size_t)gr*K + gc*8;
    bgp[q] = Wb + (size_t)(col0 + r)*K + gc*8;
  }
  char* asb = (char*)As; char* bsb = (char*)Bs;
  // fragment LDS byte offsets (chunk swizzle applied)
  int fr_a[4], fr_b[4];
  int cf = ln >> 4;
#pragma unroll
  for (int i=0;i<4;i++){
    int ra = (w&1)*64 + i*16 + (ln & 15);
    fr_a[i] = (ra*4 + (cf ^ ((ra>>1)&3)))*16;
    int rb = (w>>1)*64 + i*16 + (ln & 15);
    fr_b[i] = (rb*4 + (cf ^ ((rb>>1)&3)))*16;
  }
  float4v acc[4][4] = {};

  for (int k0 = 0; k0 < K; k0 += GBK){
#pragma unroll
    for (int q=0;q<2;q++){
      GLL(agp[q] + k0, asb + q*4096 + w*1024);
      GLL(bgp[q] + k0, bsb + q*4096 + w*1024);
    }
    __syncthreads();
    short8 af[4], bf[4];
#pragma unroll
    for (int i=0;i<4;i++) af[i] = *(const short8*)(asb + fr_a[i]);
#pragma unroll
    for (int j=0;j<4;j++) bf[j] = *(const short8*)(bsb + fr_b[j]);
#pragma unroll
    for (int i=0;i<4;i++)
#pragma unroll
      for (int j=0;j<4;j++)
        acc[i][j] = __builtin_amdgcn_mfma_f32_16x16x32_bf16(af[i], bf[j], acc[i][j], 0, 0, 0);
    __syncthreads();
  }

  // epilogue: row = i*16 + (ln>>4)*4 + reg, col = j*16 + (ln&15)
  float* Cf = (float*)C;
  unsigned short* Cb = (unsigned short*)C;
  int colb = col0 + (w>>1)*64 + (ln & 15);
#pragma unroll
  for (int i=0;i<4;i++){
#pragma unroll
    for (int r=0;r<4;r++){
      int grow = row0 + (w&1)*64 + i*16 + (ln>>4)*4 + r;
      size_t base = (size_t)grow*N + colb;
#pragma unroll
      for (int j=0;j<4;j++){
        float v = acc[i][j][r];
        if (bias) v += bias[colb + j*16];
        if (act)  v = 0.5f * v * (1.0f + erff(v * 0.70710678f));
        if (outbf) Cb[base + j*16] = f2b(v);
        else {
          if (beta) v += Cf[base + j*16];
          Cf[base + j*16] = v;
        }
      }
    }
  }
}

// ---------------- m = max_s - mean_s of sampled dots; q,k bf16 ----------------
__global__ __launch_bounds__(256) void sample_m(const unsigned short* __restrict__ q,
    const unsigned short* __restrict__ k, const int* __restrict__ idx, float* __restrict__ m, int L, int u){
  int w = (int)(((size_t)blockIdx.x*256 + threadIdx.x) >> 6);
  int lane = threadIdx.x & 63;
  int l = w % L; int hh = (w / L) & 7; int b = w / (L * 8);
  float qv = b2f(q[((size_t)b*L + l)*DM + hh*DH + lane]);
  const unsigned short* kb = k + (size_t)b*L*DM + hh*DH + lane;
  float mx = -1e30f, sum = 0.f;
  for (int s=0; s<u; s++){
    int kp = idx[l*u + s];
    float p = qv * b2f(kb[(size_t)kp*DM]);
#pragma unroll
    for (int off=32; off; off>>=1) p += __shfl_xor(p, off);
    mx = fmaxf(mx, p); sum += p;
  }
  if (lane == 0) m[((size_t)b*8 + hh)*L + l] = mx - sum/(float)u;
}

// ---------------- iterative top-u argmax per (b,h), min-index tie-break ----------------
__global__ __launch_bounds__(256) void topk_kernel(const float* __restrict__ m, int* __restrict__ top, int L, int u){
  int bh = blockIdx.x;
  const float* mm = m + (size_t)bh*L;
  __shared__ float vals[2048];
  __shared__ float rv[256];
  __shared__ int   ri[256];
  for (int i=threadIdx.x; i<L; i+=256) vals[i] = mm[i];
  __syncthreads();
  for (int it=0; it<u; it++){
    float bv = -1e30f; int bi = 0x7fffffff;
    for (int i=threadIdx.x; i<L; i+=256){
      float v = vals[i];
      if (v > bv || (v == bv && i < bi)) { bv = v; bi = i; }
    }
    rv[threadIdx.x] = bv; ri[threadIdx.x] = bi;
    __syncthreads();
    for (int s=128; s; s>>=1){
      if (threadIdx.x < s){
        float v = rv[threadIdx.x+s]; int i2 = ri[threadIdx.x+s];
        if (v > rv[threadIdx.x] || (v == rv[threadIdx.x] && i2 < ri[threadIdx.x])){
          rv[threadIdx.x] = v; ri[threadIdx.x] = i2;
        }
      }
      __syncthreads();
    }
    if (threadIdx.x == 0){ top[bh*u + it] = ri[0]; vals[ri[0]] = -1e31f; }
    __syncthreads();
  }
}

// ---------------- column mean over L rows per batch (fp32 h) ----------------
__global__ __launch_bounds__(256) void colmean_kernel(const float* __restrict__ src, float* __restrict__ dst, int L){
  int i = blockIdx.x*256 + threadIdx.x;   // B*DM
  int d = i % DM, b = i / DM;
  const float* p = src + (size_t)b*L*DM + d;
  float s = 0.f;
  for (int l=0; l<L; l++) s += p[(size_t)l*DM];
  dst[i] = s / (float)L;
}

// ---------------- tiny fp32 GEMM: one block per row ----------------
__global__ __launch_bounds__(256) void tiny_gemm(const float* __restrict__ A, const float* __restrict__ W,
    const float* __restrict__ bias, float* __restrict__ C, int N, int K){
  int row = blockIdx.x;
  const float* ar = A + (size_t)row*K;
  __shared__ float as[DM];
  for (int k=threadIdx.x; k<K; k+=256) as[k] = ar[k];
  __syncthreads();
  for (int n = threadIdx.x; n < N; n += 256){
    float acc = bias ? bias[n] : 0.f;
    const float* wr = W + (size_t)n*K;
    for (int k=0; k<K; k++) acc += as[k]*wr[k];
    C[(size_t)row*N + n] = acc;
  }
}

// ---------------- gather q rows for top queries (bf16 q -> fp32 qred) ----------------
__global__ __launch_bounds__(256) void qred_kernel(const unsigned short* __restrict__ q, const int* __restrict__ top,
    float* __restrict__ qred, int L, int u, int n){
  int i = blockIdx.x*256 + threadIdx.x;
  if (i >= n) return;
  int d = i & 63; int rest = i >> 6; int j = rest % u; int bh = rest / u;
  int hh = bh & 7; int b = bh >> 3;
  int pos = top[bh*u + j];
  qred[i] = b2f(q[((size_t)b*L + pos)*DM + hh*DH + d]);
}

// ---------------- full attention for selected queries; k,v bf16 ----------------
__global__ __launch_bounds__(256) void attn_topq(const float* __restrict__ qred, const unsigned short* __restrict__ k,
    const unsigned short* __restrict__ v, float* __restrict__ ctxt, int L, int u){
  int bid = blockIdx.x;
  int j = bid % u; int bh = bid / u; int hh = bh & 7; int b = bh >> 3;
  extern __shared__ float sc[];
  __shared__ float red[16];
  __shared__ float comb[4][DH];
  int t = threadIdx.x, lane = t & 63, w = t >> 6;
  float qv = qred[(size_t)(bh*u + j)*DH + lane];
  const unsigned short* kb = k + (size_t)b*L*DM + hh*DH;
  float lmax = -1e30f;
  for (int key=w; key<L; key+=4){
    float p = qv * b2f(kb[(size_t)key*DM + lane]);
#pragma unroll
    for (int off=32; off; off>>=1) p += __shfl_xor(p, off);
    p *= 0.125f;
    if (lane == 0) sc[key] = p;
    lmax = fmaxf(lmax, p);
  }
  if (lane == 0) red[w] = lmax;
  __syncthreads();
  float gmax = fmaxf(fmaxf(red[0],red[1]), fmaxf(red[2],red[3]));
  float lsum = 0.f;
  for (int i2=t; i2<L; i2+=256){ float e = expf(sc[i2]-gmax); sc[i2] = e; lsum += e; }
#pragma unroll
  for (int off=32; off; off>>=1) lsum += __shfl_xor(lsum, off);
  if (lane == 0) red[8+w] = lsum;
  __syncthreads();
  float gsum = red[8]+red[9]+red[10]+red[11];
  const unsigned short* vb = v + (size_t)b*L*DM + hh*DH;
  float acc = 0.f;
  for (int key=w; key<L; key+=4) acc += sc[key] * b2f(vb[(size_t)key*DM + lane]);
  comb[w][lane] = acc;
  __syncthreads();
  if (w == 0){
    ctxt[(size_t)(bh*u + j)*DH + lane] = (comb[0][lane]+comb[1][lane]+comb[2][lane]+comb[3][lane]) / gsum;
  }
}

// ---------------- h[b,l,:] += cw[b,:] ----------------
__global__ __launch_bounds__(256) void addcw_kernel(float* __restrict__ h, const float* __restrict__ cw, int L){
  size_t i = (size_t)blockIdx.x*256 + threadIdx.x;
  int d = (int)(i % DM);
  int b = (int)(i / ((size_t)DM*L));
  h[i] += cw[b*DM + d];
}

// ---------------- sparse correction: h[b,pos] += (ctxt - vmean_slice)@wo_slice^T ----------------
__global__ __launch_bounds__(256) void scatter_delta(const float* __restrict__ ctxt, const float* __restrict__ vmean,
    const float* __restrict__ wo, const int* __restrict__ top, float* __restrict__ h, int L, int u){
  int bid = blockIdx.x;
  int j = bid % u; int bh = bid / u; int hh = bh & 7; int b = bh >> 3;
  int pos = top[bh*u + j];
  __shared__ float delta[DH];
  int t = threadIdx.x;
  if (t < DH) delta[t] = ctxt[(size_t)(bh*u + j)*DH + t] - vmean[b*DM + hh*DH + t];
  __syncthreads();
  float* hrow = h + ((size_t)b*L + pos)*DM;
  const float* wbase = wo + hh*DH;
  for (int n = t; n < DM; n += 256){
    float acc = 0.f;
    const float* wr = wbase + (size_t)n*DM;
#pragma unroll
    for (int dd=0; dd<DH; dd++) acc += delta[dd] * wr[dd];
    atomicAdd(&hrow[n], acc);
  }
}

// ---------------- LayerNorm D=512; Yadd optional (fp32/bf16); out fp32/bf16 ----------------
__global__ __launch_bounds__(256) void ln_kernel(const float* __restrict__ X, const void* __restrict__ Yadd,
    int yb, const float* __restrict__ g, const float* __restrict__ bta, void* __restrict__ Out, int ob){
  size_t row = blockIdx.x;
  const float* xr = X + row*DM;
  int t = threadIdx.x;
  float v0 = xr[t], v1 = xr[t+256];
  if (Yadd){
    if (yb){ const unsigned short* yr = (const unsigned short*)Yadd + row*DM; v0 += b2f(yr[t]); v1 += b2f(yr[t+256]); }
    else   { const float* yr = (const float*)Yadd + row*DM; v0 += yr[t]; v1 += yr[t+256]; }
  }
  float s = v0+v1, q = v0*v0+v1*v1;
#pragma unroll
  for (int off=32; off; off>>=1){ s += __shfl_xor(s,off); q += __shfl_xor(q,off); }
  __shared__ float ss[4], qq[4];
  int w = t >> 6;
  if ((t & 63) == 0){ ss[w] = s; qq[w] = q; }
  __syncthreads();
  s = ss[0]+ss[1]+ss[2]+ss[3]; q = qq[0]+qq[1]+qq[2]+qq[3];
  float mu  = s * (1.0f/DM);
  float var = q * (1.0f/DM) - mu*mu;
  float r = rsqrtf(var + 1e-5f);
  float o0 = (v0 - mu)*r*g[t]     + bta[t];
  float o1 = (v1 - mu)*r*g[t+256] + bta[t+256];
  if (ob){
    unsigned short* Ob = (unsigned short*)Out;
    Ob[row*DM + t] = f2b(o0); Ob[row*DM + t+256] = f2b(o1);
  } else {
    float* Of = (float*)Out;
    Of[row*DM + t] = o0; Of[row*DM + t+256] = o1;
  }
}

// ---------------- BN partial sums (grid: 8 x 32) ----------------
__global__ __launch_bounds__(256) void bnstat1(const float* __restrict__ C, float* __restrict__ partS,
                                               float* __restrict__ partQ, int rpb){
  int chb = blockIdx.x;
  int mb  = blockIdx.y;
  int g = threadIdx.x >> 6, c = threadIdx.x & 63;
  int ch = chb*64 + c;
  float s = 0.f, q = 0.f;
  int r0 = mb * rpb;
  for (int r = r0 + g; r < r0 + rpb; r += 4){
    float v = C[(size_t)r*DM + ch]; s += v; q += v*v;
  }
  __shared__ float ls[4][64], lq[4][64];
  ls[g][c] = s; lq[g][c] = q;
  __syncthreads();
  if (g == 0){
    s = ls[0][c]+ls[1][c]+ls[2][c]+ls[3][c];
    q = lq[0][c]+lq[1][c]+lq[2][c]+lq[3][c];
    partS[(size_t)mb*DM + ch] = s;
    partQ[(size_t)mb*DM + ch] = q;
  }
}
__global__ __launch_bounds__(256) void bnstat2(const float* __restrict__ partS, const float* __restrict__ partQ,
                                               float* __restrict__ stats, int NB, int M){
  int ch = blockIdx.x*256 + threadIdx.x;
  if (ch >= DM) return;
  float s = 0.f, q = 0.f;
  for (int mb=0; mb<NB; mb++){
    s += partS[(size_t)mb*DM + ch];
    q += partQ[(size_t)mb*DM + ch];
  }
  float mu = s / (float)M;
  stats[ch] = mu;
  stats[DM + ch] = q / (float)M - mu*mu;
}

// ---------------- BN + ELU + maxpool(3,2); group-local C, global Out ----------------
__global__ __launch_bounds__(256) void bnpool(const float* __restrict__ C, const float* __restrict__ stats,
    const float* __restrict__ g, const float* __restrict__ bta, float* __restrict__ Out,
    int L, int Lo, int gbase){
  size_t i = (size_t)blockIdx.x*256 + threadIdx.x;
  int ch = (int)(i % DM);
  size_t r = i / DM;
  int lo = (int)(r % Lo);
  int bl = (int)(r / Lo);
  float mu = stats[ch];
  float rstd = rsqrtf(stats[DM+ch] + 1e-5f);
  float gg = g[ch], bb = bta[ch];
  float best = -1e30f;
#pragma unroll
  for (int t=-1; t<=1; t++){
    int li = 2*lo + t;
    if (li >= 0 && li < L){
      float v = (C[((size_t)bl*L + li)*DM + ch] - mu)*rstd*gg + bb;
      v = v > 0.f ? v : expm1f(v);
      best = fmaxf(best, v);
    }
  }
  Out[((size_t)(gbase + bl)*Lo + lo)*DM + ch] = best;
}

// ---------------- final: LN(last row) @ proj^T + proj_b + skip ----------------
__global__ __launch_bounds__(128) void final_kernel(const float* __restrict__ h, const float* __restrict__ x,
    const float* __restrict__ fg, const float* __restrict__ fb, const float* __restrict__ pw,
    const float* __restrict__ pb, const float* __restrict__ sw, const float* __restrict__ sb,
    float* __restrict__ out, int Lf, int L0){
  int b = blockIdx.x;
  const float* row = h + ((size_t)b*Lf + (Lf-1))*DM;
  __shared__ float xn[DM];
  __shared__ float rs[2], rq[2];
  int t = threadIdx.x;
  float v[4]; float s = 0.f, q = 0.f;
#pragma unroll
  for (int i=0;i<4;i++){ v[i] = row[t + i*128]; s += v[i]; q += v[i]*v[i]; }
#pragma unroll
  for (int off=32; off; off>>=1){ s += __shfl_xor(s,off); q += __shfl_xor(q,off); }
  if ((t & 63) == 0){ rs[t>>6] = s; rq[t>>6] = q; }
  __syncthreads();
  s = rs[0]+rs[1]; q = rq[0]+rq[1];
  float mu = s*(1.0f/DM), var = q*(1.0f/DM) - mu*mu;
  float r = rsqrtf(var + 1e-5f);
#pragma unroll
  for (int i=0;i<4;i++){ int d = t + i*128; xn[d] = (v[i]-mu)*r*fg[d] + fb[d]; }
  __syncthreads();
  if (t < 96){
    float acc = pb[t] + sb[t];
    const float* xr = x + ((size_t)b*L0 + (L0-1))*7;
#pragma unroll
    for (int c=0;c<7;c++) acc += xr[c]*sw[t*7+c];
    for (int d=0; d<DM; d++) acc += xn[d]*pw[(size_t)t*DM + d];
    out[b*96 + t] = acc;
  }
}

// =======================================================================
extern "C" void kernel_launch(void* const* d_in, const int* in_sizes, int n_in,
                              void* d_out, int out_size, void* d_ws, size_t ws_size,
                              hipStream_t stream){
  const float* x    = (const float*)d_in[0];
  const float* skw  = (const float*)d_in[1];
  const float* skb  = (const float*)d_in[2];
  const float* tcw  = (const float*)d_in[3];
  const float* wq   = (const float*)d_in[4];
  const float* bq   = (const float*)d_in[5];
  const float* wk   = (const float*)d_in[6];
  const float* bk   = (const float*)d_in[7];
  const float* wv   = (const float*)d_in[8];
  const float* bv   = (const float*)d_in[9];
  const float* wo   = (const float*)d_in[10];
  const float* bo   = (const float*)d_in[11];
  const float* w1   = (const float*)d_in[12];
  const float* b1   = (const float*)d_in[13];
  const float* w2   = (const float*)d_in[14];
  const float* b2   = (const float*)d_in[15];
  const float* ln1g = (const float*)d_in[16];
  const float* ln1b = (const float*)d_in[17];
  const float* ln2g = (const float*)d_in[18];
  const float* ln2b = (const float*)d_in[19];
  const float* dcw  = (const float*)d_in[20];
  const float* dcb  = (const float*)d_in[21];
  const float* bng  = (const float*)d_in[22];
  const float* bnb  = (const float*)d_in[23];
  const float* flg  = (const float*)d_in[24];
  const float* flb  = (const float*)d_in[25];
  const float* pw   = (const float*)d_in[26];
  const float* pb   = (const float*)d_in[27];

  const int B = 32, L0 = 2048, DFF = 2048;
  const int RG = 16384;                // rows per attention/conv group
  const int RF = 8192;                 // rows per FFN chunk
  char* ws = (char*)d_ws;
  const size_t SZH  = (size_t)B*L0*DM*sizeof(float);        // 134.2 MB
  const size_t SLOT = (size_t)RG*DM*sizeof(unsigned short); // 16.78 MB

  const size_t WBSZ = (size_t)(3*DM*DM + 2*DFF*DM + 3*DM*DM)*2;  // 7.34 MB
  size_t small_bytes = (size_t)L0*40*4          // idx_buf
                     + (size_t)RG*8*4           // m_buf
                     + (size_t)B*8*40*4         // top_all
                     + (size_t)32*8*40*64*4     // qred_loc
                     + (size_t)32*8*40*64*4     // ctxt_all
                     + 3*(size_t)B*DM*4         // hm, vmean, cw
                     + 2*(size_t)4*32*DM*4      // partS, partQ
                     + (size_t)2*DM*4;          // stats
  if (ws_size < SZH + 4*SLOT + WBSZ + small_bytes) return;   // clean fail, not fault

  float*          h   = (float*)(ws);
  unsigned short* P0  = (unsigned short*)(ws + SZH);               // hgb / y+y2
  unsigned short* P1  = (unsigned short*)(ws + SZH + SLOT);        // q / mid / convf
  unsigned short* P2  = (unsigned short*)(ws + SZH + 2*SLOT);      // k / mid / convf
  unsigned short* P3  = (unsigned short*)(ws + SZH + 3*SLOT);      // v
  unsigned short* wb  = (unsigned short*)(ws + SZH + 4*SLOT);      // bf16 weights
  unsigned short* wqb = wb;
  unsigned short* wkb = wqb + (size_t)DM*DM;
  unsigned short* wvb = wkb + (size_t)DM*DM;
  unsigned short* w1b = wvb + (size_t)DM*DM;
  unsigned short* w2b = w1b + (size_t)DFF*DM;
  unsigned short* wtap= w2b + (size_t)DM*DFF;                      // 3*DM*DM
  char* sm = ws + SZH + 4*SLOT + WBSZ;
  int*   idx_buf  = (int*)sm;
  float* m_buf    = (float*)(sm + (size_t)L0*40*4);
  int*   top_all  = (int*)((char*)m_buf + (size_t)RG*8*4);
  float* qred_loc = (float*)((char*)top_all + (size_t)B*8*40*4);
  float* ctxt_all = qred_loc + (size_t)32*8*40*64;
  float* hm       = ctxt_all + (size_t)32*8*40*64;
  float* vmean    = hm + (size_t)B*DM;
  float* cw       = vmean + (size_t)B*DM;
  float* partS    = cw + (size_t)B*DM;
  float* partQ    = partS + (size_t)4*32*DM;
  float* stats    = partQ + (size_t)4*32*DM;

  auto gemm = [&](const unsigned short* A, const unsigned short* W, const float* bias, void* C,
                  int M, int N, int K, int L, int shift, int beta, int act, int outbf){
    dim3 g(N/GBN, M/GBM);
    bgemm<<<g, 256, 0, stream>>>(A, W, bias, C, N, K, L, shift, beta, act, outbf);
  };
  auto conv_b = [&](const float* src, unsigned short* dst, size_t n){
    f2b_vec<<<(int)((n/4 + 255)/256), 256, 0, stream>>>(src, dst, (int)(n/4));
  };

  // 1. token conv + positional embedding
  embed_kernel<<<(int)(((size_t)B*L0*DM)/256), 256, 0, stream>>>(x, tcw, h, L0);

  int L = L0;
  for (int layer = 0; layer < 3; layer++){
    int M = B * L;
    int u = (int)(5.0 * log((double)L + 1.0));   // 38 / 34 / 31
    int G = RG / L;                              // batches per group: 8 / 16 / 32
    int nG = M / RG;                             // groups: 4 / 2 / 1
    const float* bq_i = bq + (size_t)layer*DM;
    const float* bk_i = bk + (size_t)layer*DM;
    const float* wv_i = wv + (size_t)layer*DM*DM;  const float* bv_i = bv + (size_t)layer*DM;
    const float* wo_i = wo + (size_t)layer*DM*DM;  const float* bo_i = bo + (size_t)layer*DM;
    const float* b1_i = b1 + (size_t)layer*DFF;
    const float* b2_i = b2 + (size_t)layer*DM;

    // convert weights for this layer to bf16 (packed)
    conv_b(wq + (size_t)layer*DM*DM, wqb, (size_t)DM*DM);
    conv_b(wk + (size_t)layer*DM*DM, wkb, (size_t)DM*DM);
    conv_b(wv_i,                      wvb, (size_t)DM*DM);
    conv_b(w1 + (size_t)layer*DFF*DM, w1b, (size_t)DFF*DM);
    conv_b(w2 + (size_t)layer*DM*DFF, w2b, (size_t)DM*DFF);
    if (layer < 2)
      packconv<<<(3*DM*DM + 255)/256, 256, 0, stream>>>(dcw + (size_t)layer*DM*DM*3, wtap);

    // PRNG indices
    unsigned ka = 0u, kb2 = (unsigned)layer;
    tf2x32(0u, 42u, ka, kb2);
    unsigned a0 = 0u, a1 = 2u;  tf2x32(ka, kb2, a0, a1);
    unsigned c0 = 1u, c1 = 3u;  tf2x32(ka, kb2, c0, c1);
    int S2 = L * u / 2;
    idx_kernel<<<(S2 + 255)/256, 256, 0, stream>>>(idx_buf, a1, c1, S2, L-1);

    // ---- attention per group: hgb(P0), q(P1), k(P2), v(P3) all bf16 ----
    for (int g = 0; g < nG; g++){
      const float* hg = h + (size_t)g*RG*DM;
      conv_b(hg, P0, (size_t)RG*DM);
      gemm(P0, wqb, bq_i, P1, RG, DM, DM, L, 0, 0, 0, 1);
      gemm(P0, wkb, bk_i, P2, RG, DM, DM, L, 0, 0, 0, 1);
      gemm(P0, wvb, bv_i, P3, RG, DM, DM, L, 0, 0, 0, 1);
      sample_m<<<(int)(((size_t)RG*8*64)/256), 256, 0, stream>>>(P1, P2, idx_buf, m_buf, L, u);
      int* top_g = top_all + (size_t)g*G*8*u;
      topk_kernel<<<G*8, 256, 0, stream>>>(m_buf, top_g, L, u);
      int nqr = G*8*u*DH;
      qred_kernel<<<(nqr + 255)/256, 256, 0, stream>>>(P1, top_g, qred_loc, L, u, nqr);
      attn_topq<<<G*8*u, 256, (size_t)L*sizeof(float), stream>>>(qred_loc, P2, P3,
          ctxt_all + (size_t)g*G*8*u*DH, L, u);
    }

    // vmean = (mean_L h)@wv^T + bv ; cw = vmean@wo^T + bo (exact fp32 identity)
    colmean_kernel<<<B*DM/256, 256, 0, stream>>>(h, hm, L);
    tiny_gemm<<<B, 256, 0, stream>>>(hm, wv_i, bv_i, vmean, DM, DM);
    tiny_gemm<<<B, 256, 0, stream>>>(vmean, wo_i, bo_i, cw, DM, DM);

    addcw_kernel<<<(int)(((size_t)M*DM)/256), 256, 0, stream>>>(h, cw, L);
    scatter_delta<<<B*8*u, 256, 0, stream>>>(ctxt_all, vmean, wo_i, top_all, h, L, u);

    // ---- FFN: y(P0 bf16) -> mid(P1+P2 bf16) -> y2(P0+RF*DM bf16) -> LN2 ----
    unsigned short* ybuf = P0;
    unsigned short* mid  = P1;
    unsigned short* y2b  = P0 + (size_t)RF*DM;
    const float* l1g = ln1g + (size_t)layer*DM; const float* l1b = ln1b + (size_t)layer*DM;
    const float* l2g = ln2g + (size_t)layer*DM; const float* l2b = ln2b + (size_t)layer*DM;
    for (int r0 = 0; r0 < M; r0 += RF){
      ln_kernel<<<RF, 256, 0, stream>>>(h + (size_t)r0*DM, nullptr, 0, l1g, l1b, ybuf, 1);
      gemm(ybuf, w1b, b1_i, mid, RF, DFF, DM, L, 0, 0, 1, 1);
      gemm(mid, w2b, b2_i, y2b, RF, DM, DFF, L, 0, 0, 0, 1);
      ln_kernel<<<RF, 256, 0, stream>>>(h + (size_t)r0*DM, y2b, 1, l2g, l2b, h + (size_t)r0*DM, 0);
    }

    // ---- conv + BN + ELU + pool (two passes per group; bf16 taps, fp32 out) ----
    if (layer < 2){
      const float* db = dcb + (size_t)layer*DM;
      float* convf = (float*)P1;   // RG x DM fp32 spans P1+P2
      for (int g = 0; g < nG; g++){
        const float* hg = h + (size_t)g*RG*DM;
        conv_b(hg, P0, (size_t)RG*DM);
        gemm(P0, wtap + 0*DM*DM, db,      convf, RG, DM, DM, L, -1, 0, 0, 0);
        gemm(P0, wtap + 1*DM*DM, nullptr, convf, RG, DM, DM, L,  0, 1, 0, 0);
        gemm(P0, wtap + 2*DM*DM, nullptr, convf, RG, DM, DM, L, +1, 1, 0, 0);
        bnstat1<<<dim3(8, 32), 256, 0, stream>>>(convf, partS + (size_t)g*32*DM,
                                                 partQ + (size_t)g*32*DM, RG/32);
      }
      bnstat2<<<2, 256, 0, stream>>>(partS, partQ, stats, nG*32, M);
      int Lo = L/2;
      for (int g = 0; g < nG; g++){
        const float* hg = h + (size_t)g*RG*DM;
        conv_b(hg, P0, (size_t)RG*DM);
        gemm(P0, wtap + 0*DM*DM, db,      convf, RG, DM, DM, L, -1, 0, 0, 0);
        gemm(P0, wtap + 1*DM*DM, nullptr, convf, RG, DM, DM, L,  0, 1, 0, 0);
        gemm(P0, wtap + 2*DM*DM, nullptr, convf, RG, DM, DM, L, +1, 1, 0, 0);
        bnpool<<<(int)(((size_t)G*Lo*DM)/256), 256, 0, stream>>>(convf, stats,
            bng + (size_t)layer*DM, bnb + (size_t)layer*DM, h, L, Lo, g*G);
      }
      L = Lo;
    }
  }

  final_kernel<<<B, 128, 0, stream>>>(h, x, flg, flb, pw, pb, skw, skb, (float*)d_out, L, L0);
}

// Round 5
// 10325.932 us; speedup vs baseline: 4.3750x; 1.3557x over previous
//
#include <hip/hip_runtime.h>
#include <cmath>

#define DM 512
#define DH 64

typedef __attribute__((ext_vector_type(8))) short short8;
typedef __attribute__((ext_vector_type(4))) float float4v;

__device__ inline float b2f(unsigned short u){
  union{unsigned int i; float f;} z; z.i = ((unsigned)u)<<16; return z.f;
}
__device__ inline unsigned short f2b(float f){
  unsigned int x = __float_as_uint(f);
  return (unsigned short)((x + 0x7fffu + ((x>>16)&1u)) >> 16);   // RNE
}

#define GLL(gp, lp) __builtin_amdgcn_global_load_lds((const __attribute__((address_space(1))) void*)(gp), \
    (__attribute__((address_space(3))) void*)(lp), 16, 0, 0)

// ---------------- Threefry-2x32-20 (matches jax.random) ----------------
__host__ __device__ inline void tf2x32(unsigned k0, unsigned k1, unsigned& x0, unsigned& x1){
  const unsigned ks0=k0, ks1=k1, ks2=k0^k1^0x1BD11BDAu;
  x0 += ks0; x1 += ks1;
#define TF_ROT(r) { x0 += x1; x1 = (x1<<(r))|(x1>>(32-(r))); x1 ^= x0; }
  TF_ROT(13) TF_ROT(15) TF_ROT(26) TF_ROT(6)
  x0 += ks1; x1 += ks2 + 1u;
  TF_ROT(17) TF_ROT(29) TF_ROT(16) TF_ROT(24)
  x0 += ks2; x1 += ks0 + 2u;
  TF_ROT(13) TF_ROT(15) TF_ROT(26) TF_ROT(6)
  x0 += ks0; x1 += ks1 + 3u;
  TF_ROT(17) TF_ROT(29) TF_ROT(16) TF_ROT(24)
  x0 += ks1; x1 += ks2 + 4u;
  TF_ROT(13) TF_ROT(15) TF_ROT(26) TF_ROT(6)
  x0 += ks2; x1 += ks0 + 5u;
#undef TF_ROT
}

__global__ __launch_bounds__(256) void idx_kernel(int* __restrict__ idx, unsigned k2a, unsigned k2b,
                                                  int S2, int Lmask){
  int j = blockIdx.x*256 + threadIdx.x;
  if (j >= S2) return;
  unsigned x0 = (unsigned)j, x1 = (unsigned)(S2 + j);
  tf2x32(k2a, k2b, x0, x1);
  idx[j]      = (int)(x0 & (unsigned)Lmask);
  idx[S2 + j] = (int)(x1 & (unsigned)Lmask);
}

// ---------------- token embed: circular conv (7ch->512) + sinusoid PE ----------------
__global__ __launch_bounds__(256) void embed_kernel(const float* __restrict__ x, const float* __restrict__ tcw,
                                                    float* __restrict__ h, int L){
  size_t i = (size_t)blockIdx.x*256 + threadIdx.x;
  int d = (int)(i % DM);
  size_t r = i / DM;
  int l = (int)(r % L);
  int b = (int)(r / L);
  const float* xb = x + (size_t)b*L*7;
  float acc = 0.f;
#pragma unroll
  for (int kk=0; kk<3; kk++){
    int ls = l + kk - 1;
    ls = (ls < 0) ? ls + L : (ls >= L ? ls - L : ls);
    const float* xe = xb + (size_t)ls*7;
    const float* wp = tcw + (size_t)d*21 + kk;
#pragma unroll
    for (int c=0;c<7;c++) acc += xe[c]*wp[3*c];
  }
  const float scale = -0.017988946f;  // -ln(10000)/512
  float freq = expf((float)(d & ~1) * scale);
  float ang  = (float)l * freq;
  float pe   = (d & 1) ? cosf(ang) : sinf(ang);
  h[i] = acc + pe;
}

// ---------------- fp32 -> bf16 conversion (vectorized) ----------------
__global__ __launch_bounds__(256) void f2b_vec(const float* __restrict__ src, unsigned short* __restrict__ dst, int n4){
  int i = blockIdx.x*256 + threadIdx.x;
  if (i >= n4) return;
  float4 v = ((const float4*)src)[i];
  ushort4 o; o.x = f2b(v.x); o.y = f2b(v.y); o.z = f2b(v.z); o.w = f2b(v.w);
  ((ushort4*)dst)[i] = o;
}

// ---------------- pack conv weights: wtap[k][n][c] = dcw[n][c][k] (bf16) ----------------
__global__ __launch_bounds__(256) void packconv(const float* __restrict__ dcw, unsigned short* __restrict__ wtap){
  int i = blockIdx.x*256 + threadIdx.x;
  if (i >= 3*DM*DM) return;
  int k = i / (DM*DM); int rem = i % (DM*DM); int n = rem / DM; int c = rem % DM;
  wtap[i] = f2b(dcw[(size_t)n*(DM*3) + c*3 + k]);
}

// =======================================================================
// bf16 MFMA GEMM: C = act(A@W^T + bias) [+C].  128x128 tile, BK=32.
// =======================================================================
#define GBM 128
#define GBN 128
#define GBK 32
__global__ __launch_bounds__(256) void bgemm(const unsigned short* __restrict__ A,
    const unsigned short* __restrict__ Wb, const float* __restrict__ bias, void* __restrict__ C,
    int N, int K, int L, int shift, int beta, int act, int outbf){
  __shared__ unsigned short As[GBM*GBK];
  __shared__ unsigned short Bs[GBN*GBK];
  int tid = threadIdx.x;
  int w = tid >> 6, ln = tid & 63;
  int row0 = blockIdx.y*GBM, col0 = blockIdx.x*GBN;

  const unsigned short* agp[2];
  const unsigned short* bgp[2];
#pragma unroll
  for (int q=0;q<2;q++){
    int ch = q*256 + tid;
    int r = ch >> 2, c = ch & 3;
    int gc = c ^ ((r>>1)&3);
    int gr = row0 + r;
    if (shift != 0){
      int b = gr / L, l = gr % L;
      int ls = l + shift; if (ls < 0) ls += L; if (ls >= L) ls -= L;
      gr = b*L + ls;
    }
    agp[q] = A  + (size_t)gr*K + gc*8;
    bgp[q] = Wb + (size_t)(col0 + r)*K + gc*8;
  }
  char* asb = (char*)As; char* bsb = (char*)Bs;
  int fr_a[4], fr_b[4];
  int cf = ln >> 4;
#pragma unroll
  for (int i=0;i<4;i++){
    int ra = (w&1)*64 + i*16 + (ln & 15);
    fr_a[i] = (ra*4 + (cf ^ ((ra>>1)&3)))*16;
    int rb = (w>>1)*64 + i*16 + (ln & 15);
    fr_b[i] = (rb*4 + (cf ^ ((rb>>1)&3)))*16;
  }
  float4v acc[4][4] = {};

  for (int k0 = 0; k0 < K; k0 += GBK){
#pragma unroll
    for (int q=0;q<2;q++){
      GLL(agp[q] + k0, asb + q*4096 + w*1024);
      GLL(bgp[q] + k0, bsb + q*4096 + w*1024);
    }
    __syncthreads();
    short8 af[4], bf[4];
#pragma unroll
    for (int i=0;i<4;i++) af[i] = *(const short8*)(asb + fr_a[i]);
#pragma unroll
    for (int j=0;j<4;j++) bf[j] = *(const short8*)(bsb + fr_b[j]);
#pragma unroll
    for (int i=0;i<4;i++)
#pragma unroll
      for (int j=0;j<4;j++)
        acc[i][j] = __builtin_amdgcn_mfma_f32_16x16x32_bf16(af[i], bf[j], acc[i][j], 0, 0, 0);
    __syncthreads();
  }

  float* Cf = (float*)C;
  unsigned short* Cb = (unsigned short*)C;
  int colb = col0 + (w>>1)*64 + (ln & 15);
#pragma unroll
  for (int i=0;i<4;i++){
#pragma unroll
    for (int r=0;r<4;r++){
      int grow = row0 + (w&1)*64 + i*16 + (ln>>4)*4 + r;
      size_t base = (size_t)grow*N + colb;
#pragma unroll
      for (int j=0;j<4;j++){
        float v = acc[i][j][r];
        if (bias) v += bias[colb + j*16];
        if (act)  v = 0.5f * v * (1.0f + erff(v * 0.70710678f));
        if (outbf) Cb[base + j*16] = f2b(v);
        else {
          if (beta) v += Cf[base + j*16];
          Cf[base + j*16] = v;
        }
      }
    }
  }
}

// ---------------- m = max_s - mean_s of sampled dots; q,k bf16 ----------------
__global__ __launch_bounds__(256) void sample_m(const unsigned short* __restrict__ q,
    const unsigned short* __restrict__ k, const int* __restrict__ idx, float* __restrict__ m, int L, int u){
  int w = (int)(((size_t)blockIdx.x*256 + threadIdx.x) >> 6);
  int lane = threadIdx.x & 63;
  int l = w % L; int hh = (w / L) & 7; int b = w / (L * 8);
  float qv = b2f(q[((size_t)b*L + l)*DM + hh*DH + lane]);
  const unsigned short* kb = k + (size_t)b*L*DM + hh*DH + lane;
  float mx = -1e30f, sum = 0.f;
  for (int s=0; s<u; s++){
    int kp = idx[l*u + s];
    float p = qv * b2f(kb[(size_t)kp*DM]);
#pragma unroll
    for (int off=32; off; off>>=1) p += __shfl_xor(p, off);
    mx = fmaxf(mx, p); sum += p;
  }
  if (lane == 0) m[((size_t)b*8 + hh)*L + l] = mx - sum/(float)u;
}

// ---------------- iterative top-u argmax per (b,h), min-index tie-break ----------------
__global__ __launch_bounds__(256) void topk_kernel(const float* __restrict__ m, int* __restrict__ top, int L, int u){
  int bh = blockIdx.x;
  const float* mm = m + (size_t)bh*L;
  __shared__ float vals[2048];
  __shared__ float rv[256];
  __shared__ int   ri[256];
  for (int i=threadIdx.x; i<L; i+=256) vals[i] = mm[i];
  __syncthreads();
  for (int it=0; it<u; it++){
    float bv = -1e30f; int bi = 0x7fffffff;
    for (int i=threadIdx.x; i<L; i+=256){
      float v = vals[i];
      if (v > bv || (v == bv && i < bi)) { bv = v; bi = i; }
    }
    rv[threadIdx.x] = bv; ri[threadIdx.x] = bi;
    __syncthreads();
    for (int s=128; s; s>>=1){
      if (threadIdx.x < s){
        float v = rv[threadIdx.x+s]; int i2 = ri[threadIdx.x+s];
        if (v > rv[threadIdx.x] || (v == rv[threadIdx.x] && i2 < ri[threadIdx.x])){
          rv[threadIdx.x] = v; ri[threadIdx.x] = i2;
        }
      }
      __syncthreads();
    }
    if (threadIdx.x == 0){ top[bh*u + it] = ri[0]; vals[ri[0]] = -1e31f; }
    __syncthreads();
  }
}

// ---------------- column mean over L rows per batch (fp32 h) ----------------
__global__ __launch_bounds__(256) void colmean_kernel(const float* __restrict__ src, float* __restrict__ dst, int L){
  int i = blockIdx.x*256 + threadIdx.x;   // B*DM
  int d = i % DM, b = i / DM;
  const float* p = src + (size_t)b*L*DM + d;
  float s = 0.f;
  for (int l=0; l<L; l++) s += p[(size_t)l*DM];
  dst[i] = s / (float)L;
}

// ---------------- tiny fp32 GEMM: one block per row ----------------
__global__ __launch_bounds__(256) void tiny_gemm(const float* __restrict__ A, const float* __restrict__ W,
    const float* __restrict__ bias, float* __restrict__ C, int N, int K){
  int row = blockIdx.x;
  const float* ar = A + (size_t)row*K;
  __shared__ float as[DM];
  for (int k=threadIdx.x; k<K; k+=256) as[k] = ar[k];
  __syncthreads();
  for (int n = threadIdx.x; n < N; n += 256){
    float acc = bias ? bias[n] : 0.f;
    const float* wr = W + (size_t)n*K;
    for (int k=0; k<K; k++) acc += as[k]*wr[k];
    C[(size_t)row*N + n] = acc;
  }
}

// ---------------- gather q rows for top queries (bf16 q -> fp32 qred) ----------------
__global__ __launch_bounds__(256) void qred_kernel(const unsigned short* __restrict__ q, const int* __restrict__ top,
    float* __restrict__ qred, int L, int u, int n){
  int i = blockIdx.x*256 + threadIdx.x;
  if (i >= n) return;
  int d = i & 63; int rest = i >> 6; int j = rest % u; int bh = rest / u;
  int hh = bh & 7; int b = bh >> 3;
  int pos = top[bh*u + j];
  qred[i] = b2f(q[((size_t)b*L + pos)*DM + hh*DH + d]);
}

// ---------------- batched scores: S[bh][m][key] = (qred . K)/8 ----------------
// grid (L/256, sg*8); one key per thread; K row unpacked into 64 VGPRs.
__global__ __launch_bounds__(256) void qk_scores(const float* __restrict__ qred,
    const unsigned short* __restrict__ kbuf, float* __restrict__ S, int L, int u){
  int bh = blockIdx.y; int b = bh >> 3, h = bh & 7;
  int key = blockIdx.x*256 + threadIdx.x;
  __shared__ float Qs[38*64];
  int t = threadIdx.x;
  for (int i = t; i < u*64; i += 256) Qs[i] = qred[(size_t)bh*u*64 + i];
  __syncthreads();
  const unsigned short* krow = kbuf + ((size_t)(b*L + key))*DM + h*DH;
  float kr[64];
#pragma unroll
  for (int c=0;c<8;c++){
    uint4 kk = *(const uint4*)(krow + c*8);
    kr[c*8+0]=b2f((unsigned short)(kk.x&0xffff)); kr[c*8+1]=b2f((unsigned short)(kk.x>>16));
    kr[c*8+2]=b2f((unsigned short)(kk.y&0xffff)); kr[c*8+3]=b2f((unsigned short)(kk.y>>16));
    kr[c*8+4]=b2f((unsigned short)(kk.z&0xffff)); kr[c*8+5]=b2f((unsigned short)(kk.z>>16));
    kr[c*8+6]=b2f((unsigned short)(kk.w&0xffff)); kr[c*8+7]=b2f((unsigned short)(kk.w>>16));
  }
  float* srow = S + (size_t)bh*u*L + key;
  for (int m = 0; m < u; m++){
    const float4* q4 = (const float4*)(Qs + m*64);
    float acc = 0.f;
#pragma unroll
    for (int c=0;c<16;c++){
      float4 qv = q4[c];
      acc += qv.x*kr[c*4] + qv.y*kr[c*4+1] + qv.z*kr[c*4+2] + qv.w*kr[c*4+3];
    }
    srow[(size_t)m*L] = acc * 0.125f;
  }
}

// ---------------- softmax over each score row, in place ----------------
__global__ __launch_bounds__(256) void softmax_rows(float* __restrict__ S, int L){
  size_t row = blockIdx.x;
  float* r = S + row*(size_t)L;
  int t = threadIdx.x;
  __shared__ float red[8];
  float mx = -1e30f;
  for (int i=t;i<L;i+=256) mx = fmaxf(mx, r[i]);
#pragma unroll
  for (int off=32; off; off>>=1) mx = fmaxf(mx, __shfl_xor(mx, off));
  if ((t&63)==0) red[t>>6] = mx;
  __syncthreads();
  mx = fmaxf(fmaxf(red[0],red[1]), fmaxf(red[2],red[3]));
  float sum = 0.f;
  for (int i=t;i<L;i+=256){ float e = expf(r[i]-mx); r[i] = e; sum += e; }
#pragma unroll
  for (int off=32; off; off>>=1) sum += __shfl_xor(sum, off);
  if ((t&63)==0) red[4+(t>>6)] = sum;
  __syncthreads();
  float inv = 1.f/(red[4]+red[5]+red[6]+red[7]);
  for (int i=t;i<L;i+=256) r[i] *= inv;
}

// ---------------- ctx += P @ V over a key tile; V staged in LDS ----------------
#define PVKT 256
__global__ __launch_bounds__(256) void pv_kernel(const float* __restrict__ P,
    const unsigned short* __restrict__ vbuf, float* __restrict__ ctxt, int L, int u){
  int bh = blockIdx.y; int b = bh >> 3, h = bh & 7;
  int k0 = blockIdx.x*PVKT;
  int t = threadIdx.x;
  __shared__ unsigned short Vs[PVKT*64];
  for (int e = t*8; e < PVKT*64; e += 2048){
    int k = e>>6, d = e&63;
    *(uint4*)(Vs + e) = *(const uint4*)(vbuf + ((size_t)(b*L + k0 + k))*DM + h*DH + d);
  }
  __syncthreads();
  int n = t & 63, mg = t >> 6;
  for (int m = mg; m < u; m += 4){
    const float* prow = P + ((size_t)bh*u + m)*L + k0;
    float acc = 0.f;
    for (int k=0;k<PVKT;k+=4){
      float4 p4 = *(const float4*)(prow + k);
      acc += p4.x*b2f(Vs[(k+0)*64+n]);
      acc += p4.y*b2f(Vs[(k+1)*64+n]);
      acc += p4.z*b2f(Vs[(k+2)*64+n]);
      acc += p4.w*b2f(Vs[(k+3)*64+n]);
    }
    atomicAdd(&ctxt[((size_t)bh*u + m)*64 + n], acc);
  }
}

// ---------------- h[b,l,:] += cw[b,:] ----------------
__global__ __launch_bounds__(256) void addcw_kernel(float* __restrict__ h, const float* __restrict__ cw, int L){
  size_t i = (size_t)blockIdx.x*256 + threadIdx.x;
  int d = (int)(i % DM);
  int b = (int)(i / ((size_t)DM*L));
  h[i] += cw[b*DM + d];
}

// ---------------- sparse correction: h[b,pos] += (ctxt - vmean_slice)@wo_slice^T ----------------
__global__ __launch_bounds__(256) void scatter_delta(const float* __restrict__ ctxt, const float* __restrict__ vmean,
    const float* __restrict__ wo, const int* __restrict__ top, float* __restrict__ h, int L, int u){
  int bid = blockIdx.x;
  int j = bid % u; int bh = bid / u; int hh = bh & 7; int b = bh >> 3;
  int pos = top[bh*u + j];
  __shared__ float delta[DH];
  int t = threadIdx.x;
  if (t < DH) delta[t] = ctxt[(size_t)(bh*u + j)*DH + t] - vmean[b*DM + hh*DH + t];
  __syncthreads();
  float* hrow = h + ((size_t)b*L + pos)*DM;
  const float* wbase = wo + hh*DH;
  for (int n = t; n < DM; n += 256){
    float acc = 0.f;
    const float* wr = wbase + (size_t)n*DM;
#pragma unroll
    for (int dd=0; dd<DH; dd++) acc += delta[dd] * wr[dd];
    atomicAdd(&hrow[n], acc);
  }
}

// ---------------- LayerNorm D=512; Yadd optional (fp32/bf16); out fp32/bf16 ----------------
__global__ __launch_bounds__(256) void ln_kernel(const float* __restrict__ X, const void* __restrict__ Yadd,
    int yb, const float* __restrict__ g, const float* __restrict__ bta, void* __restrict__ Out, int ob){
  size_t row = blockIdx.x;
  const float* xr = X + row*DM;
  int t = threadIdx.x;
  float v0 = xr[t], v1 = xr[t+256];
  if (Yadd){
    if (yb){ const unsigned short* yr = (const unsigned short*)Yadd + row*DM; v0 += b2f(yr[t]); v1 += b2f(yr[t+256]); }
    else   { const float* yr = (const float*)Yadd + row*DM; v0 += yr[t]; v1 += yr[t+256]; }
  }
  float s = v0+v1, q = v0*v0+v1*v1;
#pragma unroll
  for (int off=32; off; off>>=1){ s += __shfl_xor(s,off); q += __shfl_xor(q,off); }
  __shared__ float ss[4], qq[4];
  int w = t >> 6;
  if ((t & 63) == 0){ ss[w] = s; qq[w] = q; }
  __syncthreads();
  s = ss[0]+ss[1]+ss[2]+ss[3]; q = qq[0]+qq[1]+qq[2]+qq[3];
  float mu  = s * (1.0f/DM);
  float var = q * (1.0f/DM) - mu*mu;
  float r = rsqrtf(var + 1e-5f);
  float o0 = (v0 - mu)*r*g[t]     + bta[t];
  float o1 = (v1 - mu)*r*g[t+256] + bta[t+256];
  if (ob){
    unsigned short* Ob = (unsigned short*)Out;
    Ob[row*DM + t] = f2b(o0); Ob[row*DM + t+256] = f2b(o1);
  } else {
    float* Of = (float*)Out;
    Of[row*DM + t] = o0; Of[row*DM + t+256] = o1;
  }
}

// ---------------- BN partial sums (grid: 8 x 32) ----------------
__global__ __launch_bounds__(256) void bnstat1(const float* __restrict__ C, float* __restrict__ partS,
                                               float* __restrict__ partQ, int rpb){
  int chb = blockIdx.x;
  int mb  = blockIdx.y;
  int g = threadIdx.x >> 6, c = threadIdx.x & 63;
  int ch = chb*64 + c;
  float s = 0.f, q = 0.f;
  int r0 = mb * rpb;
  for (int r = r0 + g; r < r0 + rpb; r += 4){
    float v = C[(size_t)r*DM + ch]; s += v; q += v*v;
  }
  __shared__ float ls[4][64], lq[4][64];
  ls[g][c] = s; lq[g][c] = q;
  __syncthreads();
  if (g == 0){
    s = ls[0][c]+ls[1][c]+ls[2][c]+ls[3][c];
    q = lq[0][c]+lq[1][c]+lq[2][c]+lq[3][c];
    partS[(size_t)mb*DM + ch] = s;
    partQ[(size_t)mb*DM + ch] = q;
  }
}
__global__ __launch_bounds__(256) void bnstat2(const float* __restrict__ partS, const float* __restrict__ partQ,
                                               float* __restrict__ stats, int NB, int M){
  int ch = blockIdx.x*256 + threadIdx.x;
  if (ch >= DM) return;
  float s = 0.f, q = 0.f;
  for (int mb=0; mb<NB; mb++){
    s += partS[(size_t)mb*DM + ch];
    q += partQ[(size_t)mb*DM + ch];
  }
  float mu = s / (float)M;
  stats[ch] = mu;
  stats[DM + ch] = q / (float)M - mu*mu;
}

// ---------------- BN + ELU + maxpool(3,2); group-local C, global Out ----------------
__global__ __launch_bounds__(256) void bnpool(const float* __restrict__ C, const float* __restrict__ stats,
    const float* __restrict__ g, const float* __restrict__ bta, float* __restrict__ Out,
    int L, int Lo, int gbase){
  size_t i = (size_t)blockIdx.x*256 + threadIdx.x;
  int ch = (int)(i % DM);
  size_t r = i / DM;
  int lo = (int)(r % Lo);
  int bl = (int)(r / Lo);
  float mu = stats[ch];
  float rstd = rsqrtf(stats[DM+ch] + 1e-5f);
  float gg = g[ch], bb = bta[ch];
  float best = -1e30f;
#pragma unroll
  for (int t=-1; t<=1; t++){
    int li = 2*lo + t;
    if (li >= 0 && li < L){
      float v = (C[((size_t)bl*L + li)*DM + ch] - mu)*rstd*gg + bb;
      v = v > 0.f ? v : expm1f(v);
      best = fmaxf(best, v);
    }
  }
  Out[((size_t)(gbase + bl)*Lo + lo)*DM + ch] = best;
}

// ---------------- final: LN(last row) @ proj^T + proj_b + skip ----------------
__global__ __launch_bounds__(128) void final_kernel(const float* __restrict__ h, const float* __restrict__ x,
    const float* __restrict__ fg, const float* __restrict__ fb, const float* __restrict__ pw,
    const float* __restrict__ pb, const float* __restrict__ sw, const float* __restrict__ sb,
    float* __restrict__ out, int Lf, int L0){
  int b = blockIdx.x;
  const float* row = h + ((size_t)b*Lf + (Lf-1))*DM;
  __shared__ float xn[DM];
  __shared__ float rs[2], rq[2];
  int t = threadIdx.x;
  float v[4]; float s = 0.f, q = 0.f;
#pragma unroll
  for (int i=0;i<4;i++){ v[i] = row[t + i*128]; s += v[i]; q += v[i]*v[i]; }
#pragma unroll
  for (int off=32; off; off>>=1){ s += __shfl_xor(s,off); q += __shfl_xor(q,off); }
  if ((t & 63) == 0){ rs[t>>6] = s; rq[t>>6] = q; }
  __syncthreads();
  s = rs[0]+rs[1]; q = rq[0]+rq[1];
  float mu = s*(1.0f/DM), var = q*(1.0f/DM) - mu*mu;
  float r = rsqrtf(var + 1e-5f);
#pragma unroll
  for (int i=0;i<4;i++){ int d = t + i*128; xn[d] = (v[i]-mu)*r*fg[d] + fb[d]; }
  __syncthreads();
  if (t < 96){
    float acc = pb[t] + sb[t];
    const float* xr = x + ((size_t)b*L0 + (L0-1))*7;
#pragma unroll
    for (int c=0;c<7;c++) acc += xr[c]*sw[t*7+c];
    for (int d=0; d<DM; d++) acc += xn[d]*pw[(size_t)t*DM + d];
    out[b*96 + t] = acc;
  }
}

// =======================================================================
extern "C" void kernel_launch(void* const* d_in, const int* in_sizes, int n_in,
                              void* d_out, int out_size, void* d_ws, size_t ws_size,
                              hipStream_t stream){
  const float* x    = (const float*)d_in[0];
  const float* skw  = (const float*)d_in[1];
  const float* skb  = (const float*)d_in[2];
  const float* tcw  = (const float*)d_in[3];
  const float* wq   = (const float*)d_in[4];
  const float* bq   = (const float*)d_in[5];
  const float* wk   = (const float*)d_in[6];
  const float* bk   = (const float*)d_in[7];
  const float* wv   = (const float*)d_in[8];
  const float* bv   = (const float*)d_in[9];
  const float* wo   = (const float*)d_in[10];
  const float* bo   = (const float*)d_in[11];
  const float* w1   = (const float*)d_in[12];
  const float* b1   = (const float*)d_in[13];
  const float* w2   = (const float*)d_in[14];
  const float* b2   = (const float*)d_in[15];
  const float* ln1g = (const float*)d_in[16];
  const float* ln1b = (const float*)d_in[17];
  const float* ln2g = (const float*)d_in[18];
  const float* ln2b = (const float*)d_in[19];
  const float* dcw  = (const float*)d_in[20];
  const float* dcb  = (const float*)d_in[21];
  const float* bng  = (const float*)d_in[22];
  const float* bnb  = (const float*)d_in[23];
  const float* flg  = (const float*)d_in[24];
  const float* flb  = (const float*)d_in[25];
  const float* pw   = (const float*)d_in[26];
  const float* pb   = (const float*)d_in[27];

  const int B = 32, L0 = 2048, DFF = 2048;
  const int RG = 16384;                // rows per attention/conv group
  const int RF = 8192;                 // rows per FFN chunk
  char* ws = (char*)d_ws;
  const size_t SZH  = (size_t)B*L0*DM*sizeof(float);        // 134.2 MB
  const size_t SLOT = (size_t)RG*DM*sizeof(unsigned short); // 16.78 MB

  const size_t WBSZ = (size_t)(3*DM*DM + 2*DFF*DM + 3*DM*DM)*2;  // 7.34 MB
  size_t small_bytes = (size_t)L0*40*4          // idx_buf
                     + (size_t)RG*8*4           // m_buf
                     + (size_t)B*8*40*4         // top_all
                     + (size_t)32*8*40*64*4     // qred_loc
                     + (size_t)32*8*40*64*4     // ctxt_all
                     + 3*(size_t)B*DM*4         // hm, vmean, cw
                     + 2*(size_t)4*32*DM*4      // partS, partQ
                     + (size_t)2*DM*4;          // stats
  if (ws_size < SZH + 4*SLOT + WBSZ + small_bytes) return;   // clean fail, not fault

  float*          h   = (float*)(ws);
  unsigned short* P0  = (unsigned short*)(ws + SZH);               // hgb / S / y+y2
  unsigned short* P1  = (unsigned short*)(ws + SZH + SLOT);        // q / mid / convf
  unsigned short* P2  = (unsigned short*)(ws + SZH + 2*SLOT);      // k / mid / convf
  unsigned short* P3  = (unsigned short*)(ws + SZH + 3*SLOT);      // v
  unsigned short* wb  = (unsigned short*)(ws + SZH + 4*SLOT);      // bf16 weights
  unsigned short* wqb = wb;
  unsigned short* wkb = wqb + (size_t)DM*DM;
  unsigned short* wvb = wkb + (size_t)DM*DM;
  unsigned short* w1b = wvb + (size_t)DM*DM;
  unsigned short* w2b = w1b + (size_t)DFF*DM;
  unsigned short* wtap= w2b + (size_t)DM*DFF;                      // 3*DM*DM
  char* sm = ws + SZH + 4*SLOT + WBSZ;
  int*   idx_buf  = (int*)sm;
  float* m_buf    = (float*)(sm + (size_t)L0*40*4);
  int*   top_all  = (int*)((char*)m_buf + (size_t)RG*8*4);
  float* qred_loc = (float*)((char*)top_all + (size_t)B*8*40*4);
  float* ctxt_all = qred_loc + (size_t)32*8*40*64;
  float* hm       = ctxt_all + (size_t)32*8*40*64;
  float* vmean    = hm + (size_t)B*DM;
  float* cw       = vmean + (size_t)B*DM;
  float* partS    = cw + (size_t)B*DM;
  float* partQ    = partS + (size_t)4*32*DM;
  float* stats    = partQ + (size_t)4*32*DM;

  auto gemm = [&](const unsigned short* A, const unsigned short* W, const float* bias, void* C,
                  int M, int N, int K, int L, int shift, int beta, int act, int outbf){
    dim3 g(N/GBN, M/GBM);
    bgemm<<<g, 256, 0, stream>>>(A, W, bias, C, N, K, L, shift, beta, act, outbf);
  };
  auto conv_b = [&](const float* src, unsigned short* dst, size_t n){
    f2b_vec<<<(int)((n/4 + 255)/256), 256, 0, stream>>>(src, dst, (int)(n/4));
  };

  // 1. token conv + positional embedding
  embed_kernel<<<(int)(((size_t)B*L0*DM)/256), 256, 0, stream>>>(x, tcw, h, L0);

  int L = L0;
  const int SGtab[3] = {4, 8, 16};   // batches per attention sub-group (S fits one slot)
  for (int layer = 0; layer < 3; layer++){
    int M = B * L;
    int u = (int)(5.0 * log((double)L + 1.0));   // 38 / 34 / 31
    int G = RG / L;                              // batches per group: 8 / 16 / 32
    int nG = M / RG;                             // groups: 4 / 2 / 1
    const float* bq_i = bq + (size_t)layer*DM;
    const float* bk_i = bk + (size_t)layer*DM;
    const float* wv_i = wv + (size_t)layer*DM*DM;  const float* bv_i = bv + (size_t)layer*DM;
    const float* wo_i = wo + (size_t)layer*DM*DM;  const float* bo_i = bo + (size_t)layer*DM;
    const float* b1_i = b1 + (size_t)layer*DFF;
    const float* b2_i = b2 + (size_t)layer*DM;

    conv_b(wq + (size_t)layer*DM*DM, wqb, (size_t)DM*DM);
    conv_b(wk + (size_t)layer*DM*DM, wkb, (size_t)DM*DM);
    conv_b(wv_i,                      wvb, (size_t)DM*DM);
    conv_b(w1 + (size_t)layer*DFF*DM, w1b, (size_t)DFF*DM);
    conv_b(w2 + (size_t)layer*DM*DFF, w2b, (size_t)DM*DFF);
    if (layer < 2)
      packconv<<<(3*DM*DM + 255)/256, 256, 0, stream>>>(dcw + (size_t)layer*DM*DM*3, wtap);

    // PRNG indices
    unsigned ka = 0u, kb2 = (unsigned)layer;
    tf2x32(0u, 42u, ka, kb2);
    unsigned a0 = 0u, a1 = 2u;  tf2x32(ka, kb2, a0, a1);
    unsigned c0 = 1u, c1 = 3u;  tf2x32(ka, kb2, c0, c1);
    int S2 = L * u / 2;
    idx_kernel<<<(S2 + 255)/256, 256, 0, stream>>>(idx_buf, a1, c1, S2, L-1);

    hipMemsetAsync(ctxt_all, 0, (size_t)B*8*u*64*sizeof(float), stream);

    // ---- attention per group: QKV gemms, selection, then batched S/softmax/PV ----
    int sg = SGtab[layer];
    for (int g = 0; g < nG; g++){
      const float* hg = h + (size_t)g*RG*DM;
      conv_b(hg, P0, (size_t)RG*DM);
      gemm(P0, wqb, bq_i, P1, RG, DM, DM, L, 0, 0, 0, 1);
      gemm(P0, wkb, bk_i, P2, RG, DM, DM, L, 0, 0, 0, 1);
      gemm(P0, wvb, bv_i, P3, RG, DM, DM, L, 0, 0, 0, 1);
      sample_m<<<(int)(((size_t)RG*8*64)/256), 256, 0, stream>>>(P1, P2, idx_buf, m_buf, L, u);
      int* top_g = top_all + (size_t)g*G*8*u;
      topk_kernel<<<G*8, 256, 0, stream>>>(m_buf, top_g, L, u);
      int nqr = G*8*u*DH;
      qred_kernel<<<(nqr + 255)/256, 256, 0, stream>>>(P1, top_g, qred_loc, L, u, nqr);

      float* Sbuf = (float*)P0;          // hgb no longer needed
      int nsub = G / sg;
      for (int s = 0; s < nsub; s++){
        const float* qr = qred_loc + (size_t)s*sg*8*u*64;
        const unsigned short* kb_ = P2 + (size_t)s*sg*L*DM;
        const unsigned short* vb_ = P3 + (size_t)s*sg*L*DM;
        float* ct = ctxt_all + (size_t)(g*G + s*sg)*8*u*64;
        qk_scores<<<dim3(L/256, sg*8), 256, 0, stream>>>(qr, kb_, Sbuf, L, u);
        softmax_rows<<<sg*8*u, 256, 0, stream>>>(Sbuf, L);
        pv_kernel<<<dim3(L/PVKT, sg*8), 256, 0, stream>>>(Sbuf, vb_, ct, L, u);
      }
    }

    // vmean = (mean_L h)@wv^T + bv ; cw = vmean@wo^T + bo (exact fp32 identity)
    colmean_kernel<<<B*DM/256, 256, 0, stream>>>(h, hm, L);
    tiny_gemm<<<B, 256, 0, stream>>>(hm, wv_i, bv_i, vmean, DM, DM);
    tiny_gemm<<<B, 256, 0, stream>>>(vmean, wo_i, bo_i, cw, DM, DM);

    addcw_kernel<<<(int)(((size_t)M*DM)/256), 256, 0, stream>>>(h, cw, L);
    scatter_delta<<<B*8*u, 256, 0, stream>>>(ctxt_all, vmean, wo_i, top_all, h, L, u);

    // ---- FFN: y(P0 bf16) -> mid(P1+P2 bf16) -> y2(P0+RF*DM bf16) -> LN2 ----
    unsigned short* ybuf = P0;
    unsigned short* mid  = P1;
    unsigned short* y2b  = P0 + (size_t)RF*DM;
    const float* l1g = ln1g + (size_t)layer*DM; const float* l1b = ln1b + (size_t)layer*DM;
    const float* l2g = ln2g + (size_t)layer*DM; const float* l2b = ln2b + (size_t)layer*DM;
    for (int r0 = 0; r0 < M; r0 += RF){
      ln_kernel<<<RF, 256, 0, stream>>>(h + (size_t)r0*DM, nullptr, 0, l1g, l1b, ybuf, 1);
      gemm(ybuf, w1b, b1_i, mid, RF, DFF, DM, L, 0, 0, 1, 1);
      gemm(mid, w2b, b2_i, y2b, RF, DM, DFF, L, 0, 0, 0, 1);
      ln_kernel<<<RF, 256, 0, stream>>>(h + (size_t)r0*DM, y2b, 1, l2g, l2b, h + (size_t)r0*DM, 0);
    }

    // ---- conv + BN + ELU + pool (two passes per group; bf16 taps, fp32 out) ----
    if (layer < 2){
      const float* db = dcb + (size_t)layer*DM;
      float* convf = (float*)P1;   // RG x DM fp32 spans P1+P2
      for (int g = 0; g < nG; g++){
        const float* hg = h + (size_t)g*RG*DM;
        conv_b(hg, P0, (size_t)RG*DM);
        gemm(P0, wtap + 0*DM*DM, db,      convf, RG, DM, DM, L, -1, 0, 0, 0);
        gemm(P0, wtap + 1*DM*DM, nullptr, convf, RG, DM, DM, L,  0, 1, 0, 0);
        gemm(P0, wtap + 2*DM*DM, nullptr, convf, RG, DM, DM, L, +1, 1, 0, 0);
        bnstat1<<<dim3(8, 32), 256, 0, stream>>>(convf, partS + (size_t)g*32*DM,
                                                 partQ + (size_t)g*32*DM, RG/32);
      }
      bnstat2<<<2, 256, 0, stream>>>(partS, partQ, stats, nG*32, M);
      int Lo = L/2;
      for (int g = 0; g < nG; g++){
        const float* hg = h + (size_t)g*RG*DM;
        conv_b(hg, P0, (size_t)RG*DM);
        gemm(P0, wtap + 0*DM*DM, db,      convf, RG, DM, DM, L, -1, 0, 0, 0);
        gemm(P0, wtap + 1*DM*DM, nullptr, convf, RG, DM, DM, L,  0, 1, 0, 0);
        gemm(P0, wtap + 2*DM*DM, nullptr, convf, RG, DM, DM, L, +1, 1, 0, 0);
        bnpool<<<(int)(((size_t)G*Lo*DM)/256), 256, 0, stream>>>(convf, stats,
            bng + (size_t)layer*DM, bnb + (size_t)layer*DM, h, L, Lo, g*G);
      }
      L = Lo;
    }
  }

  final_kernel<<<B, 128, 0, stream>>>(h, x, flg, flb, pw, pb, skw, skb, (float*)d_out, L, L0);
}

// Round 6
// 9603.748 us; speedup vs baseline: 4.7040x; 1.0752x over previous
//
#include <hip/hip_runtime.h>
#include <cmath>

#define DM 512
#define DH 64

typedef __attribute__((ext_vector_type(8))) short short8;
typedef __attribute__((ext_vector_type(4))) float float4v;

__device__ inline float b2f(unsigned short u){
  union{unsigned int i; float f;} z; z.i = ((unsigned)u)<<16; return z.f;
}
__device__ inline unsigned short f2b(float f){
  unsigned int x = __float_as_uint(f);
  return (unsigned short)((x + 0x7fffu + ((x>>16)&1u)) >> 16);   // RNE
}

#define GLL(gp, lp) __builtin_amdgcn_global_load_lds((const __attribute__((address_space(1))) void*)(gp), \
    (__attribute__((address_space(3))) void*)(lp), 16, 0, 0)

// ---------------- Threefry-2x32-20 (matches jax.random) ----------------
__host__ __device__ inline void tf2x32(unsigned k0, unsigned k1, unsigned& x0, unsigned& x1){
  const unsigned ks0=k0, ks1=k1, ks2=k0^k1^0x1BD11BDAu;
  x0 += ks0; x1 += ks1;
#define TF_ROT(r) { x0 += x1; x1 = (x1<<(r))|(x1>>(32-(r))); x1 ^= x0; }
  TF_ROT(13) TF_ROT(15) TF_ROT(26) TF_ROT(6)
  x0 += ks1; x1 += ks2 + 1u;
  TF_ROT(17) TF_ROT(29) TF_ROT(16) TF_ROT(24)
  x0 += ks2; x1 += ks0 + 2u;
  TF_ROT(13) TF_ROT(15) TF_ROT(26) TF_ROT(6)
  x0 += ks0; x1 += ks1 + 3u;
  TF_ROT(17) TF_ROT(29) TF_ROT(16) TF_ROT(24)
  x0 += ks1; x1 += ks2 + 4u;
  TF_ROT(13) TF_ROT(15) TF_ROT(26) TF_ROT(6)
  x0 += ks2; x1 += ks0 + 5u;
#undef TF_ROT
}

__global__ __launch_bounds__(256) void idx_kernel(int* __restrict__ idx, unsigned k2a, unsigned k2b,
                                                  int S2, int Lmask){
  int j = blockIdx.x*256 + threadIdx.x;
  if (j >= S2) return;
  unsigned x0 = (unsigned)j, x1 = (unsigned)(S2 + j);
  tf2x32(k2a, k2b, x0, x1);
  idx[j]      = (int)(x0 & (unsigned)Lmask);
  idx[S2 + j] = (int)(x1 & (unsigned)Lmask);
}

// ---------------- token embed: circular conv (7ch->512) + sinusoid PE ----------------
__global__ __launch_bounds__(256) void embed_kernel(const float* __restrict__ x, const float* __restrict__ tcw,
                                                    float* __restrict__ h, int L){
  size_t i = (size_t)blockIdx.x*256 + threadIdx.x;
  int d = (int)(i % DM);
  size_t r = i / DM;
  int l = (int)(r % L);
  int b = (int)(r / L);
  const float* xb = x + (size_t)b*L*7;
  float acc = 0.f;
#pragma unroll
  for (int kk=0; kk<3; kk++){
    int ls = l + kk - 1;
    ls = (ls < 0) ? ls + L : (ls >= L ? ls - L : ls);
    const float* xe = xb + (size_t)ls*7;
    const float* wp = tcw + (size_t)d*21 + kk;
#pragma unroll
    for (int c=0;c<7;c++) acc += xe[c]*wp[3*c];
  }
  const float scale = -0.017988946f;  // -ln(10000)/512
  float freq = expf((float)(d & ~1) * scale);
  float ang  = (float)l * freq;
  float pe   = (d & 1) ? cosf(ang) : sinf(ang);
  h[i] = acc + pe;
}

// ---------------- fp32 -> bf16 conversion (vectorized) ----------------
__global__ __launch_bounds__(256) void f2b_vec(const float* __restrict__ src, unsigned short* __restrict__ dst, int n4){
  int i = blockIdx.x*256 + threadIdx.x;
  if (i >= n4) return;
  float4 v = ((const float4*)src)[i];
  ushort4 o; o.x = f2b(v.x); o.y = f2b(v.y); o.z = f2b(v.z); o.w = f2b(v.w);
  ((ushort4*)dst)[i] = o;
}

// ---------------- pack conv weights along K: wtapK[n][tap*512+c] = dcw[n][c][tap] ----------------
__global__ __launch_bounds__(256) void packconv(const float* __restrict__ dcw, unsigned short* __restrict__ wtapK){
  int i = blockIdx.x*256 + threadIdx.x;
  if (i >= 3*DM*DM) return;
  int n = i / (3*DM); int rem = i % (3*DM); int tap = rem / DM; int c = rem % DM;
  wtapK[(size_t)n*(3*DM) + tap*DM + c] = f2b(dcw[((size_t)n*DM + c)*3 + tap]);
}

// ---------------- concat qkv bias ----------------
__global__ __launch_bounds__(256) void catb_kernel(const float* __restrict__ a, const float* __restrict__ b,
    const float* __restrict__ c, float* __restrict__ o){
  int i = blockIdx.x*256 + threadIdx.x;
  if (i >= 1536) return;
  o[i] = (i < 512) ? a[i] : (i < 1024 ? b[i-512] : c[i-1024]);
}

// =======================================================================
// bgemm2: bf16 MFMA GEMM, 128xTN tile, BK=64, double-buffered LDS staging.
// C = act(A@W^T + bias); convmode: K=1536 in 3 segments with circular row
// shift -1/0/+1 (depthwise conv as one GEMM); qkv: route 512-col groups to
// consecutive bufstride-sized buffers.
// =======================================================================
template<int TN>
__global__ __launch_bounds__(256) void bgemm2(const unsigned short* __restrict__ A,
    const unsigned short* __restrict__ Wb, const float* __restrict__ bias, void* __restrict__ C,
    int N, int K, int L, int convmode, int act, int outbf, int qkv, size_t bufstride){
  constexpr int NJ = TN/32;          // j-tiles per wave
  constexpr int BR = TN/32;          // B staging rounds
  __shared__ unsigned short As[2][128*64];
  __shared__ unsigned short Bs[2][TN*64];
  int tid = threadIdx.x;
  int w = tid >> 6, ln = tid & 63;
  int row0 = blockIdx.y*128, col0 = blockIdx.x*TN;
  int KA = convmode ? 512 : K;

  // per-thread staging descriptors
  long aBase[4], dPrev[4], dNext[4]; int aCol[4];
#pragma unroll
  for (int g=0; g<4; g++){
    int ch = g*256 + tid;
    int r = ch >> 3, c = ch & 7;
    int gc = c ^ (r & 7);
    int gr = row0 + r;
    aCol[g] = gc*8;
    aBase[g] = (long)gr * KA;
    if (convmode){
      int l = gr % L;
      dPrev[g] = (l==0)   ? (long)(L-1)*KA : -(long)KA;
      dNext[g] = (l==L-1) ? -(long)(L-1)*KA : (long)KA;
    } else { dPrev[g]=0; dNext[g]=0; }
  }
  long bBase[BR];
#pragma unroll
  for (int g=0; g<BR; g++){
    int ch = g*256 + tid;
    int r = ch >> 3, c = ch & 7;
    int gc = c ^ (r & 7);
    bBase[g] = (long)(col0 + r)*K + gc*8;
  }
  // fragment LDS row offsets (slots; xor applied at read time)
  int raBase[4], rbBase[NJ];
#pragma unroll
  for (int i=0;i<4;i++)  raBase[i] = ((w&1)*64 + i*16 + (ln&15))*8;
#pragma unroll
  for (int j=0;j<NJ;j++) rbBase[j] = ((w>>1)*(TN/2) + j*16 + (ln&15))*8;

  float4v acc[4][NJ] = {};
  int nIter = K/64;

  auto stage = [&](int buf, int it){
    int k0 = it*64;
    long dA = 0; int kk = k0;
    if (convmode){ int seg = k0>>9; kk = k0 & 511; dA = (seg==0)? 0 : 0;
      dA = (seg==0) ? dPrev[0] : (seg==2 ? dNext[0] : 0); }
#pragma unroll
    for (int g=0; g<4; g++){
      long d = 0;
      if (convmode){ int seg = k0>>9; d = (seg==0)? dPrev[g] : (seg==2 ? dNext[g] : 0); }
      GLL(A + aBase[g] + d + kk + aCol[g], (char*)As + buf*16384 + g*4096 + w*1024);
    }
#pragma unroll
    for (int g=0; g<BR; g++)
      GLL(Wb + bBase[g] + k0, (char*)Bs + buf*(TN*128) + g*4096 + w*1024);
  };

  stage(0, 0);
  int cur = 0;
  for (int it=0; it<nIter; it++){
    __syncthreads();                         // cur staged; prev compute done
    if (it+1 < nIter) stage(cur^1, it+1);    // async prefetch overlaps compute
    const char* ab = (const char*)As + cur*16384;
    const char* bb = (const char*)Bs + cur*(TN*128);
#pragma unroll
    for (int s=0;s<2;s++){
      int xs = (s*4 + (ln>>4)) ^ (ln&7);
      short8 af[4], bf[NJ];
#pragma unroll
      for (int i=0;i<4;i++)  af[i] = *(const short8*)(ab + (raBase[i] + xs)*16);
#pragma unroll
      for (int j=0;j<NJ;j++) bf[j] = *(const short8*)(bb + (rbBase[j] + xs)*16);
#pragma unroll
      for (int i=0;i<4;i++)
#pragma unroll
        for (int j=0;j<NJ;j++)
          acc[i][j] = __builtin_amdgcn_mfma_f32_16x16x32_bf16(af[i], bf[j], acc[i][j], 0, 0, 0);
    }
    cur ^= 1;
  }

  float* Cf = (float*)C;
  unsigned short* Cb = (unsigned short*)C;
  int colb0 = col0 + (w>>1)*(TN/2) + (ln & 15);
#pragma unroll
  for (int i=0;i<4;i++){
#pragma unroll
    for (int r=0;r<4;r++){
      int grow = row0 + (w&1)*64 + i*16 + (ln>>4)*4 + r;
#pragma unroll
      for (int j=0;j<NJ;j++){
        int colb = colb0 + j*16;
        float v = acc[i][j][r];
        if (bias) v += bias[colb];
        if (act)  v = 0.5f * v * (1.0f + erff(v * 0.70710678f));
        if (outbf){
          if (qkv){
            int bsel = colb >> 9;
            Cb[(size_t)bsel*bufstride + (size_t)grow*512 + (colb & 511)] = f2b(v);
          } else {
            Cb[(size_t)grow*N + colb] = f2b(v);
          }
        } else {
          Cf[(size_t)grow*N + colb] = v;
        }
      }
    }
  }
}

// ---------------- m = max_s - mean_s of sampled dots; q,k bf16 ----------------
__global__ __launch_bounds__(256) void sample_m(const unsigned short* __restrict__ q,
    const unsigned short* __restrict__ k, const int* __restrict__ idx, float* __restrict__ m, int L, int u){
  int w = (int)(((size_t)blockIdx.x*256 + threadIdx.x) >> 6);
  int lane = threadIdx.x & 63;
  int l = w % L; int hh = (w / L) & 7; int b = w / (L * 8);
  float qv = b2f(q[((size_t)b*L + l)*DM + hh*DH + lane]);
  const unsigned short* kb = k + (size_t)b*L*DM + hh*DH + lane;
  float mx = -1e30f, sum = 0.f;
  for (int s=0; s<u; s++){
    int kp = idx[l*u + s];
    float p = qv * b2f(kb[(size_t)kp*DM]);
#pragma unroll
    for (int off=32; off; off>>=1) p += __shfl_xor(p, off);
    mx = fmaxf(mx, p); sum += p;
  }
  if (lane == 0) m[((size_t)b*8 + hh)*L + l] = mx - sum/(float)u;
}

// ---------------- iterative top-u argmax per (b,h), min-index tie-break ----------------
__global__ __launch_bounds__(256) void topk_kernel(const float* __restrict__ m, int* __restrict__ top, int L, int u){
  int bh = blockIdx.x;
  const float* mm = m + (size_t)bh*L;
  __shared__ float vals[2048];
  __shared__ float rv[256];
  __shared__ int   ri[256];
  for (int i=threadIdx.x; i<L; i+=256) vals[i] = mm[i];
  __syncthreads();
  for (int it=0; it<u; it++){
    float bv = -1e30f; int bi = 0x7fffffff;
    for (int i=threadIdx.x; i<L; i+=256){
      float v = vals[i];
      if (v > bv || (v == bv && i < bi)) { bv = v; bi = i; }
    }
    rv[threadIdx.x] = bv; ri[threadIdx.x] = bi;
    __syncthreads();
    for (int s=128; s; s>>=1){
      if (threadIdx.x < s){
        float v = rv[threadIdx.x+s]; int i2 = ri[threadIdx.x+s];
        if (v > rv[threadIdx.x] || (v == rv[threadIdx.x] && i2 < ri[threadIdx.x])){
          rv[threadIdx.x] = v; ri[threadIdx.x] = i2;
        }
      }
      __syncthreads();
    }
    if (threadIdx.x == 0){ top[bh*u + it] = ri[0]; vals[ri[0]] = -1e31f; }
    __syncthreads();
  }
}

// ---------------- column mean over L rows per batch (fp32 h) ----------------
__global__ __launch_bounds__(256) void colmean_kernel(const float* __restrict__ src, float* __restrict__ dst, int L){
  int i = blockIdx.x*256 + threadIdx.x;   // B*DM
  int d = i % DM, b = i / DM;
  const float* p = src + (size_t)b*L*DM + d;
  float s = 0.f;
  for (int l=0; l<L; l++) s += p[(size_t)l*DM];
  dst[i] = s / (float)L;
}

// ---------------- tiny fp32 GEMM: one block per row ----------------
__global__ __launch_bounds__(256) void tiny_gemm(const float* __restrict__ A, const float* __restrict__ W,
    const float* __restrict__ bias, float* __restrict__ C, int N, int K){
  int row = blockIdx.x;
  const float* ar = A + (size_t)row*K;
  __shared__ float as[DM];
  for (int k=threadIdx.x; k<K; k+=256) as[k] = ar[k];
  __syncthreads();
  for (int n = threadIdx.x; n < N; n += 256){
    float acc = bias ? bias[n] : 0.f;
    const float* wr = W + (size_t)n*K;
    for (int k=0; k<K; k++) acc += as[k]*wr[k];
    C[(size_t)row*N + n] = acc;
  }
}

// ---------------- gather q rows for top queries (bf16 q -> fp32 qred) ----------------
__global__ __launch_bounds__(256) void qred_kernel(const unsigned short* __restrict__ q, const int* __restrict__ top,
    float* __restrict__ qred, int L, int u, int n){
  int i = blockIdx.x*256 + threadIdx.x;
  if (i >= n) return;
  int d = i & 63; int rest = i >> 6; int j = rest % u; int bh = rest / u;
  int hh = bh & 7; int b = bh >> 3;
  int pos = top[bh*u + j];
  qred[i] = b2f(q[((size_t)b*L + pos)*DM + hh*DH + d]);
}

// ---------------- batched scores: S[bh][m][key] = (qred . K)/8 ----------------
__global__ __launch_bounds__(256) void qk_scores(const float* __restrict__ qred,
    const unsigned short* __restrict__ kbuf, float* __restrict__ S, int L, int u){
  int bh = blockIdx.y; int b = bh >> 3, h = bh & 7;
  int key = blockIdx.x*256 + threadIdx.x;
  __shared__ float Qs[38*64];
  int t = threadIdx.x;
  for (int i = t; i < u*64; i += 256) Qs[i] = qred[(size_t)bh*u*64 + i];
  __syncthreads();
  const unsigned short* krow = kbuf + ((size_t)(b*L + key))*DM + h*DH;
  float kr[64];
#pragma unroll
  for (int c=0;c<8;c++){
    uint4 kk = *(const uint4*)(krow + c*8);
    kr[c*8+0]=b2f((unsigned short)(kk.x&0xffff)); kr[c*8+1]=b2f((unsigned short)(kk.x>>16));
    kr[c*8+2]=b2f((unsigned short)(kk.y&0xffff)); kr[c*8+3]=b2f((unsigned short)(kk.y>>16));
    kr[c*8+4]=b2f((unsigned short)(kk.z&0xffff)); kr[c*8+5]=b2f((unsigned short)(kk.z>>16));
    kr[c*8+6]=b2f((unsigned short)(kk.w&0xffff)); kr[c*8+7]=b2f((unsigned short)(kk.w>>16));
  }
  float* srow = S + (size_t)bh*u*L + key;
  for (int m = 0; m < u; m++){
    const float4* q4 = (const float4*)(Qs + m*64);
    float acc = 0.f;
#pragma unroll
    for (int c=0;c<16;c++){
      float4 qv = q4[c];
      acc += qv.x*kr[c*4] + qv.y*kr[c*4+1] + qv.z*kr[c*4+2] + qv.w*kr[c*4+3];
    }
    srow[(size_t)m*L] = acc * 0.125f;
  }
}

// ---------------- softmax over each score row, in place ----------------
__global__ __launch_bounds__(256) void softmax_rows(float* __restrict__ S, int L){
  size_t row = blockIdx.x;
  float* r = S + row*(size_t)L;
  int t = threadIdx.x;
  __shared__ float red[8];
  float mx = -1e30f;
  for (int i=t;i<L;i+=256) mx = fmaxf(mx, r[i]);
#pragma unroll
  for (int off=32; off; off>>=1) mx = fmaxf(mx, __shfl_xor(mx, off));
  if ((t&63)==0) red[t>>6] = mx;
  __syncthreads();
  mx = fmaxf(fmaxf(red[0],red[1]), fmaxf(red[2],red[3]));
  float sum = 0.f;
  for (int i=t;i<L;i+=256){ float e = expf(r[i]-mx); r[i] = e; sum += e; }
#pragma unroll
  for (int off=32; off; off>>=1) sum += __shfl_xor(sum, off);
  if ((t&63)==0) red[4+(t>>6)] = sum;
  __syncthreads();
  float inv = 1.f/(red[4]+red[5]+red[6]+red[7]);
  for (int i=t;i<L;i+=256) r[i] *= inv;
}

// ---------------- ctx += P @ V over a key tile; V staged in LDS ----------------
#define PVKT 256
__global__ __launch_bounds__(256) void pv_kernel(const float* __restrict__ P,
    const unsigned short* __restrict__ vbuf, float* __restrict__ ctxt, int L, int u){
  int bh = blockIdx.y; int b = bh >> 3, h = bh & 7;
  int k0 = blockIdx.x*PVKT;
  int t = threadIdx.x;
  __shared__ unsigned short Vs[PVKT*64];
  for (int e = t*8; e < PVKT*64; e += 2048){
    int k = e>>6, d = e&63;
    *(uint4*)(Vs + e) = *(const uint4*)(vbuf + ((size_t)(b*L + k0 + k))*DM + h*DH + d);
  }
  __syncthreads();
  int n = t & 63, mg = t >> 6;
  for (int m = mg; m < u; m += 4){
    const float* prow = P + ((size_t)bh*u + m)*L + k0;
    float acc = 0.f;
    for (int k=0;k<PVKT;k+=4){
      float4 p4 = *(const float4*)(prow + k);
      acc += p4.x*b2f(Vs[(k+0)*64+n]);
      acc += p4.y*b2f(Vs[(k+1)*64+n]);
      acc += p4.z*b2f(Vs[(k+2)*64+n]);
      acc += p4.w*b2f(Vs[(k+3)*64+n]);
    }
    atomicAdd(&ctxt[((size_t)bh*u + m)*64 + n], acc);
  }
}

// ---------------- sparse correction: h[b,pos] += (ctxt - vmean_slice)@wo_slice^T ----------------
__global__ __launch_bounds__(256) void scatter_delta(const float* __restrict__ ctxt, const float* __restrict__ vmean,
    const float* __restrict__ wo, const int* __restrict__ top, float* __restrict__ h, int L, int u){
  int bid = blockIdx.x;
  int j = bid % u; int bh = bid / u; int hh = bh & 7; int b = bh >> 3;
  int pos = top[bh*u + j];
  __shared__ float delta[DH];
  int t = threadIdx.x;
  if (t < DH) delta[t] = ctxt[(size_t)(bh*u + j)*DH + t] - vmean[b*DM + hh*DH + t];
  __syncthreads();
  float* hrow = h + ((size_t)b*L + pos)*DM;
  const float* wbase = wo + hh*DH;
  for (int n = t; n < DM; n += 256){
    float acc = 0.f;
    const float* wr = wbase + (size_t)n*DM;
#pragma unroll
    for (int dd=0; dd<DH; dd++) acc += delta[dd] * wr[dd];
    atomicAdd(&hrow[n], acc);
  }
}

// ---------------- LayerNorm D=512; optional +cw[b], +Yadd; out fp32/bf16 ----------------
__global__ __launch_bounds__(256) void ln_kernel(const float* __restrict__ X, const void* __restrict__ Yadd,
    int yb, const float* __restrict__ g, const float* __restrict__ bta, void* __restrict__ Out, int ob,
    const float* __restrict__ cwv, int Lrow, int row0g){
  size_t row = blockIdx.x;
  const float* xr = X + row*DM;
  int t = threadIdx.x;
  float v0 = xr[t], v1 = xr[t+256];
  if (cwv){
    int b = (int)((row0g + (int)row) / Lrow);
    v0 += cwv[b*DM + t]; v1 += cwv[b*DM + t+256];
  }
  if (Yadd){
    if (yb){ const unsigned short* yr = (const unsigned short*)Yadd + row*DM; v0 += b2f(yr[t]); v1 += b2f(yr[t+256]); }
    else   { const float* yr = (const float*)Yadd + row*DM; v0 += yr[t]; v1 += yr[t+256]; }
  }
  float s = v0+v1, q = v0*v0+v1*v1;
#pragma unroll
  for (int off=32; off; off>>=1){ s += __shfl_xor(s,off); q += __shfl_xor(q,off); }
  __shared__ float ss[4], qq[4];
  int w = t >> 6;
  if ((t & 63) == 0){ ss[w] = s; qq[w] = q; }
  __syncthreads();
  s = ss[0]+ss[1]+ss[2]+ss[3]; q = qq[0]+qq[1]+qq[2]+qq[3];
  float mu  = s * (1.0f/DM);
  float var = q * (1.0f/DM) - mu*mu;
  float r = rsqrtf(var + 1e-5f);
  float o0 = (v0 - mu)*r*g[t]     + bta[t];
  float o1 = (v1 - mu)*r*g[t+256] + bta[t+256];
  if (ob){
    unsigned short* Ob = (unsigned short*)Out;
    Ob[row*DM + t] = f2b(o0); Ob[row*DM + t+256] = f2b(o1);
  } else {
    float* Of = (float*)Out;
    Of[row*DM + t] = o0; Of[row*DM + t+256] = o1;
  }
}

// ---------------- BN partial sums (grid: 8 x 32) ----------------
__global__ __launch_bounds__(256) void bnstat1(const float* __restrict__ C, float* __restrict__ partS,
                                               float* __restrict__ partQ, int rpb){
  int chb = blockIdx.x;
  int mb  = blockIdx.y;
  int g = threadIdx.x >> 6, c = threadIdx.x & 63;
  int ch = chb*64 + c;
  float s = 0.f, q = 0.f;
  int r0 = mb * rpb;
  for (int r = r0 + g; r < r0 + rpb; r += 4){
    float v = C[(size_t)r*DM + ch]; s += v; q += v*v;
  }
  __shared__ float ls[4][64], lq[4][64];
  ls[g][c] = s; lq[g][c] = q;
  __syncthreads();
  if (g == 0){
    s = ls[0][c]+ls[1][c]+ls[2][c]+ls[3][c];
    q = lq[0][c]+lq[1][c]+lq[2][c]+lq[3][c];
    partS[(size_t)mb*DM + ch] = s;
    partQ[(size_t)mb*DM + ch] = q;
  }
}
__global__ __launch_bounds__(256) void bnstat2(const float* __restrict__ partS, const float* __restrict__ partQ,
                                               float* __restrict__ stats, int NB, int M){
  int ch = blockIdx.x*256 + threadIdx.x;
  if (ch >= DM) return;
  float s = 0.f, q = 0.f;
  for (int mb=0; mb<NB; mb++){
    s += partS[(size_t)mb*DM + ch];
    q += partQ[(size_t)mb*DM + ch];
  }
  float mu = s / (float)M;
  stats[ch] = mu;
  stats[DM + ch] = q / (float)M - mu*mu;
}

// ---------------- BN + ELU + maxpool(3,2); group-local C, global Out ----------------
__global__ __launch_bounds__(256) void bnpool(const float* __restrict__ C, const float* __restrict__ stats,
    const float* __restrict__ g, const float* __restrict__ bta, float* __restrict__ Out,
    int L, int Lo, int gbase){
  size_t i = (size_t)blockIdx.x*256 + threadIdx.x;
  int ch = (int)(i % DM);
  size_t r = i / DM;
  int lo = (int)(r % Lo);
  int bl = (int)(r / Lo);
  float mu = stats[ch];
  float rstd = rsqrtf(stats[DM+ch] + 1e-5f);
  float gg = g[ch], bb = bta[ch];
  float best = -1e30f;
#pragma unroll
  for (int t=-1; t<=1; t++){
    int li = 2*lo + t;
    if (li >= 0 && li < L){
      float v = (C[((size_t)bl*L + li)*DM + ch] - mu)*rstd*gg + bb;
      v = v > 0.f ? v : expm1f(v);
      best = fmaxf(best, v);
    }
  }
  Out[((size_t)(gbase + bl)*Lo + lo)*DM + ch] = best;
}

// ---------------- final: LN(last row) @ proj^T + proj_b + skip ----------------
__global__ __launch_bounds__(128) void final_kernel(const float* __restrict__ h, const float* __restrict__ x,
    const float* __restrict__ fg, const float* __restrict__ fb, const float* __restrict__ pw,
    const float* __restrict__ pb, const float* __restrict__ sw, const float* __restrict__ sb,
    float* __restrict__ out, int Lf, int L0){
  int b = blockIdx.x;
  const float* row = h + ((size_t)b*Lf + (Lf-1))*DM;
  __shared__ float xn[DM];
  __shared__ float rs[2], rq[2];
  int t = threadIdx.x;
  float v[4]; float s = 0.f, q = 0.f;
#pragma unroll
  for (int i=0;i<4;i++){ v[i] = row[t + i*128]; s += v[i]; q += v[i]*v[i]; }
#pragma unroll
  for (int off=32; off; off>>=1){ s += __shfl_xor(s,off); q += __shfl_xor(q,off); }
  if ((t & 63) == 0){ rs[t>>6] = s; rq[t>>6] = q; }
  __syncthreads();
  s = rs[0]+rs[1]; q = rq[0]+rq[1];
  float mu = s*(1.0f/DM), var = q*(1.0f/DM) - mu*mu;
  float r = rsqrtf(var + 1e-5f);
#pragma unroll
  for (int i=0;i<4;i++){ int d = t + i*128; xn[d] = (v[i]-mu)*r*fg[d] + fb[d]; }
  __syncthreads();
  if (t < 96){
    float acc = pb[t] + sb[t];
    const float* xr = x + ((size_t)b*L0 + (L0-1))*7;
#pragma unroll
    for (int c=0;c<7;c++) acc += xr[c]*sw[t*7+c];
    for (int d=0; d<DM; d++) acc += xn[d]*pw[(size_t)t*DM + d];
    out[b*96 + t] = acc;
  }
}

// =======================================================================
extern "C" void kernel_launch(void* const* d_in, const int* in_sizes, int n_in,
                              void* d_out, int out_size, void* d_ws, size_t ws_size,
                              hipStream_t stream){
  const float* x    = (const float*)d_in[0];
  const float* skw  = (const float*)d_in[1];
  const float* skb  = (const float*)d_in[2];
  const float* tcw  = (const float*)d_in[3];
  const float* wq   = (const float*)d_in[4];
  const float* bq   = (const float*)d_in[5];
  const float* wk   = (const float*)d_in[6];
  const float* bk   = (const float*)d_in[7];
  const float* wv   = (const float*)d_in[8];
  const float* bv   = (const float*)d_in[9];
  const float* wo   = (const float*)d_in[10];
  const float* bo   = (const float*)d_in[11];
  const float* w1   = (const float*)d_in[12];
  const float* b1   = (const float*)d_in[13];
  const float* w2   = (const float*)d_in[14];
  const float* b2   = (const float*)d_in[15];
  const float* ln1g = (const float*)d_in[16];
  const float* ln1b = (const float*)d_in[17];
  const float* ln2g = (const float*)d_in[18];
  const float* ln2b = (const float*)d_in[19];
  const float* dcw  = (const float*)d_in[20];
  const float* dcb  = (const float*)d_in[21];
  const float* bng  = (const float*)d_in[22];
  const float* bnb  = (const float*)d_in[23];
  const float* flg  = (const float*)d_in[24];
  const float* flb  = (const float*)d_in[25];
  const float* pw   = (const float*)d_in[26];
  const float* pb   = (const float*)d_in[27];

  const int B = 32, L0 = 2048, DFF = 2048;
  const int RG = 16384;                // rows per attention/conv group
  const int RF = 8192;                 // rows per FFN chunk
  char* ws = (char*)d_ws;
  const size_t SZH  = (size_t)B*L0*DM*sizeof(float);        // 134.2 MB
  const size_t SLOT = (size_t)RG*DM*sizeof(unsigned short); // 16.78 MB

  const size_t WBSZ = (size_t)(3*DM*DM + 2*DFF*DM + 3*DM*DM)*2;  // 7.34 MB
  size_t small_bytes = (size_t)L0*40*4          // idx_buf
                     + (size_t)RG*8*4           // m_buf
                     + (size_t)B*8*40*4         // top_all
                     + (size_t)32*8*40*64*4     // qred_loc
                     + (size_t)32*8*40*64*4     // ctxt_all
                     + 3*(size_t)B*DM*4         // hm, vmean, cw
                     + 2*(size_t)4*32*DM*4      // partS, partQ
                     + (size_t)2*DM*4           // stats
                     + (size_t)1536*4;          // bqkv
  if (ws_size < SZH + 4*SLOT + WBSZ + small_bytes) return;   // clean fail, not fault

  float*          h   = (float*)(ws);
  unsigned short* P0  = (unsigned short*)(ws + SZH);               // hgb / S / y+y2
  unsigned short* P1  = (unsigned short*)(ws + SZH + SLOT);        // q / mid / convf
  unsigned short* P2  = (unsigned short*)(ws + SZH + 2*SLOT);      // k / mid / convf
  unsigned short* P3  = (unsigned short*)(ws + SZH + 3*SLOT);      // v
  unsigned short* wb  = (unsigned short*)(ws + SZH + 4*SLOT);      // bf16 weights
  unsigned short* wqb = wb;                                        // [wq|wk|wv] contiguous
  unsigned short* w1b = wqb + (size_t)3*DM*DM;
  unsigned short* w2b = w1b + (size_t)DFF*DM;
  unsigned short* wtapK= w2b + (size_t)DM*DFF;                     // 512 x 1536
  char* sm = ws + SZH + 4*SLOT + WBSZ;
  int*   idx_buf  = (int*)sm;
  float* m_buf    = (float*)(sm + (size_t)L0*40*4);
  int*   top_all  = (int*)((char*)m_buf + (size_t)RG*8*4);
  float* qred_loc = (float*)((char*)top_all + (size_t)B*8*40*4);
  float* ctxt_all = qred_loc + (size_t)32*8*40*64;
  float* hm       = ctxt_all + (size_t)32*8*40*64;
  float* vmean    = hm + (size_t)B*DM;
  float* cw       = vmean + (size_t)B*DM;
  float* partS    = cw + (size_t)B*DM;
  float* partQ    = partS + (size_t)4*32*DM;
  float* stats    = partQ + (size_t)4*32*DM;
  float* bqkv     = stats + (size_t)2*DM;

  auto conv_b = [&](const float* src, unsigned short* dst, size_t n){
    f2b_vec<<<(int)((n/4 + 255)/256), 256, 0, stream>>>(src, dst, (int)(n/4));
  };

  // 1. token conv + positional embedding
  embed_kernel<<<(int)(((size_t)B*L0*DM)/256), 256, 0, stream>>>(x, tcw, h, L0);

  int L = L0;
  const int SGtab[3] = {4, 8, 16};
  for (int layer = 0; layer < 3; layer++){
    int M = B * L;
    int u = (int)(5.0 * log((double)L + 1.0));   // 38 / 34 / 31
    int G = RG / L;                              // batches per group: 8 / 16 / 32
    int nG = M / RG;                             // groups: 4 / 2 / 1
    const float* wv_i = wv + (size_t)layer*DM*DM;  const float* bv_i = bv + (size_t)layer*DM;
    const float* wo_i = wo + (size_t)layer*DM*DM;  const float* bo_i = bo + (size_t)layer*DM;
    const float* b1_i = b1 + (size_t)layer*DFF;
    const float* b2_i = b2 + (size_t)layer*DM;

    // weights -> bf16 (wq|wk|wv contiguous for fused QKV)
    conv_b(wq + (size_t)layer*DM*DM, wqb,                    (size_t)DM*DM);
    conv_b(wk + (size_t)layer*DM*DM, wqb + (size_t)DM*DM,    (size_t)DM*DM);
    conv_b(wv_i,                     wqb + (size_t)2*DM*DM,  (size_t)DM*DM);
    conv_b(w1 + (size_t)layer*DFF*DM, w1b, (size_t)DFF*DM);
    conv_b(w2 + (size_t)layer*DM*DFF, w2b, (size_t)DM*DFF);
    catb_kernel<<<6, 256, 0, stream>>>(bq + (size_t)layer*DM, bk + (size_t)layer*DM, bv_i, bqkv);
    if (layer < 2)
      packconv<<<(3*DM*DM + 255)/256, 256, 0, stream>>>(dcw + (size_t)layer*DM*DM*3, wtapK);

    // PRNG indices
    unsigned ka = 0u, kb2 = (unsigned)layer;
    tf2x32(0u, 42u, ka, kb2);
    unsigned a0 = 0u, a1 = 2u;  tf2x32(ka, kb2, a0, a1);
    unsigned c0 = 1u, c1 = 3u;  tf2x32(ka, kb2, c0, c1);
    int S2 = L * u / 2;
    idx_kernel<<<(S2 + 255)/256, 256, 0, stream>>>(idx_buf, a1, c1, S2, L-1);

    hipMemsetAsync(ctxt_all, 0, (size_t)B*8*u*64*sizeof(float), stream);

    // ---- attention per group: fused QKV, selection, batched S/softmax/PV ----
    int sg = SGtab[layer];
    for (int g = 0; g < nG; g++){
      const float* hg = h + (size_t)g*RG*DM;
      conv_b(hg, P0, (size_t)RG*DM);
      bgemm2<128><<<dim3(12, RG/128), 256, 0, stream>>>(P0, wqb, bqkv, P1,
          1536, 512, L, 0, 0, 1, 1, (size_t)RG*DM);
      sample_m<<<(int)(((size_t)RG*8*64)/256), 256, 0, stream>>>(P1, P2, idx_buf, m_buf, L, u);
      int* top_g = top_all + (size_t)g*G*8*u;
      topk_kernel<<<G*8, 256, 0, stream>>>(m_buf, top_g, L, u);
      int nqr = G*8*u*DH;
      qred_kernel<<<(nqr + 255)/256, 256, 0, stream>>>(P1, top_g, qred_loc, L, u, nqr);

      float* Sbuf = (float*)P0;
      int nsub = G / sg;
      for (int s = 0; s < nsub; s++){
        const float* qr = qred_loc + (size_t)s*sg*8*u*64;
        const unsigned short* kb_ = P2 + (size_t)s*sg*L*DM;
        const unsigned short* vb_ = P3 + (size_t)s*sg*L*DM;
        float* ct = ctxt_all + (size_t)(g*G + s*sg)*8*u*64;
        qk_scores<<<dim3(L/256, sg*8), 256, 0, stream>>>(qr, kb_, Sbuf, L, u);
        softmax_rows<<<sg*8*u, 256, 0, stream>>>(Sbuf, L);
        pv_kernel<<<dim3(L/PVKT, sg*8), 256, 0, stream>>>(Sbuf, vb_, ct, L, u);
      }
    }

    // vmean = (mean_L h)@wv^T + bv ; cw = vmean@wo^T + bo (exact fp32 identity)
    colmean_kernel<<<B*DM/256, 256, 0, stream>>>(h, hm, L);
    tiny_gemm<<<B, 256, 0, stream>>>(hm, wv_i, bv_i, vmean, DM, DM);
    tiny_gemm<<<B, 256, 0, stream>>>(vmean, wo_i, bo_i, cw, DM, DM);

    // sparse residual deltas (cw broadcast is folded into the FFN layernorms)
    scatter_delta<<<B*8*u, 256, 0, stream>>>(ctxt_all, vmean, wo_i, top_all, h, L, u);

    // ---- FFN: y(P0 bf16) -> mid(P1+P2 bf16) -> y2(P0+RF*DM bf16) -> LN2 ----
    unsigned short* ybuf = P0;
    unsigned short* mid  = P1;
    unsigned short* y2b  = P0 + (size_t)RF*DM;
    const float* l1g = ln1g + (size_t)layer*DM; const float* l1b = ln1b + (size_t)layer*DM;
    const float* l2g = ln2g + (size_t)layer*DM; const float* l2b = ln2b + (size_t)layer*DM;
    for (int r0 = 0; r0 < M; r0 += RF){
      ln_kernel<<<RF, 256, 0, stream>>>(h + (size_t)r0*DM, nullptr, 0, l1g, l1b, ybuf, 1, cw, L, r0);
      bgemm2<128><<<dim3(16, RF/128), 256, 0, stream>>>(ybuf, w1b, b1_i, mid,
          2048, 512, L, 0, 1, 1, 0, 0);
      bgemm2<64><<<dim3(8, RF/128), 256, 0, stream>>>(mid, w2b, b2_i, y2b,
          512, 2048, L, 0, 0, 1, 0, 0);
      ln_kernel<<<RF, 256, 0, stream>>>(h + (size_t)r0*DM, y2b, 1, l2g, l2b, h + (size_t)r0*DM, 0, cw, L, r0);
    }

    // ---- conv (fused 3-tap, K=1536) + BN + ELU + pool ----
    if (layer < 2){
      const float* db = dcb + (size_t)layer*DM;
      float* convf = (float*)P1;   // RG x DM fp32 spans P1+P2
      for (int g = 0; g < nG; g++){
        const float* hg = h + (size_t)g*RG*DM;
        conv_b(hg, P0, (size_t)RG*DM);
        bgemm2<64><<<dim3(8, RG/128), 256, 0, stream>>>(P0, wtapK, db, convf,
            512, 1536, L, 1, 0, 0, 0, 0);
        bnstat1<<<dim3(8, 32), 256, 0, stream>>>(convf, partS + (size_t)g*32*DM,
                                                 partQ + (size_t)g*32*DM, RG/32);
      }
      bnstat2<<<2, 256, 0, stream>>>(partS, partQ, stats, nG*32, M);
      int Lo = L/2;
      for (int g = 0; g < nG; g++){
        const float* hg = h + (size_t)g*RG*DM;
        conv_b(hg, P0, (size_t)RG*DM);
        bgemm2<64><<<dim3(8, RG/128), 256, 0, stream>>>(P0, wtapK, db, convf,
            512, 1536, L, 1, 0, 0, 0, 0);
        bnpool<<<(int)(((size_t)G*Lo*DM)/256), 256, 0, stream>>>(convf, stats,
            bng + (size_t)layer*DM, bnb + (size_t)layer*DM, h, L, Lo, g*G);
      }
      L = Lo;
    }
  }

  final_kernel<<<B, 128, 0, stream>>>(h, x, flg, flb, pw, pb, skw, skb, (float*)d_out, L, L0);
}

// Round 7
// 6497.457 us; speedup vs baseline: 6.9529x; 1.4781x over previous
//
#include <hip/hip_runtime.h>
#include <cmath>

#define DM 512
#define DH 64

typedef __attribute__((ext_vector_type(8))) short short8;
typedef __attribute__((ext_vector_type(4))) float float4v;

__device__ inline float b2f(unsigned short u){
  union{unsigned int i; float f;} z; z.i = ((unsigned)u)<<16; return z.f;
}
__device__ inline unsigned short f2b(float f){
  unsigned int x = __float_as_uint(f);
  return (unsigned short)((x + 0x7fffu + ((x>>16)&1u)) >> 16);   // RNE
}

#define GLL(gp, lp) __builtin_amdgcn_global_load_lds((const __attribute__((address_space(1))) void*)(gp), \
    (__attribute__((address_space(3))) void*)(lp), 16, 0, 0)

// ---------------- Threefry-2x32-20 (matches jax.random) ----------------
__host__ __device__ inline void tf2x32(unsigned k0, unsigned k1, unsigned& x0, unsigned& x1){
  const unsigned ks0=k0, ks1=k1, ks2=k0^k1^0x1BD11BDAu;
  x0 += ks0; x1 += ks1;
#define TF_ROT(r) { x0 += x1; x1 = (x1<<(r))|(x1>>(32-(r))); x1 ^= x0; }
  TF_ROT(13) TF_ROT(15) TF_ROT(26) TF_ROT(6)
  x0 += ks1; x1 += ks2 + 1u;
  TF_ROT(17) TF_ROT(29) TF_ROT(16) TF_ROT(24)
  x0 += ks2; x1 += ks0 + 2u;
  TF_ROT(13) TF_ROT(15) TF_ROT(26) TF_ROT(6)
  x0 += ks0; x1 += ks1 + 3u;
  TF_ROT(17) TF_ROT(29) TF_ROT(16) TF_ROT(24)
  x0 += ks1; x1 += ks2 + 4u;
  TF_ROT(13) TF_ROT(15) TF_ROT(26) TF_ROT(6)
  x0 += ks2; x1 += ks0 + 5u;
#undef TF_ROT
}

__global__ __launch_bounds__(256) void idx_kernel(int* __restrict__ idx, unsigned k2a, unsigned k2b,
                                                  int S2, int Lmask){
  int j = blockIdx.x*256 + threadIdx.x;
  if (j >= S2) return;
  unsigned x0 = (unsigned)j, x1 = (unsigned)(S2 + j);
  tf2x32(k2a, k2b, x0, x1);
  idx[j]      = (int)(x0 & (unsigned)Lmask);
  idx[S2 + j] = (int)(x1 & (unsigned)Lmask);
}

// ---------------- token embed: circular conv (7ch->512) + sinusoid PE ----------------
__global__ __launch_bounds__(256) void embed_kernel(const float* __restrict__ x, const float* __restrict__ tcw,
                                                    float* __restrict__ h, int L){
  size_t i = (size_t)blockIdx.x*256 + threadIdx.x;
  int d = (int)(i % DM);
  size_t r = i / DM;
  int l = (int)(r % L);
  int b = (int)(r / L);
  const float* xb = x + (size_t)b*L*7;
  float acc = 0.f;
#pragma unroll
  for (int kk=0; kk<3; kk++){
    int ls = l + kk - 1;
    ls = (ls < 0) ? ls + L : (ls >= L ? ls - L : ls);
    const float* xe = xb + (size_t)ls*7;
    const float* wp = tcw + (size_t)d*21 + kk;
#pragma unroll
    for (int c=0;c<7;c++) acc += xe[c]*wp[3*c];
  }
  const float scale = -0.017988946f;  // -ln(10000)/512
  float freq = expf((float)(d & ~1) * scale);
  float ang  = (float)l * freq;
  float pe   = (d & 1) ? cosf(ang) : sinf(ang);
  h[i] = acc + pe;
}

// ---------------- fp32 -> bf16 conversion (vectorized) ----------------
__global__ __launch_bounds__(256) void f2b_vec(const float* __restrict__ src, unsigned short* __restrict__ dst, int n4){
  int i = blockIdx.x*256 + threadIdx.x;
  if (i >= n4) return;
  float4 v = ((const float4*)src)[i];
  ushort4 o; o.x = f2b(v.x); o.y = f2b(v.y); o.z = f2b(v.z); o.w = f2b(v.w);
  ((ushort4*)dst)[i] = o;
}

// ---------------- pack conv weights along K: wtapK[n][tap*512+c] = dcw[n][c][tap] ----------------
__global__ __launch_bounds__(256) void packconv(const float* __restrict__ dcw, unsigned short* __restrict__ wtapK){
  int i = blockIdx.x*256 + threadIdx.x;
  if (i >= 3*DM*DM) return;
  int n = i / (3*DM); int rem = i % (3*DM); int tap = rem / DM; int c = rem % DM;
  wtapK[(size_t)n*(3*DM) + tap*DM + c] = f2b(dcw[((size_t)n*DM + c)*3 + tap]);
}

// ---------------- concat qkv bias ----------------
__global__ __launch_bounds__(256) void catb_kernel(const float* __restrict__ a, const float* __restrict__ b,
    const float* __restrict__ c, float* __restrict__ o){
  int i = blockIdx.x*256 + threadIdx.x;
  if (i >= 1536) return;
  o[i] = (i < 512) ? a[i] : (i < 1024 ? b[i-512] : c[i-1024]);
}

// =======================================================================
// bgemm2: bf16 MFMA GEMM, 128xTN tile, BK=64, SINGLE-buffered LDS staging
// (m97 structure — occupancy-driven inter-block overlap, 24-32KB LDS).
// convmode: K=1536 = 3 taps with circular row shift. qkv: route 512-col
// groups to consecutive bufstride-spaced buffers.
// =======================================================================
template<int TN>
__global__ __launch_bounds__(256) void bgemm2(const unsigned short* __restrict__ A,
    const unsigned short* __restrict__ Wb, const float* __restrict__ bias, void* __restrict__ C,
    int N, int K, int L, int convmode, int act, int outbf, int qkv, size_t bufstride){
  constexpr int NJ = TN/32;
  constexpr int BR = TN/32;
  __shared__ unsigned short As[128*64];   // 16 KB
  __shared__ unsigned short Bs[TN*64];    // 16/8 KB
  int tid = threadIdx.x;
  int w = tid >> 6, ln = tid & 63;
  int row0 = blockIdx.y*128, col0 = blockIdx.x*TN;
  int KA = convmode ? 512 : K;

  long aBase[4], dPrev[4], dNext[4]; int aCol[4];
#pragma unroll
  for (int g=0; g<4; g++){
    int ch = g*256 + tid;
    int r = ch >> 3, c = ch & 7;
    int gc = c ^ (r & 7);
    int gr = row0 + r;
    aCol[g] = gc*8;
    aBase[g] = (long)gr * KA;
    if (convmode){
      int l = gr % L;
      dPrev[g] = (l==0)   ? (long)(L-1)*KA : -(long)KA;
      dNext[g] = (l==L-1) ? -(long)(L-1)*KA : (long)KA;
    } else { dPrev[g]=0; dNext[g]=0; }
  }
  long bBase[BR];
#pragma unroll
  for (int g=0; g<BR; g++){
    int ch = g*256 + tid;
    int r = ch >> 3, c = ch & 7;
    int gc = c ^ (r & 7);
    bBase[g] = (long)(col0 + r)*K + gc*8;
  }
  int raBase[4], rbBase[NJ];
#pragma unroll
  for (int i=0;i<4;i++)  raBase[i] = ((w&1)*64 + i*16 + (ln&15))*8;
#pragma unroll
  for (int j=0;j<NJ;j++) rbBase[j] = ((w>>1)*(TN/2) + j*16 + (ln&15))*8;

  float4v acc[4][NJ] = {};
  int nIter = K/64;

  for (int it=0; it<nIter; it++){
    int k0 = it*64;
    int kk = convmode ? (k0 & 511) : k0;
    int seg = convmode ? (k0 >> 9) : 1;
#pragma unroll
    for (int g=0; g<4; g++){
      long d = convmode ? ((seg==0) ? dPrev[g] : (seg==2 ? dNext[g] : 0)) : 0;
      GLL(A + aBase[g] + d + kk + aCol[g], (char*)As + g*4096 + w*1024);
    }
#pragma unroll
    for (int g=0; g<BR; g++)
      GLL(Wb + bBase[g] + k0, (char*)Bs + g*4096 + w*1024);
    __syncthreads();
    const char* ab = (const char*)As;
    const char* bb = (const char*)Bs;
#pragma unroll
    for (int s=0;s<2;s++){
      int xs = (s*4 + (ln>>4)) ^ (ln&7);
      short8 af[4], bf[NJ];
#pragma unroll
      for (int i=0;i<4;i++)  af[i] = *(const short8*)(ab + (raBase[i] + xs)*16);
#pragma unroll
      for (int j=0;j<NJ;j++) bf[j] = *(const short8*)(bb + (rbBase[j] + xs)*16);
#pragma unroll
      for (int i=0;i<4;i++)
#pragma unroll
        for (int j=0;j<NJ;j++)
          acc[i][j] = __builtin_amdgcn_mfma_f32_16x16x32_bf16(af[i], bf[j], acc[i][j], 0, 0, 0);
    }
    __syncthreads();
  }

  float* Cf = (float*)C;
  unsigned short* Cb = (unsigned short*)C;
  int colb0 = col0 + (w>>1)*(TN/2) + (ln & 15);
#pragma unroll
  for (int i=0;i<4;i++){
#pragma unroll
    for (int r=0;r<4;r++){
      int grow = row0 + (w&1)*64 + i*16 + (ln>>4)*4 + r;
#pragma unroll
      for (int j=0;j<NJ;j++){
        int colb = colb0 + j*16;
        float v = acc[i][j][r];
        if (bias) v += bias[colb];
        if (act)  v = 0.5f * v * (1.0f + erff(v * 0.70710678f));
        if (outbf){
          if (qkv){
            int bsel = colb >> 9;
            Cb[(size_t)bsel*bufstride + (size_t)grow*512 + (colb & 511)] = f2b(v);
          } else {
            Cb[(size_t)grow*N + colb] = f2b(v);
          }
        } else {
          Cf[(size_t)grow*N + colb] = v;
        }
      }
    }
  }
}

// ---------------- sample_m2: one wave per (b,l), all 8 heads; 16B/lane loads ----------------
__global__ __launch_bounds__(256) void sample_m2(const unsigned short* __restrict__ q,
    const unsigned short* __restrict__ k, const int* __restrict__ idx, float* __restrict__ m, int L, int u){
  int w = (blockIdx.x*256 + threadIdx.x) >> 6;    // (b_local, l)
  int lane = threadIdx.x & 63;
  int l = w % L; int b = w / L;
  const unsigned short* qrow = q + (size_t)w*DM + lane*8;
  uint4 qq = *(const uint4*)qrow;
  float qv[8];
  qv[0]=b2f((unsigned short)(qq.x&0xffff)); qv[1]=b2f((unsigned short)(qq.x>>16));
  qv[2]=b2f((unsigned short)(qq.y&0xffff)); qv[3]=b2f((unsigned short)(qq.y>>16));
  qv[4]=b2f((unsigned short)(qq.z&0xffff)); qv[5]=b2f((unsigned short)(qq.z>>16));
  qv[6]=b2f((unsigned short)(qq.w&0xffff)); qv[7]=b2f((unsigned short)(qq.w>>16));
  const unsigned short* kb = k + (size_t)b*L*DM + lane*8;
  const int* ip = idx + (size_t)l*u;
  float mx = -1e30f, sum = 0.f;
  for (int s=0; s<u; s++){
    int kp = ip[s];
    uint4 kk = *(const uint4*)(kb + (size_t)kp*DM);
    float p;
    p  = qv[0]*b2f((unsigned short)(kk.x&0xffff)) + qv[1]*b2f((unsigned short)(kk.x>>16));
    p += qv[2]*b2f((unsigned short)(kk.y&0xffff)) + qv[3]*b2f((unsigned short)(kk.y>>16));
    p += qv[4]*b2f((unsigned short)(kk.z&0xffff)) + qv[5]*b2f((unsigned short)(kk.z>>16));
    p += qv[6]*b2f((unsigned short)(kk.w&0xffff)) + qv[7]*b2f((unsigned short)(kk.w>>16));
    p += __shfl_xor(p, 1); p += __shfl_xor(p, 2); p += __shfl_xor(p, 4);   // 8-lane head reduce
    mx = fmaxf(mx, p); sum += p;
  }
  if ((lane & 7) == 0){
    int hh = lane >> 3;
    m[((size_t)b*8 + hh)*L + l] = mx - sum/(float)u;
  }
}

// ---------------- iterative top-u argmax per (b,h), min-index tie-break ----------------
__global__ __launch_bounds__(256) void topk_kernel(const float* __restrict__ m, int* __restrict__ top, int L, int u){
  int bh = blockIdx.x;
  const float* mm = m + (size_t)bh*L;
  __shared__ float vals[2048];
  __shared__ float rv[256];
  __shared__ int   ri[256];
  for (int i=threadIdx.x; i<L; i+=256) vals[i] = mm[i];
  __syncthreads();
  for (int it=0; it<u; it++){
    float bv = -1e30f; int bi = 0x7fffffff;
    for (int i=threadIdx.x; i<L; i+=256){
      float v = vals[i];
      if (v > bv || (v == bv && i < bi)) { bv = v; bi = i; }
    }
    rv[threadIdx.x] = bv; ri[threadIdx.x] = bi;
    __syncthreads();
    for (int s=128; s; s>>=1){
      if (threadIdx.x < s){
        float v = rv[threadIdx.x+s]; int i2 = ri[threadIdx.x+s];
        if (v > rv[threadIdx.x] || (v == rv[threadIdx.x] && i2 < ri[threadIdx.x])){
          rv[threadIdx.x] = v; ri[threadIdx.x] = i2;
        }
      }
      __syncthreads();
    }
    if (threadIdx.x == 0){ top[bh*u + it] = ri[0]; vals[ri[0]] = -1e31f; }
    __syncthreads();
  }
}

// ---------------- column mean, two-stage ----------------
#define CMC 32
__global__ __launch_bounds__(256) void colmean1(const float* __restrict__ src, float* __restrict__ part, int L){
  int b = blockIdx.x, ch = blockIdx.y;     // grid (B, CMC)
  int rpb = L / CMC;
  int t = threadIdx.x;
  const float* p = src + ((size_t)b*L + (size_t)ch*rpb)*DM;
  float s0 = 0.f, s1 = 0.f;
  for (int r=0; r<rpb; r++){ s0 += p[(size_t)r*DM + t]; s1 += p[(size_t)r*DM + t + 256]; }
  float* o = part + ((size_t)b*CMC + ch)*DM;
  o[t] = s0; o[t+256] = s1;
}
__global__ __launch_bounds__(256) void colmean2(const float* __restrict__ part, float* __restrict__ dst, int L){
  int i = blockIdx.x*256 + threadIdx.x;    // B*DM
  int d = i % DM, b = i / DM;
  float s = 0.f;
  for (int c=0; c<CMC; c++) s += part[((size_t)b*CMC + c)*DM + d];
  dst[i] = s / (float)L;
}

// ---------------- tiny fp32 GEMM: one block per row ----------------
__global__ __launch_bounds__(256) void tiny_gemm(const float* __restrict__ A, const float* __restrict__ W,
    const float* __restrict__ bias, float* __restrict__ C, int N, int K){
  int row = blockIdx.x;
  const float* ar = A + (size_t)row*K;
  __shared__ float as[DM];
  for (int k=threadIdx.x; k<K; k+=256) as[k] = ar[k];
  __syncthreads();
  for (int n = threadIdx.x; n < N; n += 256){
    float acc = bias ? bias[n] : 0.f;
    const float* wr = W + (size_t)n*K;
    for (int k=0; k<K; k++) acc += as[k]*wr[k];
    C[(size_t)row*N + n] = acc;
  }
}

// ---------------- gather q rows for top queries (bf16 q -> fp32 qred) ----------------
__global__ __launch_bounds__(256) void qred_kernel(const unsigned short* __restrict__ q, const int* __restrict__ top,
    float* __restrict__ qred, int L, int u, int n){
  int i = blockIdx.x*256 + threadIdx.x;
  if (i >= n) return;
  int d = i & 63; int rest = i >> 6; int j = rest % u; int bh = rest / u;
  int hh = bh & 7; int b = bh >> 3;
  int pos = top[bh*u + j];
  qred[i] = b2f(q[((size_t)b*L + pos)*DM + hh*DH + d]);
}

// ---------------- batched scores: S[bh][m][key] = (qred . K)/8 ----------------
__global__ __launch_bounds__(256) void qk_scores(const float* __restrict__ qred,
    const unsigned short* __restrict__ kbuf, float* __restrict__ S, int L, int u){
  int bh = blockIdx.y; int b = bh >> 3, h = bh & 7;
  int key = blockIdx.x*256 + threadIdx.x;
  __shared__ float Qs[38*64];
  int t = threadIdx.x;
  for (int i = t; i < u*64; i += 256) Qs[i] = qred[(size_t)bh*u*64 + i];
  __syncthreads();
  const unsigned short* krow = kbuf + ((size_t)(b*L + key))*DM + h*DH;
  float kr[64];
#pragma unroll
  for (int c=0;c<8;c++){
    uint4 kk = *(const uint4*)(krow + c*8);
    kr[c*8+0]=b2f((unsigned short)(kk.x&0xffff)); kr[c*8+1]=b2f((unsigned short)(kk.x>>16));
    kr[c*8+2]=b2f((unsigned short)(kk.y&0xffff)); kr[c*8+3]=b2f((unsigned short)(kk.y>>16));
    kr[c*8+4]=b2f((unsigned short)(kk.z&0xffff)); kr[c*8+5]=b2f((unsigned short)(kk.z>>16));
    kr[c*8+6]=b2f((unsigned short)(kk.w&0xffff)); kr[c*8+7]=b2f((unsigned short)(kk.w>>16));
  }
  float* srow = S + (size_t)bh*u*L + key;
  for (int m = 0; m < u; m++){
    const float4* q4 = (const float4*)(Qs + m*64);
    float acc = 0.f;
#pragma unroll
    for (int c=0;c<16;c++){
      float4 qv = q4[c];
      acc += qv.x*kr[c*4] + qv.y*kr[c*4+1] + qv.z*kr[c*4+2] + qv.w*kr[c*4+3];
    }
    srow[(size_t)m*L] = acc * 0.125f;
  }
}

// ---------------- softmax over each score row, in place ----------------
__global__ __launch_bounds__(256) void softmax_rows(float* __restrict__ S, int L){
  size_t row = blockIdx.x;
  float* r = S + row*(size_t)L;
  int t = threadIdx.x;
  __shared__ float red[8];
  float mx = -1e30f;
  for (int i=t;i<L;i+=256) mx = fmaxf(mx, r[i]);
#pragma unroll
  for (int off=32; off; off>>=1) mx = fmaxf(mx, __shfl_xor(mx, off));
  if ((t&63)==0) red[t>>6] = mx;
  __syncthreads();
  mx = fmaxf(fmaxf(red[0],red[1]), fmaxf(red[2],red[3]));
  float sum = 0.f;
  for (int i=t;i<L;i+=256){ float e = expf(r[i]-mx); r[i] = e; sum += e; }
#pragma unroll
  for (int off=32; off; off>>=1) sum += __shfl_xor(sum, off);
  if ((t&63)==0) red[4+(t>>6)] = sum;
  __syncthreads();
  float inv = 1.f/(red[4]+red[5]+red[6]+red[7]);
  for (int i=t;i<L;i+=256) r[i] *= inv;
}

// ---------------- ctx += P @ V over a key tile; V staged in LDS ----------------
#define PVKT 256
__global__ __launch_bounds__(256) void pv_kernel(const float* __restrict__ P,
    const unsigned short* __restrict__ vbuf, float* __restrict__ ctxt, int L, int u){
  int bh = blockIdx.y; int b = bh >> 3, h = bh & 7;
  int k0 = blockIdx.x*PVKT;
  int t = threadIdx.x;
  __shared__ unsigned short Vs[PVKT*64];
  for (int e = t*8; e < PVKT*64; e += 2048){
    int k = e>>6, d = e&63;
    *(uint4*)(Vs + e) = *(const uint4*)(vbuf + ((size_t)(b*L + k0 + k))*DM + h*DH + d);
  }
  __syncthreads();
  int n = t & 63, mg = t >> 6;
  for (int m = mg; m < u; m += 4){
    const float* prow = P + ((size_t)bh*u + m)*L + k0;
    float acc = 0.f;
    for (int k=0;k<PVKT;k+=4){
      float4 p4 = *(const float4*)(prow + k);
      acc += p4.x*b2f(Vs[(k+0)*64+n]);
      acc += p4.y*b2f(Vs[(k+1)*64+n]);
      acc += p4.z*b2f(Vs[(k+2)*64+n]);
      acc += p4.w*b2f(Vs[(k+3)*64+n]);
    }
    atomicAdd(&ctxt[((size_t)bh*u + m)*64 + n], acc);
  }
}

// ---------------- sparse correction: h[b,pos] += (ctxt - vmean_slice)@wo_slice^T ----------------
__global__ __launch_bounds__(256) void scatter_delta(const float* __restrict__ ctxt, const float* __restrict__ vmean,
    const float* __restrict__ wo, const int* __restrict__ top, float* __restrict__ h, int L, int u){
  int bid = blockIdx.x;
  int j = bid % u; int bh = bid / u; int hh = bh & 7; int b = bh >> 3;
  int pos = top[bh*u + j];
  __shared__ float delta[DH];
  int t = threadIdx.x;
  if (t < DH) delta[t] = ctxt[(size_t)(bh*u + j)*DH + t] - vmean[b*DM + hh*DH + t];
  __syncthreads();
  float* hrow = h + ((size_t)b*L + pos)*DM;
  const float* wbase = wo + hh*DH;
  for (int n = t; n < DM; n += 256){
    float acc = 0.f;
    const float* wr = wbase + (size_t)n*DM;
#pragma unroll
    for (int dd=0; dd<DH; dd++) acc += delta[dd] * wr[dd];
    atomicAdd(&hrow[n], acc);
  }
}

// ---------------- LayerNorm D=512; optional +cw[b], +Yadd; out fp32/bf16 ----------------
__global__ __launch_bounds__(256) void ln_kernel(const float* __restrict__ X, const void* __restrict__ Yadd,
    int yb, const float* __restrict__ g, const float* __restrict__ bta, void* __restrict__ Out, int ob,
    const float* __restrict__ cwv, int Lrow, int row0g){
  size_t row = blockIdx.x;
  const float* xr = X + row*DM;
  int t = threadIdx.x;
  float v0 = xr[t], v1 = xr[t+256];
  if (cwv){
    int b = (int)((row0g + (int)row) / Lrow);
    v0 += cwv[b*DM + t]; v1 += cwv[b*DM + t+256];
  }
  if (Yadd){
    if (yb){ const unsigned short* yr = (const unsigned short*)Yadd + row*DM; v0 += b2f(yr[t]); v1 += b2f(yr[t+256]); }
    else   { const float* yr = (const float*)Yadd + row*DM; v0 += yr[t]; v1 += yr[t+256]; }
  }
  float s = v0+v1, q = v0*v0+v1*v1;
#pragma unroll
  for (int off=32; off; off>>=1){ s += __shfl_xor(s,off); q += __shfl_xor(q,off); }
  __shared__ float ss[4], qq[4];
  int w = t >> 6;
  if ((t & 63) == 0){ ss[w] = s; qq[w] = q; }
  __syncthreads();
  s = ss[0]+ss[1]+ss[2]+ss[3]; q = qq[0]+qq[1]+qq[2]+qq[3];
  float mu  = s * (1.0f/DM);
  float var = q * (1.0f/DM) - mu*mu;
  float r = rsqrtf(var + 1e-5f);
  float o0 = (v0 - mu)*r*g[t]     + bta[t];
  float o1 = (v1 - mu)*r*g[t+256] + bta[t+256];
  if (ob){
    unsigned short* Ob = (unsigned short*)Out;
    Ob[row*DM + t] = f2b(o0); Ob[row*DM + t+256] = f2b(o1);
  } else {
    float* Of = (float*)Out;
    Of[row*DM + t] = o0; Of[row*DM + t+256] = o1;
  }
}

// ---------------- BN partial sums (grid: 8 x 32) ----------------
__global__ __launch_bounds__(256) void bnstat1(const float* __restrict__ C, float* __restrict__ partS,
                                               float* __restrict__ partQ, int rpb){
  int chb = blockIdx.x;
  int mb  = blockIdx.y;
  int g = threadIdx.x >> 6, c = threadIdx.x & 63;
  int ch = chb*64 + c;
  float s = 0.f, q = 0.f;
  int r0 = mb * rpb;
  for (int r = r0 + g; r < r0 + rpb; r += 4){
    float v = C[(size_t)r*DM + ch]; s += v; q += v*v;
  }
  __shared__ float ls[4][64], lq[4][64];
  ls[g][c] = s; lq[g][c] = q;
  __syncthreads();
  if (g == 0){
    s = ls[0][c]+ls[1][c]+ls[2][c]+ls[3][c];
    q = lq[0][c]+lq[1][c]+lq[2][c]+lq[3][c];
    partS[(size_t)mb*DM + ch] = s;
    partQ[(size_t)mb*DM + ch] = q;
  }
}
__global__ __launch_bounds__(256) void bnstat2(const float* __restrict__ partS, const float* __restrict__ partQ,
                                               float* __restrict__ stats, int NB, int M){
  int ch = blockIdx.x*256 + threadIdx.x;
  if (ch >= DM) return;
  float s = 0.f, q = 0.f;
  for (int mb=0; mb<NB; mb++){
    s += partS[(size_t)mb*DM + ch];
    q += partQ[(size_t)mb*DM + ch];
  }
  float mu = s / (float)M;
  stats[ch] = mu;
  stats[DM + ch] = q / (float)M - mu*mu;
}

// ---------------- BN + ELU + maxpool(3,2); group-local C, global Out ----------------
__global__ __launch_bounds__(256) void bnpool(const float* __restrict__ C, const float* __restrict__ stats,
    const float* __restrict__ g, const float* __restrict__ bta, float* __restrict__ Out,
    int L, int Lo, int gbase){
  size_t i = (size_t)blockIdx.x*256 + threadIdx.x;
  int ch = (int)(i % DM);
  size_t r = i / DM;
  int lo = (int)(r % Lo);
  int bl = (int)(r / Lo);
  float mu = stats[ch];
  float rstd = rsqrtf(stats[DM+ch] + 1e-5f);
  float gg = g[ch], bb = bta[ch];
  float best = -1e30f;
#pragma unroll
  for (int t=-1; t<=1; t++){
    int li = 2*lo + t;
    if (li >= 0 && li < L){
      float v = (C[((size_t)bl*L + li)*DM + ch] - mu)*rstd*gg + bb;
      v = v > 0.f ? v : expm1f(v);
      best = fmaxf(best, v);
    }
  }
  Out[((size_t)(gbase + bl)*Lo + lo)*DM + ch] = best;
}

// ---------------- final: LN(last row) @ proj^T + proj_b + skip ----------------
__global__ __launch_bounds__(128) void final_kernel(const float* __restrict__ h, const float* __restrict__ x,
    const float* __restrict__ fg, const float* __restrict__ fb, const float* __restrict__ pw,
    const float* __restrict__ pb, const float* __restrict__ sw, const float* __restrict__ sb,
    float* __restrict__ out, int Lf, int L0){
  int b = blockIdx.x;
  const float* row = h + ((size_t)b*Lf + (Lf-1))*DM;
  __shared__ float xn[DM];
  __shared__ float rs[2], rq[2];
  int t = threadIdx.x;
  float v[4]; float s = 0.f, q = 0.f;
#pragma unroll
  for (int i=0;i<4;i++){ v[i] = row[t + i*128]; s += v[i]; q += v[i]*v[i]; }
#pragma unroll
  for (int off=32; off; off>>=1){ s += __shfl_xor(s,off); q += __shfl_xor(q,off); }
  if ((t & 63) == 0){ rs[t>>6] = s; rq[t>>6] = q; }
  __syncthreads();
  s = rs[0]+rs[1]; q = rq[0]+rq[1];
  float mu = s*(1.0f/DM), var = q*(1.0f/DM) - mu*mu;
  float r = rsqrtf(var + 1e-5f);
#pragma unroll
  for (int i=0;i<4;i++){ int d = t + i*128; xn[d] = (v[i]-mu)*r*fg[d] + fb[d]; }
  __syncthreads();
  if (t < 96){
    float acc = pb[t] + sb[t];
    const float* xr = x + ((size_t)b*L0 + (L0-1))*7;
#pragma unroll
    for (int c=0;c<7;c++) acc += xr[c]*sw[t*7+c];
    for (int d=0; d<DM; d++) acc += xn[d]*pw[(size_t)t*DM + d];
    out[b*96 + t] = acc;
  }
}

// =======================================================================
extern "C" void kernel_launch(void* const* d_in, const int* in_sizes, int n_in,
                              void* d_out, int out_size, void* d_ws, size_t ws_size,
                              hipStream_t stream){
  const float* x    = (const float*)d_in[0];
  const float* skw  = (const float*)d_in[1];
  const float* skb  = (const float*)d_in[2];
  const float* tcw  = (const float*)d_in[3];
  const float* wq   = (const float*)d_in[4];
  const float* bq   = (const float*)d_in[5];
  const float* wk   = (const float*)d_in[6];
  const float* bk   = (const float*)d_in[7];
  const float* wv   = (const float*)d_in[8];
  const float* bv   = (const float*)d_in[9];
  const float* wo   = (const float*)d_in[10];
  const float* bo   = (const float*)d_in[11];
  const float* w1   = (const float*)d_in[12];
  const float* b1   = (const float*)d_in[13];
  const float* w2   = (const float*)d_in[14];
  const float* b2   = (const float*)d_in[15];
  const float* ln1g = (const float*)d_in[16];
  const float* ln1b = (const float*)d_in[17];
  const float* ln2g = (const float*)d_in[18];
  const float* ln2b = (const float*)d_in[19];
  const float* dcw  = (const float*)d_in[20];
  const float* dcb  = (const float*)d_in[21];
  const float* bng  = (const float*)d_in[22];
  const float* bnb  = (const float*)d_in[23];
  const float* flg  = (const float*)d_in[24];
  const float* flb  = (const float*)d_in[25];
  const float* pw   = (const float*)d_in[26];
  const float* pb   = (const float*)d_in[27];

  const int B = 32, L0 = 2048, DFF = 2048;
  const int RG = 16384;
  const int RF = 8192;
  char* ws = (char*)d_ws;
  const size_t SZH  = (size_t)B*L0*DM*sizeof(float);
  const size_t SLOT = (size_t)RG*DM*sizeof(unsigned short);

  const size_t WBSZ = (size_t)(3*DM*DM + 2*DFF*DM + 3*DM*DM)*2;
  size_t small_bytes = (size_t)L0*40*4
                     + (size_t)RG*8*4
                     + (size_t)B*8*40*4
                     + (size_t)32*8*40*64*4
                     + (size_t)32*8*40*64*4
                     + 3*(size_t)B*DM*4
                     + 2*(size_t)4*32*DM*4
                     + (size_t)2*DM*4
                     + (size_t)1536*4
                     + (size_t)B*CMC*DM*4;     // colmean partials (2 MB)
  if (ws_size < SZH + 4*SLOT + WBSZ + small_bytes) return;

  float*          h   = (float*)(ws);
  unsigned short* P0  = (unsigned short*)(ws + SZH);
  unsigned short* P1  = (unsigned short*)(ws + SZH + SLOT);
  unsigned short* P2  = (unsigned short*)(ws + SZH + 2*SLOT);
  unsigned short* P3  = (unsigned short*)(ws + SZH + 3*SLOT);
  unsigned short* wb  = (unsigned short*)(ws + SZH + 4*SLOT);
  unsigned short* wqb = wb;
  unsigned short* w1b = wqb + (size_t)3*DM*DM;
  unsigned short* w2b = w1b + (size_t)DFF*DM;
  unsigned short* wtapK= w2b + (size_t)DM*DFF;
  char* sm = ws + SZH + 4*SLOT + WBSZ;
  int*   idx_buf  = (int*)sm;
  float* m_buf    = (float*)(sm + (size_t)L0*40*4);
  int*   top_all  = (int*)((char*)m_buf + (size_t)RG*8*4);
  float* qred_loc = (float*)((char*)top_all + (size_t)B*8*40*4);
  float* ctxt_all = qred_loc + (size_t)32*8*40*64;
  float* hm       = ctxt_all + (size_t)32*8*40*64;
  float* vmean    = hm + (size_t)B*DM;
  float* cw       = vmean + (size_t)B*DM;
  float* partS    = cw + (size_t)B*DM;
  float* partQ    = partS + (size_t)4*32*DM;
  float* stats    = partQ + (size_t)4*32*DM;
  float* bqkv     = stats + (size_t)2*DM;
  float* partC    = bqkv + (size_t)1536;

  auto conv_b = [&](const float* src, unsigned short* dst, size_t n){
    f2b_vec<<<(int)((n/4 + 255)/256), 256, 0, stream>>>(src, dst, (int)(n/4));
  };

  embed_kernel<<<(int)(((size_t)B*L0*DM)/256), 256, 0, stream>>>(x, tcw, h, L0);

  int L = L0;
  const int SGtab[3] = {4, 8, 16};
  for (int layer = 0; layer < 3; layer++){
    int M = B * L;
    int u = (int)(5.0 * log((double)L + 1.0));   // 38 / 34 / 31
    int G = RG / L;
    int nG = M / RG;
    const float* wv_i = wv + (size_t)layer*DM*DM;  const float* bv_i = bv + (size_t)layer*DM;
    const float* wo_i = wo + (size_t)layer*DM*DM;  const float* bo_i = bo + (size_t)layer*DM;
    const float* b1_i = b1 + (size_t)layer*DFF;
    const float* b2_i = b2 + (size_t)layer*DM;

    conv_b(wq + (size_t)layer*DM*DM, wqb,                    (size_t)DM*DM);
    conv_b(wk + (size_t)layer*DM*DM, wqb + (size_t)DM*DM,    (size_t)DM*DM);
    conv_b(wv_i,                     wqb + (size_t)2*DM*DM,  (size_t)DM*DM);
    conv_b(w1 + (size_t)layer*DFF*DM, w1b, (size_t)DFF*DM);
    conv_b(w2 + (size_t)layer*DM*DFF, w2b, (size_t)DM*DFF);
    catb_kernel<<<6, 256, 0, stream>>>(bq + (size_t)layer*DM, bk + (size_t)layer*DM, bv_i, bqkv);
    if (layer < 2)
      packconv<<<(3*DM*DM + 255)/256, 256, 0, stream>>>(dcw + (size_t)layer*DM*DM*3, wtapK);

    unsigned ka = 0u, kb2 = (unsigned)layer;
    tf2x32(0u, 42u, ka, kb2);
    unsigned a0 = 0u, a1 = 2u;  tf2x32(ka, kb2, a0, a1);
    unsigned c0 = 1u, c1 = 3u;  tf2x32(ka, kb2, c0, c1);
    int S2 = L * u / 2;
    idx_kernel<<<(S2 + 255)/256, 256, 0, stream>>>(idx_buf, a1, c1, S2, L-1);

    hipMemsetAsync(ctxt_all, 0, (size_t)B*8*u*64*sizeof(float), stream);

    int sg = SGtab[layer];
    for (int g = 0; g < nG; g++){
      const float* hg = h + (size_t)g*RG*DM;
      conv_b(hg, P0, (size_t)RG*DM);
      bgemm2<128><<<dim3(12, RG/128), 256, 0, stream>>>(P0, wqb, bqkv, P1,
          1536, 512, L, 0, 0, 1, 1, (size_t)RG*DM);
      sample_m2<<<RG/4, 256, 0, stream>>>(P1, P2, idx_buf, m_buf, L, u);
      int* top_g = top_all + (size_t)g*G*8*u;
      topk_kernel<<<G*8, 256, 0, stream>>>(m_buf, top_g, L, u);
      int nqr = G*8*u*DH;
      qred_kernel<<<(nqr + 255)/256, 256, 0, stream>>>(P1, top_g, qred_loc, L, u, nqr);

      float* Sbuf = (float*)P0;
      int nsub = G / sg;
      for (int s = 0; s < nsub; s++){
        const float* qr = qred_loc + (size_t)s*sg*8*u*64;
        const unsigned short* kb_ = P2 + (size_t)s*sg*L*DM;
        const unsigned short* vb_ = P3 + (size_t)s*sg*L*DM;
        float* ct = ctxt_all + (size_t)(g*G + s*sg)*8*u*64;
        qk_scores<<<dim3(L/256, sg*8), 256, 0, stream>>>(qr, kb_, Sbuf, L, u);
        softmax_rows<<<sg*8*u, 256, 0, stream>>>(Sbuf, L);
        pv_kernel<<<dim3(L/PVKT, sg*8), 256, 0, stream>>>(Sbuf, vb_, ct, L, u);
      }
    }

    // vmean = (mean_L h)@wv^T + bv ; cw = vmean@wo^T + bo (exact fp32 identity)
    colmean1<<<dim3(B, CMC), 256, 0, stream>>>(h, partC, L);
    colmean2<<<B*DM/256, 256, 0, stream>>>(partC, hm, L);
    tiny_gemm<<<B, 256, 0, stream>>>(hm, wv_i, bv_i, vmean, DM, DM);
    tiny_gemm<<<B, 256, 0, stream>>>(vmean, wo_i, bo_i, cw, DM, DM);

    scatter_delta<<<B*8*u, 256, 0, stream>>>(ctxt_all, vmean, wo_i, top_all, h, L, u);

    unsigned short* ybuf = P0;
    unsigned short* mid  = P1;
    unsigned short* y2b  = P0 + (size_t)RF*DM;
    const float* l1g = ln1g + (size_t)layer*DM; const float* l1b = ln1b + (size_t)layer*DM;
    const float* l2g = ln2g + (size_t)layer*DM; const float* l2b = ln2b + (size_t)layer*DM;
    for (int r0 = 0; r0 < M; r0 += RF){
      ln_kernel<<<RF, 256, 0, stream>>>(h + (size_t)r0*DM, nullptr, 0, l1g, l1b, ybuf, 1, cw, L, r0);
      bgemm2<128><<<dim3(16, RF/128), 256, 0, stream>>>(ybuf, w1b, b1_i, mid,
          2048, 512, L, 0, 1, 1, 0, 0);
      bgemm2<64><<<dim3(8, RF/128), 256, 0, stream>>>(mid, w2b, b2_i, y2b,
          512, 2048, L, 0, 0, 1, 0, 0);
      ln_kernel<<<RF, 256, 0, stream>>>(h + (size_t)r0*DM, y2b, 1, l2g, l2b, h + (size_t)r0*DM, 0, cw, L, r0);
    }

    if (layer < 2){
      const float* db = dcb + (size_t)layer*DM;
      float* convf = (float*)P1;
      for (int g = 0; g < nG; g++){
        const float* hg = h + (size_t)g*RG*DM;
        conv_b(hg, P0, (size_t)RG*DM);
        bgemm2<64><<<dim3(8, RG/128), 256, 0, stream>>>(P0, wtapK, db, convf,
            512, 1536, L, 1, 0, 0, 0, 0);
        bnstat1<<<dim3(8, 32), 256, 0, stream>>>(convf, partS + (size_t)g*32*DM,
                                                 partQ + (size_t)g*32*DM, RG/32);
      }
      bnstat2<<<2, 256, 0, stream>>>(partS, partQ, stats, nG*32, M);
      int Lo = L/2;
      for (int g = 0; g < nG; g++){
        const float* hg = h + (size_t)g*RG*DM;
        conv_b(hg, P0, (size_t)RG*DM);
        bgemm2<64><<<dim3(8, RG/128), 256, 0, stream>>>(P0, wtapK, db, convf,
            512, 1536, L, 1, 0, 0, 0, 0);
        bnpool<<<(int)(((size_t)(RG/L)*Lo*DM)/256), 256, 0, stream>>>(convf, stats,
            bng + (size_t)layer*DM, bnb + (size_t)layer*DM, h, L, Lo, g*G);
      }
      L = Lo;
    }
  }

  final_kernel<<<B, 128, 0, stream>>>(h, x, flg, flb, pw, pb, skw, skb, (float*)d_out, L, L0);
}

// Round 8
// 5686.332 us; speedup vs baseline: 7.9447x; 1.1426x over previous
//
#include <hip/hip_runtime.h>
#include <cmath>

#define DM 512
#define DH 64

typedef __attribute__((ext_vector_type(8))) short short8;
typedef __attribute__((ext_vector_type(4))) float float4v;

__device__ inline float b2f(unsigned short u){
  union{unsigned int i; float f;} z; z.i = ((unsigned)u)<<16; return z.f;
}
__device__ inline unsigned short f2b(float f){
  unsigned int x = __float_as_uint(f);
  return (unsigned short)((x + 0x7fffu + ((x>>16)&1u)) >> 16);   // RNE
}

#define GLL(gp, lp) __builtin_amdgcn_global_load_lds((const __attribute__((address_space(1))) void*)(gp), \
    (__attribute__((address_space(3))) void*)(lp), 16, 0, 0)

// ---------------- Threefry-2x32-20 (matches jax.random) ----------------
__host__ __device__ inline void tf2x32(unsigned k0, unsigned k1, unsigned& x0, unsigned& x1){
  const unsigned ks0=k0, ks1=k1, ks2=k0^k1^0x1BD11BDAu;
  x0 += ks0; x1 += ks1;
#define TF_ROT(r) { x0 += x1; x1 = (x1<<(r))|(x1>>(32-(r))); x1 ^= x0; }
  TF_ROT(13) TF_ROT(15) TF_ROT(26) TF_ROT(6)
  x0 += ks1; x1 += ks2 + 1u;
  TF_ROT(17) TF_ROT(29) TF_ROT(16) TF_ROT(24)
  x0 += ks2; x1 += ks0 + 2u;
  TF_ROT(13) TF_ROT(15) TF_ROT(26) TF_ROT(6)
  x0 += ks0; x1 += ks1 + 3u;
  TF_ROT(17) TF_ROT(29) TF_ROT(16) TF_ROT(24)
  x0 += ks1; x1 += ks2 + 4u;
  TF_ROT(13) TF_ROT(15) TF_ROT(26) TF_ROT(6)
  x0 += ks2; x1 += ks0 + 5u;
#undef TF_ROT
}

__global__ __launch_bounds__(256) void idx_kernel(int* __restrict__ idx, unsigned k2a, unsigned k2b,
                                                  int S2, int Lmask){
  int j = blockIdx.x*256 + threadIdx.x;
  if (j >= S2) return;
  unsigned x0 = (unsigned)j, x1 = (unsigned)(S2 + j);
  tf2x32(k2a, k2b, x0, x1);
  idx[j]      = (int)(x0 & (unsigned)Lmask);
  idx[S2 + j] = (int)(x1 & (unsigned)Lmask);
}

// ---------------- positional-embedding table (computed once, batch-independent) ----------------
__global__ __launch_bounds__(256) void pe_kernel(float* __restrict__ pe, int L){
  int i = blockIdx.x*256 + threadIdx.x;
  int d = i % DM, l = i / DM;
  const float scale = -0.017988946f;  // -ln(10000)/512
  float freq = expf((float)(d & ~1) * scale);
  float ang  = (float)l * freq;
  pe[i] = (d & 1) ? cosf(ang) : sinf(ang);
}

// ---------------- token embed: circular conv (7ch->512) + PE table ----------------
__global__ __launch_bounds__(256) void embed_kernel(const float* __restrict__ x, const float* __restrict__ tcw,
                                                    const float* __restrict__ pe, float* __restrict__ h, int L){
  size_t i = (size_t)blockIdx.x*256 + threadIdx.x;
  int d = (int)(i % DM);
  size_t r = i / DM;
  int l = (int)(r % L);
  int b = (int)(r / L);
  const float* xb = x + (size_t)b*L*7;
  float acc = 0.f;
#pragma unroll
  for (int kk=0; kk<3; kk++){
    int ls = l + kk - 1;
    ls = (ls < 0) ? ls + L : (ls >= L ? ls - L : ls);
    const float* xe = xb + (size_t)ls*7;
    const float* wp = tcw + (size_t)d*21 + kk;
#pragma unroll
    for (int c=0;c<7;c++) acc += xe[c]*wp[3*c];
  }
  h[i] = acc + pe[(size_t)l*DM + d];
}

// ---------------- fp32 -> bf16 conversion (weights only now) ----------------
__global__ __launch_bounds__(256) void f2b_vec(const float* __restrict__ src, unsigned short* __restrict__ dst, int n4){
  int i = blockIdx.x*256 + threadIdx.x;
  if (i >= n4) return;
  float4 v = ((const float4*)src)[i];
  ushort4 o; o.x = f2b(v.x); o.y = f2b(v.y); o.z = f2b(v.z); o.w = f2b(v.w);
  ((ushort4*)dst)[i] = o;
}

// ---------------- pack conv weights along K: wtapK[n][tap*512+c] = dcw[n][c][tap] ----------------
__global__ __launch_bounds__(256) void packconv(const float* __restrict__ dcw, unsigned short* __restrict__ wtapK){
  int i = blockIdx.x*256 + threadIdx.x;
  if (i >= 3*DM*DM) return;
  int n = i / (3*DM); int rem = i % (3*DM); int tap = rem / DM; int c = rem % DM;
  wtapK[(size_t)n*(3*DM) + tap*DM + c] = f2b(dcw[((size_t)n*DM + c)*3 + tap]);
}

// ---------------- concat qkv bias ----------------
__global__ __launch_bounds__(256) void catb_kernel(const float* __restrict__ a, const float* __restrict__ b,
    const float* __restrict__ c, float* __restrict__ o){
  int i = blockIdx.x*256 + threadIdx.x;
  if (i >= 1536) return;
  o[i] = (i < 512) ? a[i] : (i < 1024 ? b[i-512] : c[i-1024]);
}

// =======================================================================
// bgemm2: bf16 MFMA GEMM, 128xTN tile, BK=64, single-buffered staging.
// A32: A operand is fp32, staged via VGPR convert + ds_write (no f2b pass).
// swz: XCD-aware block remap — per-XCD contiguous y-chunks so each XCD's
// A-slice stays resident in its 4MB L2 across all column-blocks.
// convmode: K=1536 = 3 taps with circular row shift. qkv: route 512-col
// groups to consecutive bufstride-spaced buffers.
// =======================================================================
template<int TN, int A32>
__global__ __launch_bounds__(256) void bgemm2(const void* __restrict__ Ain,
    const unsigned short* __restrict__ Wb, const float* __restrict__ bias, void* __restrict__ C,
    int N, int K, int L, int convmode, int act, int outbf, int qkv, size_t bufstride, int swz){
  constexpr int NJ = TN/32;
  constexpr int BR = TN/32;
  __shared__ unsigned short As[128*64];   // 16 KB
  __shared__ unsigned short Bs[TN*64];    // 16/8 KB
  int tid = threadIdx.x;
  int w = tid >> 6, ln = tid & 63;

  int bx = blockIdx.x, by = blockIdx.y;
  if (swz){
    int XT = gridDim.x, YT = gridDim.y;
    int lid = by*XT + bx;
    int xcd = lid & 7, s = lid >> 3;
    int ych = YT >> 3;
    int CHv = ych < 16 ? ych : 16;
    int yloc = s % CHv;
    int t2 = s / CHv;
    int xx = t2 % XT;
    int chunk = t2 / XT;
    by = xcd*ych + chunk*CHv + yloc;
    bx = xx;
  }
  int row0 = by*128, col0 = bx*TN;
  int KA = convmode ? 512 : K;

  long aBase[4], dPrev[4], dNext[4]; int aCol[4];
#pragma unroll
  for (int g=0; g<4; g++){
    int ch = g*256 + tid;
    int r = ch >> 3, c = ch & 7;
    int gc = c ^ (r & 7);
    int gr = row0 + r;
    aCol[g] = gc*8;
    aBase[g] = (long)gr * KA;
    if (convmode){
      int l = gr % L;
      dPrev[g] = (l==0)   ? (long)(L-1)*KA : -(long)KA;
      dNext[g] = (l==L-1) ? -(long)(L-1)*KA : (long)KA;
    } else { dPrev[g]=0; dNext[g]=0; }
  }
  long bBase[BR];
#pragma unroll
  for (int g=0; g<BR; g++){
    int ch = g*256 + tid;
    int r = ch >> 3, c = ch & 7;
    int gc = c ^ (r & 7);
    bBase[g] = (long)(col0 + r)*K + gc*8;
  }
  int raBase[4], rbBase[NJ];
#pragma unroll
  for (int i=0;i<4;i++)  raBase[i] = ((w&1)*64 + i*16 + (ln&15))*8;
#pragma unroll
  for (int j=0;j<NJ;j++) rbBase[j] = ((w>>1)*(TN/2) + j*16 + (ln&15))*8;

  float4v acc[4][NJ] = {};
  int nIter = K/64;
  const unsigned short* A16 = (const unsigned short*)Ain;
  const float* Af = (const float*)Ain;

  for (int it=0; it<nIter; it++){
    int k0 = it*64;
    int kk = convmode ? (k0 & 511) : k0;
    int seg = convmode ? (k0 >> 9) : 1;
    if (A32){
#pragma unroll
      for (int g=0; g<4; g++){
        long d = convmode ? ((seg==0) ? dPrev[g] : (seg==2 ? dNext[g] : 0)) : 0;
        const float* src = Af + aBase[g] + d + kk + aCol[g];
        float4 v0 = *(const float4*)src;
        float4 v1 = *(const float4*)(src+4);
        short8 pk;
        pk[0]=(short)f2b(v0.x); pk[1]=(short)f2b(v0.y); pk[2]=(short)f2b(v0.z); pk[3]=(short)f2b(v0.w);
        pk[4]=(short)f2b(v1.x); pk[5]=(short)f2b(v1.y); pk[6]=(short)f2b(v1.z); pk[7]=(short)f2b(v1.w);
        *(short8*)((char*)As + g*4096 + tid*16) = pk;
      }
    } else {
#pragma unroll
      for (int g=0; g<4; g++){
        long d = convmode ? ((seg==0) ? dPrev[g] : (seg==2 ? dNext[g] : 0)) : 0;
        GLL(A16 + aBase[g] + d + kk + aCol[g], (char*)As + g*4096 + w*1024);
      }
    }
#pragma unroll
    for (int g=0; g<BR; g++)
      GLL(Wb + bBase[g] + k0, (char*)Bs + g*4096 + w*1024);
    __syncthreads();
    const char* ab = (const char*)As;
    const char* bb = (const char*)Bs;
#pragma unroll
    for (int s=0;s<2;s++){
      int xs = (s*4 + (ln>>4)) ^ (ln&7);
      short8 af[4], bf[NJ];
#pragma unroll
      for (int i=0;i<4;i++)  af[i] = *(const short8*)(ab + (raBase[i] + xs)*16);
#pragma unroll
      for (int j=0;j<NJ;j++) bf[j] = *(const short8*)(bb + (rbBase[j] + xs)*16);
#pragma unroll
      for (int i=0;i<4;i++)
#pragma unroll
        for (int j=0;j<NJ;j++)
          acc[i][j] = __builtin_amdgcn_mfma_f32_16x16x32_bf16(af[i], bf[j], acc[i][j], 0, 0, 0);
    }
    __syncthreads();
  }

  float* Cf = (float*)C;
  unsigned short* Cb = (unsigned short*)C;
  int colb0 = col0 + (w>>1)*(TN/2) + (ln & 15);
#pragma unroll
  for (int i=0;i<4;i++){
#pragma unroll
    for (int r=0;r<4;r++){
      int grow = row0 + (w&1)*64 + i*16 + (ln>>4)*4 + r;
#pragma unroll
      for (int j=0;j<NJ;j++){
        int colb = colb0 + j*16;
        float v = acc[i][j][r];
        if (bias) v += bias[colb];
        if (act)  v = 0.5f * v * (1.0f + erff(v * 0.70710678f));
        if (outbf){
          if (qkv){
            int bsel = colb >> 9;
            Cb[(size_t)bsel*bufstride + (size_t)grow*512 + (colb & 511)] = f2b(v);
          } else {
            Cb[(size_t)grow*N + colb] = f2b(v);
          }
        } else {
          Cf[(size_t)grow*N + colb] = v;
        }
      }
    }
  }
}

// ---------------- sample_m2: one wave per (b,l), all 8 heads; 16B/lane loads ----------------
__global__ __launch_bounds__(256) void sample_m2(const unsigned short* __restrict__ q,
    const unsigned short* __restrict__ k, const int* __restrict__ idx, float* __restrict__ m, int L, int u){
  int w = (blockIdx.x*256 + threadIdx.x) >> 6;    // (b_local, l)
  int lane = threadIdx.x & 63;
  int l = w % L; int b = w / L;
  const unsigned short* qrow = q + (size_t)w*DM + lane*8;
  uint4 qq = *(const uint4*)qrow;
  float qv[8];
  qv[0]=b2f((unsigned short)(qq.x&0xffff)); qv[1]=b2f((unsigned short)(qq.x>>16));
  qv[2]=b2f((unsigned short)(qq.y&0xffff)); qv[3]=b2f((unsigned short)(qq.y>>16));
  qv[4]=b2f((unsigned short)(qq.z&0xffff)); qv[5]=b2f((unsigned short)(qq.z>>16));
  qv[6]=b2f((unsigned short)(qq.w&0xffff)); qv[7]=b2f((unsigned short)(qq.w>>16));
  const unsigned short* kb = k + (size_t)b*L*DM + lane*8;
  const int* ip = idx + (size_t)l*u;
  float mx = -1e30f, sum = 0.f;
  for (int s=0; s<u; s++){
    int kp = ip[s];
    uint4 kk = *(const uint4*)(kb + (size_t)kp*DM);
    float p;
    p  = qv[0]*b2f((unsigned short)(kk.x&0xffff)) + qv[1]*b2f((unsigned short)(kk.x>>16));
    p += qv[2]*b2f((unsigned short)(kk.y&0xffff)) + qv[3]*b2f((unsigned short)(kk.y>>16));
    p += qv[4]*b2f((unsigned short)(kk.z&0xffff)) + qv[5]*b2f((unsigned short)(kk.z>>16));
    p += qv[6]*b2f((unsigned short)(kk.w&0xffff)) + qv[7]*b2f((unsigned short)(kk.w>>16));
    p += __shfl_xor(p, 1); p += __shfl_xor(p, 2); p += __shfl_xor(p, 4);
    mx = fmaxf(mx, p); sum += p;
  }
  if ((lane & 7) == 0){
    int hh = lane >> 3;
    m[((size_t)b*8 + hh)*L + l] = mx - sum/(float)u;
  }
}

// ---------------- iterative top-u argmax per (b,h), min-index tie-break ----------------
__global__ __launch_bounds__(256) void topk_kernel(const float* __restrict__ m, int* __restrict__ top, int L, int u){
  int bh = blockIdx.x;
  const float* mm = m + (size_t)bh*L;
  __shared__ float vals[2048];
  __shared__ float rv[256];
  __shared__ int   ri[256];
  for (int i=threadIdx.x; i<L; i+=256) vals[i] = mm[i];
  __syncthreads();
  for (int it=0; it<u; it++){
    float bv = -1e30f; int bi = 0x7fffffff;
    for (int i=threadIdx.x; i<L; i+=256){
      float v = vals[i];
      if (v > bv || (v == bv && i < bi)) { bv = v; bi = i; }
    }
    rv[threadIdx.x] = bv; ri[threadIdx.x] = bi;
    __syncthreads();
    for (int s=128; s; s>>=1){
      if (threadIdx.x < s){
        float v = rv[threadIdx.x+s]; int i2 = ri[threadIdx.x+s];
        if (v > rv[threadIdx.x] || (v == rv[threadIdx.x] && i2 < ri[threadIdx.x])){
          rv[threadIdx.x] = v; ri[threadIdx.x] = i2;
        }
      }
      __syncthreads();
    }
    if (threadIdx.x == 0){ top[bh*u + it] = ri[0]; vals[ri[0]] = -1e31f; }
    __syncthreads();
  }
}

// ---------------- column mean, two-stage ----------------
#define CMC 32
__global__ __launch_bounds__(256) void colmean1(const float* __restrict__ src, float* __restrict__ part, int L){
  int b = blockIdx.x, ch = blockIdx.y;
  int rpb = L / CMC;
  int t = threadIdx.x;
  const float* p = src + ((size_t)b*L + (size_t)ch*rpb)*DM;
  float s0 = 0.f, s1 = 0.f;
  for (int r=0; r<rpb; r++){ s0 += p[(size_t)r*DM + t]; s1 += p[(size_t)r*DM + t + 256]; }
  float* o = part + ((size_t)b*CMC + ch)*DM;
  o[t] = s0; o[t+256] = s1;
}
__global__ __launch_bounds__(256) void colmean2(const float* __restrict__ part, float* __restrict__ dst, int L){
  int i = blockIdx.x*256 + threadIdx.x;
  int d = i % DM, b = i / DM;
  float s = 0.f;
  for (int c=0; c<CMC; c++) s += part[((size_t)b*CMC + c)*DM + d];
  dst[i] = s / (float)L;
}

// ---------------- tiny fp32 GEMM: one block per row ----------------
__global__ __launch_bounds__(256) void tiny_gemm(const float* __restrict__ A, const float* __restrict__ W,
    const float* __restrict__ bias, float* __restrict__ C, int N, int K){
  int row = blockIdx.x;
  const float* ar = A + (size_t)row*K;
  __shared__ float as[DM];
  for (int k=threadIdx.x; k<K; k+=256) as[k] = ar[k];
  __syncthreads();
  for (int n = threadIdx.x; n < N; n += 256){
    float acc = bias ? bias[n] : 0.f;
    const float* wr = W + (size_t)n*K;
    for (int k=0; k<K; k++) acc += as[k]*wr[k];
    C[(size_t)row*N + n] = acc;
  }
}

// ---------------- gather q rows for top queries (bf16 q -> fp32 qred) ----------------
__global__ __launch_bounds__(256) void qred_kernel(const unsigned short* __restrict__ q, const int* __restrict__ top,
    float* __restrict__ qred, int L, int u, int n){
  int i = blockIdx.x*256 + threadIdx.x;
  if (i >= n) return;
  int d = i & 63; int rest = i >> 6; int j = rest % u; int bh = rest / u;
  int hh = bh & 7; int b = bh >> 3;
  int pos = top[bh*u + j];
  qred[i] = b2f(q[((size_t)b*L + pos)*DM + hh*DH + d]);
}

// ---------------- batched scores: S[bh][m][key] = (qred . K)/8 ----------------
__global__ __launch_bounds__(256) void qk_scores(const float* __restrict__ qred,
    const unsigned short* __restrict__ kbuf, float* __restrict__ S, int L, int u){
  int bh = blockIdx.y; int b = bh >> 3, h = bh & 7;
  int key = blockIdx.x*256 + threadIdx.x;
  __shared__ float Qs[38*64];
  int t = threadIdx.x;
  for (int i = t; i < u*64; i += 256) Qs[i] = qred[(size_t)bh*u*64 + i];
  __syncthreads();
  const unsigned short* krow = kbuf + ((size_t)(b*L + key))*DM + h*DH;
  float kr[64];
#pragma unroll
  for (int c=0;c<8;c++){
    uint4 kk = *(const uint4*)(krow + c*8);
    kr[c*8+0]=b2f((unsigned short)(kk.x&0xffff)); kr[c*8+1]=b2f((unsigned short)(kk.x>>16));
    kr[c*8+2]=b2f((unsigned short)(kk.y&0xffff)); kr[c*8+3]=b2f((unsigned short)(kk.y>>16));
    kr[c*8+4]=b2f((unsigned short)(kk.z&0xffff)); kr[c*8+5]=b2f((unsigned short)(kk.z>>16));
    kr[c*8+6]=b2f((unsigned short)(kk.w&0xffff)); kr[c*8+7]=b2f((unsigned short)(kk.w>>16));
  }
  float* srow = S + (size_t)bh*u*L + key;
  for (int m = 0; m < u; m++){
    const float4* q4 = (const float4*)(Qs + m*64);
    float acc = 0.f;
#pragma unroll
    for (int c=0;c<16;c++){
      float4 qv = q4[c];
      acc += qv.x*kr[c*4] + qv.y*kr[c*4+1] + qv.z*kr[c*4+2] + qv.w*kr[c*4+3];
    }
    srow[(size_t)m*L] = acc * 0.125f;
  }
}

// ---------------- softmax over each score row, in place ----------------
__global__ __launch_bounds__(256) void softmax_rows(float* __restrict__ S, int L){
  size_t row = blockIdx.x;
  float* r = S + row*(size_t)L;
  int t = threadIdx.x;
  __shared__ float red[8];
  float mx = -1e30f;
  for (int i=t;i<L;i+=256) mx = fmaxf(mx, r[i]);
#pragma unroll
  for (int off=32; off; off>>=1) mx = fmaxf(mx, __shfl_xor(mx, off));
  if ((t&63)==0) red[t>>6] = mx;
  __syncthreads();
  mx = fmaxf(fmaxf(red[0],red[1]), fmaxf(red[2],red[3]));
  float sum = 0.f;
  for (int i=t;i<L;i+=256){ float e = expf(r[i]-mx); r[i] = e; sum += e; }
#pragma unroll
  for (int off=32; off; off>>=1) sum += __shfl_xor(sum, off);
  if ((t&63)==0) red[4+(t>>6)] = sum;
  __syncthreads();
  float inv = 1.f/(red[4]+red[5]+red[6]+red[7]);
  for (int i=t;i<L;i+=256) r[i] *= inv;
}

// ---------------- ctx += P @ V over a key tile; V staged in LDS ----------------
#define PVKT 256
__global__ __launch_bounds__(256) void pv_kernel(const float* __restrict__ P,
    const unsigned short* __restrict__ vbuf, float* __restrict__ ctxt, int L, int u){
  int bh = blockIdx.y; int b = bh >> 3, h = bh & 7;
  int k0 = blockIdx.x*PVKT;
  int t = threadIdx.x;
  __shared__ unsigned short Vs[PVKT*64];
  for (int e = t*8; e < PVKT*64; e += 2048){
    int k = e>>6, d = e&63;
    *(uint4*)(Vs + e) = *(const uint4*)(vbuf + ((size_t)(b*L + k0 + k))*DM + h*DH + d);
  }
  __syncthreads();
  int n = t & 63, mg = t >> 6;
  for (int m = mg; m < u; m += 4){
    const float* prow = P + ((size_t)bh*u + m)*L + k0;
    float acc = 0.f;
    for (int k=0;k<PVKT;k+=4){
      float4 p4 = *(const float4*)(prow + k);
      acc += p4.x*b2f(Vs[(k+0)*64+n]);
      acc += p4.y*b2f(Vs[(k+1)*64+n]);
      acc += p4.z*b2f(Vs[(k+2)*64+n]);
      acc += p4.w*b2f(Vs[(k+3)*64+n]);
    }
    atomicAdd(&ctxt[((size_t)bh*u + m)*64 + n], acc);
  }
}

// ---------------- sparse correction: h[b,pos] += (ctxt - vmean_slice)@wo_slice^T ----------------
__global__ __launch_bounds__(256) void scatter_delta(const float* __restrict__ ctxt, const float* __restrict__ vmean,
    const float* __restrict__ wo, const int* __restrict__ top, float* __restrict__ h, int L, int u){
  int bid = blockIdx.x;
  int j = bid % u; int bh = bid / u; int hh = bh & 7; int b = bh >> 3;
  int pos = top[bh*u + j];
  __shared__ float delta[DH];
  int t = threadIdx.x;
  if (t < DH) delta[t] = ctxt[(size_t)(bh*u + j)*DH + t] - vmean[b*DM + hh*DH + t];
  __syncthreads();
  float* hrow = h + ((size_t)b*L + pos)*DM;
  const float* wbase = wo + hh*DH;
  for (int n = t; n < DM; n += 256){
    float acc = 0.f;
    const float* wr = wbase + (size_t)n*DM;
#pragma unroll
    for (int dd=0; dd<DH; dd++) acc += delta[dd] * wr[dd];
    atomicAdd(&hrow[n], acc);
  }
}

// ---------------- LayerNorm D=512; optional +cw[b], +Yadd; out fp32/bf16 ----------------
__global__ __launch_bounds__(256) void ln_kernel(const float* __restrict__ X, const void* __restrict__ Yadd,
    int yb, const float* __restrict__ g, const float* __restrict__ bta, void* __restrict__ Out, int ob,
    const float* __restrict__ cwv, int Lrow, int row0g){
  size_t row = blockIdx.x;
  const float* xr = X + row*DM;
  int t = threadIdx.x;
  float v0 = xr[t], v1 = xr[t+256];
  if (cwv){
    int b = (int)((row0g + (int)row) / Lrow);
    v0 += cwv[b*DM + t]; v1 += cwv[b*DM + t+256];
  }
  if (Yadd){
    if (yb){ const unsigned short* yr = (const unsigned short*)Yadd + row*DM; v0 += b2f(yr[t]); v1 += b2f(yr[t+256]); }
    else   { const float* yr = (const float*)Yadd + row*DM; v0 += yr[t]; v1 += yr[t+256]; }
  }
  float s = v0+v1, q = v0*v0+v1*v1;
#pragma unroll
  for (int off=32; off; off>>=1){ s += __shfl_xor(s,off); q += __shfl_xor(q,off); }
  __shared__ float ss[4], qq[4];
  int w = t >> 6;
  if ((t & 63) == 0){ ss[w] = s; qq[w] = q; }
  __syncthreads();
  s = ss[0]+ss[1]+ss[2]+ss[3]; q = qq[0]+qq[1]+qq[2]+qq[3];
  float mu  = s * (1.0f/DM);
  float var = q * (1.0f/DM) - mu*mu;
  float r = rsqrtf(var + 1e-5f);
  float o0 = (v0 - mu)*r*g[t]     + bta[t];
  float o1 = (v1 - mu)*r*g[t+256] + bta[t+256];
  if (ob){
    unsigned short* Ob = (unsigned short*)Out;
    Ob[row*DM + t] = f2b(o0); Ob[row*DM + t+256] = f2b(o1);
  } else {
    float* Of = (float*)Out;
    Of[row*DM + t] = o0; Of[row*DM + t+256] = o1;
  }
}

// ---------------- BN partial sums over bf16 conv output (grid: 8 x 128) ----------------
__global__ __launch_bounds__(256) void bnstat1(const unsigned short* __restrict__ C, float* __restrict__ partS,
                                               float* __restrict__ partQ, int rpb){
  int chb = blockIdx.x;
  int mb  = blockIdx.y;
  int g = threadIdx.x >> 6, c = threadIdx.x & 63;
  int ch = chb*64 + c;
  float s = 0.f, q = 0.f;
  int r0 = mb * rpb;
  for (int r = r0 + g; r < r0 + rpb; r += 4){
    float v = b2f(C[(size_t)r*DM + ch]); s += v; q += v*v;
  }
  __shared__ float ls[4][64], lq[4][64];
  ls[g][c] = s; lq[g][c] = q;
  __syncthreads();
  if (g == 0){
    s = ls[0][c]+ls[1][c]+ls[2][c]+ls[3][c];
    q = lq[0][c]+lq[1][c]+lq[2][c]+lq[3][c];
    partS[(size_t)mb*DM + ch] = s;
    partQ[(size_t)mb*DM + ch] = q;
  }
}
__global__ __launch_bounds__(256) void bnstat2(const float* __restrict__ partS, const float* __restrict__ partQ,
                                               float* __restrict__ stats, int NB, int M){
  int ch = blockIdx.x*256 + threadIdx.x;
  if (ch >= DM) return;
  float s = 0.f, q = 0.f;
  for (int mb=0; mb<NB; mb++){
    s += partS[(size_t)mb*DM + ch];
    q += partQ[(size_t)mb*DM + ch];
  }
  float mu = s / (float)M;
  stats[ch] = mu;
  stats[DM + ch] = q / (float)M - mu*mu;
}

// ---------------- BN + ELU + maxpool(3,2) over full-M bf16 conv output ----------------
__global__ __launch_bounds__(256) void bnpool(const unsigned short* __restrict__ C, const float* __restrict__ stats,
    const float* __restrict__ g, const float* __restrict__ bta, float* __restrict__ Out,
    int L, int Lo){
  size_t i = (size_t)blockIdx.x*256 + threadIdx.x;
  int ch = (int)(i % DM);
  size_t r = i / DM;
  int lo = (int)(r % Lo);
  int b  = (int)(r / Lo);
  float mu = stats[ch];
  float rstd = rsqrtf(stats[DM+ch] + 1e-5f);
  float gg = g[ch], bb = bta[ch];
  float best = -1e30f;
#pragma unroll
  for (int t=-1; t<=1; t++){
    int li = 2*lo + t;
    if (li >= 0 && li < L){
      float v = (b2f(C[((size_t)b*L + li)*DM + ch]) - mu)*rstd*gg + bb;
      v = v > 0.f ? v : expm1f(v);
      best = fmaxf(best, v);
    }
  }
  Out[((size_t)b*Lo + lo)*DM + ch] = best;
}

// ---------------- final: LN(last row) @ proj^T + proj_b + skip ----------------
__global__ __launch_bounds__(128) void final_kernel(const float* __restrict__ h, const float* __restrict__ x,
    const float* __restrict__ fg, const float* __restrict__ fb, const float* __restrict__ pw,
    const float* __restrict__ pb, const float* __restrict__ sw, const float* __restrict__ sb,
    float* __restrict__ out, int Lf, int L0){
  int b = blockIdx.x;
  const float* row = h + ((size_t)b*Lf + (Lf-1))*DM;
  __shared__ float xn[DM];
  __shared__ float rs[2], rq[2];
  int t = threadIdx.x;
  float v[4]; float s = 0.f, q = 0.f;
#pragma unroll
  for (int i=0;i<4;i++){ v[i] = row[t + i*128]; s += v[i]; q += v[i]*v[i]; }
#pragma unroll
  for (int off=32; off; off>>=1){ s += __shfl_xor(s,off); q += __shfl_xor(q,off); }
  if ((t & 63) == 0){ rs[t>>6] = s; rq[t>>6] = q; }
  __syncthreads();
  s = rs[0]+rs[1]; q = rq[0]+rq[1];
  float mu = s*(1.0f/DM), var = q*(1.0f/DM) - mu*mu;
  float r = rsqrtf(var + 1e-5f);
#pragma unroll
  for (int i=0;i<4;i++){ int d = t + i*128; xn[d] = (v[i]-mu)*r*fg[d] + fb[d]; }
  __syncthreads();
  if (t < 96){
    float acc = pb[t] + sb[t];
    const float* xr = x + ((size_t)b*L0 + (L0-1))*7;
#pragma unroll
    for (int c=0;c<7;c++) acc += xr[c]*sw[t*7+c];
    for (int d=0; d<DM; d++) acc += xn[d]*pw[(size_t)t*DM + d];
    out[b*96 + t] = acc;
  }
}

// =======================================================================
extern "C" void kernel_launch(void* const* d_in, const int* in_sizes, int n_in,
                              void* d_out, int out_size, void* d_ws, size_t ws_size,
                              hipStream_t stream){
  const float* x    = (const float*)d_in[0];
  const float* skw  = (const float*)d_in[1];
  const float* skb  = (const float*)d_in[2];
  const float* tcw  = (const float*)d_in[3];
  const float* wq   = (const float*)d_in[4];
  const float* bq   = (const float*)d_in[5];
  const float* wk   = (const float*)d_in[6];
  const float* bk   = (const float*)d_in[7];
  const float* wv   = (const float*)d_in[8];
  const float* bv   = (const float*)d_in[9];
  const float* wo   = (const float*)d_in[10];
  const float* bo   = (const float*)d_in[11];
  const float* w1   = (const float*)d_in[12];
  const float* b1   = (const float*)d_in[13];
  const float* w2   = (const float*)d_in[14];
  const float* b2   = (const float*)d_in[15];
  const float* ln1g = (const float*)d_in[16];
  const float* ln1b = (const float*)d_in[17];
  const float* ln2g = (const float*)d_in[18];
  const float* ln2b = (const float*)d_in[19];
  const float* dcw  = (const float*)d_in[20];
  const float* dcb  = (const float*)d_in[21];
  const float* bng  = (const float*)d_in[22];
  const float* bnb  = (const float*)d_in[23];
  const float* flg  = (const float*)d_in[24];
  const float* flb  = (const float*)d_in[25];
  const float* pw   = (const float*)d_in[26];
  const float* pb   = (const float*)d_in[27];

  const int B = 32, L0 = 2048, DFF = 2048;
  const int RG = 16384;
  const int RF = 8192;
  char* ws = (char*)d_ws;
  const size_t SZH  = (size_t)B*L0*DM*sizeof(float);
  const size_t SLOT = (size_t)RG*DM*sizeof(unsigned short);

  const size_t WBSZ = (size_t)(3*DM*DM + 2*DFF*DM + 3*DM*DM)*2;
  size_t small_bytes = (size_t)L0*40*4
                     + (size_t)RG*8*4
                     + (size_t)B*8*40*4
                     + (size_t)32*8*40*64*4
                     + (size_t)32*8*40*64*4
                     + 3*(size_t)B*DM*4
                     + 2*(size_t)128*DM*4
                     + (size_t)2*DM*4
                     + (size_t)1536*4
                     + (size_t)B*CMC*DM*4
                     + (size_t)L0*DM*4;        // pe table
  if (ws_size < SZH + 4*SLOT + WBSZ + small_bytes) return;

  float*          h   = (float*)(ws);
  unsigned short* P0  = (unsigned short*)(ws + SZH);
  unsigned short* P1  = (unsigned short*)(ws + SZH + SLOT);
  unsigned short* P2  = (unsigned short*)(ws + SZH + 2*SLOT);
  unsigned short* P3  = (unsigned short*)(ws + SZH + 3*SLOT);
  unsigned short* wb  = (unsigned short*)(ws + SZH + 4*SLOT);
  unsigned short* wqb = wb;
  unsigned short* w1b = wqb + (size_t)3*DM*DM;
  unsigned short* w2b = w1b + (size_t)DFF*DM;
  unsigned short* wtapK= w2b + (size_t)DM*DFF;
  char* sm = ws + SZH + 4*SLOT + WBSZ;
  int*   idx_buf  = (int*)sm;
  float* m_buf    = (float*)(sm + (size_t)L0*40*4);
  int*   top_all  = (int*)((char*)m_buf + (size_t)RG*8*4);
  float* qred_loc = (float*)((char*)top_all + (size_t)B*8*40*4);
  float* ctxt_all = qred_loc + (size_t)32*8*40*64;
  float* hm       = ctxt_all + (size_t)32*8*40*64;
  float* vmean    = hm + (size_t)B*DM;
  float* cw       = vmean + (size_t)B*DM;
  float* partS    = cw + (size_t)B*DM;
  float* partQ    = partS + (size_t)128*DM;
  float* stats    = partQ + (size_t)128*DM;
  float* bqkv     = stats + (size_t)2*DM;
  float* partC    = bqkv + (size_t)1536;
  float* pe_buf   = partC + (size_t)B*CMC*DM;

  auto conv_b = [&](const float* src, unsigned short* dst, size_t n){
    f2b_vec<<<(int)((n/4 + 255)/256), 256, 0, stream>>>(src, dst, (int)(n/4));
  };

  pe_kernel<<<(int)(((size_t)L0*DM)/256), 256, 0, stream>>>(pe_buf, L0);
  embed_kernel<<<(int)(((size_t)B*L0*DM)/256), 256, 0, stream>>>(x, tcw, pe_buf, h, L0);

  int L = L0;
  const int SGtab[3] = {4, 8, 16};
  for (int layer = 0; layer < 3; layer++){
    int M = B * L;
    int u = (int)(5.0 * log((double)L + 1.0));   // 38 / 34 / 31
    int G = RG / L;
    int nG = M / RG;
    const float* wv_i = wv + (size_t)layer*DM*DM;  const float* bv_i = bv + (size_t)layer*DM;
    const float* wo_i = wo + (size_t)layer*DM*DM;  const float* bo_i = bo + (size_t)layer*DM;
    const float* b1_i = b1 + (size_t)layer*DFF;
    const float* b2_i = b2 + (size_t)layer*DM;

    conv_b(wq + (size_t)layer*DM*DM, wqb,                    (size_t)DM*DM);
    conv_b(wk + (size_t)layer*DM*DM, wqb + (size_t)DM*DM,    (size_t)DM*DM);
    conv_b(wv_i,                     wqb + (size_t)2*DM*DM,  (size_t)DM*DM);
    conv_b(w1 + (size_t)layer*DFF*DM, w1b, (size_t)DFF*DM);
    conv_b(w2 + (size_t)layer*DM*DFF, w2b, (size_t)DM*DFF);
    catb_kernel<<<6, 256, 0, stream>>>(bq + (size_t)layer*DM, bk + (size_t)layer*DM, bv_i, bqkv);
    if (layer < 2)
      packconv<<<(3*DM*DM + 255)/256, 256, 0, stream>>>(dcw + (size_t)layer*DM*DM*3, wtapK);

    unsigned ka = 0u, kb2 = (unsigned)layer;
    tf2x32(0u, 42u, ka, kb2);
    unsigned a0 = 0u, a1 = 2u;  tf2x32(ka, kb2, a0, a1);
    unsigned c0 = 1u, c1 = 3u;  tf2x32(ka, kb2, c0, c1);
    int S2 = L * u / 2;
    idx_kernel<<<(S2 + 255)/256, 256, 0, stream>>>(idx_buf, a1, c1, S2, L-1);

    hipMemsetAsync(ctxt_all, 0, (size_t)B*8*u*64*sizeof(float), stream);

    int sg = SGtab[layer];
    for (int g = 0; g < nG; g++){
      const float* hg = h + (size_t)g*RG*DM;
      // fused QKV from fp32 h (VGPR-convert staging), XCD-swizzled
      bgemm2<128,1><<<dim3(12, RG/128), 256, 0, stream>>>(hg, wqb, bqkv, P1,
          1536, 512, L, 0, 0, 1, 1, (size_t)RG*DM, 1);
      sample_m2<<<RG/4, 256, 0, stream>>>(P1, P2, idx_buf, m_buf, L, u);
      int* top_g = top_all + (size_t)g*G*8*u;
      topk_kernel<<<G*8, 256, 0, stream>>>(m_buf, top_g, L, u);
      int nqr = G*8*u*DH;
      qred_kernel<<<(nqr + 255)/256, 256, 0, stream>>>(P1, top_g, qred_loc, L, u, nqr);

      float* Sbuf = (float*)P0;
      int nsub = G / sg;
      for (int s = 0; s < nsub; s++){
        const float* qr = qred_loc + (size_t)s*sg*8*u*64;
        const unsigned short* kb_ = P2 + (size_t)s*sg*L*DM;
        const unsigned short* vb_ = P3 + (size_t)s*sg*L*DM;
        float* ct = ctxt_all + (size_t)(g*G + s*sg)*8*u*64;
        qk_scores<<<dim3(L/256, sg*8), 256, 0, stream>>>(qr, kb_, Sbuf, L, u);
        softmax_rows<<<sg*8*u, 256, 0, stream>>>(Sbuf, L);
        pv_kernel<<<dim3(L/PVKT, sg*8), 256, 0, stream>>>(Sbuf, vb_, ct, L, u);
      }
    }

    // vmean = (mean_L h)@wv^T + bv ; cw = vmean@wo^T + bo (exact fp32 identity)
    colmean1<<<dim3(B, CMC), 256, 0, stream>>>(h, partC, L);
    colmean2<<<B*DM/256, 256, 0, stream>>>(partC, hm, L);
    tiny_gemm<<<B, 256, 0, stream>>>(hm, wv_i, bv_i, vmean, DM, DM);
    tiny_gemm<<<B, 256, 0, stream>>>(vmean, wo_i, bo_i, cw, DM, DM);

    scatter_delta<<<B*8*u, 256, 0, stream>>>(ctxt_all, vmean, wo_i, top_all, h, L, u);

    unsigned short* ybuf = P0;
    unsigned short* mid  = P1;
    unsigned short* y2b  = P0 + (size_t)RF*DM;
    const float* l1g = ln1g + (size_t)layer*DM; const float* l1b = ln1b + (size_t)layer*DM;
    const float* l2g = ln2g + (size_t)layer*DM; const float* l2b = ln2b + (size_t)layer*DM;
    for (int r0 = 0; r0 < M; r0 += RF){
      ln_kernel<<<RF, 256, 0, stream>>>(h + (size_t)r0*DM, nullptr, 0, l1g, l1b, ybuf, 1, cw, L, r0);
      bgemm2<128,0><<<dim3(16, RF/128), 256, 0, stream>>>(ybuf, w1b, b1_i, mid,
          2048, 512, L, 0, 1, 1, 0, 0, 1);
      bgemm2<64,0><<<dim3(8, RF/128), 256, 0, stream>>>(mid, w2b, b2_i, y2b,
          512, 2048, L, 0, 0, 1, 0, 0, 1);
      ln_kernel<<<RF, 256, 0, stream>>>(h + (size_t)r0*DM, y2b, 1, l2g, l2b, h + (size_t)r0*DM, 0, cw, L, r0);
    }

    // ---- conv: ONE full-M GEMM from fp32 h, bf16 output in P-slots; single pass ----
    if (layer < 2){
      const float* db = dcb + (size_t)layer*DM;
      unsigned short* convb = P0;     // M x DM bf16 spans up to 4 slots
      bgemm2<64,1><<<dim3(8, M/128), 256, 0, stream>>>(h, wtapK, db, convb,
          512, 1536, L, 1, 0, 1, 0, 0, 1);
      bnstat1<<<dim3(8, 128), 256, 0, stream>>>(convb, partS, partQ, M/128);
      bnstat2<<<2, 256, 0, stream>>>(partS, partQ, stats, 128, M);
      int Lo = L/2;
      bnpool<<<(int)(((size_t)B*Lo*DM)/256), 256, 0, stream>>>(convb, stats,
          bng + (size_t)layer*DM, bnb + (size_t)layer*DM, h, L, Lo);
      L = Lo;
    }
  }

  final_kernel<<<B, 128, 0, stream>>>(h, x, flg, flb, pw, pb, skw, skb, (float*)d_out, L, L0);
}

// Round 9
// 5425.554 us; speedup vs baseline: 8.3266x; 1.0481x over previous
//
#include <hip/hip_runtime.h>
#include <cmath>

#define DM 512
#define DH 64

typedef __attribute__((ext_vector_type(8))) short short8;
typedef __attribute__((ext_vector_type(4))) float float4v;

__device__ inline float b2f(unsigned short u){
  union{unsigned int i; float f;} z; z.i = ((unsigned)u)<<16; return z.f;
}
__device__ inline unsigned short f2b(float f){
  unsigned int x = __float_as_uint(f);
  return (unsigned short)((x + 0x7fffu + ((x>>16)&1u)) >> 16);   // RNE
}

#define GLL(gp, lp) __builtin_amdgcn_global_load_lds((const __attribute__((address_space(1))) void*)(gp), \
    (__attribute__((address_space(3))) void*)(lp), 16, 0, 0)

// ---------------- Threefry-2x32-20 (matches jax.random) ----------------
__host__ __device__ inline void tf2x32(unsigned k0, unsigned k1, unsigned& x0, unsigned& x1){
  const unsigned ks0=k0, ks1=k1, ks2=k0^k1^0x1BD11BDAu;
  x0 += ks0; x1 += ks1;
#define TF_ROT(r) { x0 += x1; x1 = (x1<<(r))|(x1>>(32-(r))); x1 ^= x0; }
  TF_ROT(13) TF_ROT(15) TF_ROT(26) TF_ROT(6)
  x0 += ks1; x1 += ks2 + 1u;
  TF_ROT(17) TF_ROT(29) TF_ROT(16) TF_ROT(24)
  x0 += ks2; x1 += ks0 + 2u;
  TF_ROT(13) TF_ROT(15) TF_ROT(26) TF_ROT(6)
  x0 += ks0; x1 += ks1 + 3u;
  TF_ROT(17) TF_ROT(29) TF_ROT(16) TF_ROT(24)
  x0 += ks1; x1 += ks2 + 4u;
  TF_ROT(13) TF_ROT(15) TF_ROT(26) TF_ROT(6)
  x0 += ks2; x1 += ks0 + 5u;
#undef TF_ROT
}

__global__ __launch_bounds__(256) void idx_kernel(int* __restrict__ idx, unsigned k2a, unsigned k2b,
                                                  int S2, int Lmask){
  int j = blockIdx.x*256 + threadIdx.x;
  if (j >= S2) return;
  unsigned x0 = (unsigned)j, x1 = (unsigned)(S2 + j);
  tf2x32(k2a, k2b, x0, x1);
  idx[j]      = (int)(x0 & (unsigned)Lmask);
  idx[S2 + j] = (int)(x1 & (unsigned)Lmask);
}

// ---------------- positional-embedding table (batch-independent) ----------------
__global__ __launch_bounds__(256) void pe_kernel(float* __restrict__ pe, int L){
  int i = blockIdx.x*256 + threadIdx.x;
  int d = i % DM, l = i / DM;
  const float scale = -0.017988946f;  // -ln(10000)/512
  float freq = expf((float)(d & ~1) * scale);
  float ang  = (float)l * freq;
  pe[i] = (d & 1) ? cosf(ang) : sinf(ang);
}

// ---------------- transpose token-conv weights: tcwT[j][d] = tcw[d][c][kk], j=kk*7+c ----------------
__global__ __launch_bounds__(256) void packtcw(const float* __restrict__ tcw, float* __restrict__ tcwT){
  int i = blockIdx.x*256 + threadIdx.x;
  if (i >= 21*DM) return;
  int j = i / DM, d = i % DM;
  tcwT[(size_t)j*DM + d] = tcw[(size_t)d*21 + (j%7)*3 + (j/7)];
}

// ---------------- token embed: one block per (b,l) row; x staged in LDS ----------------
__global__ __launch_bounds__(256) void embed2(const float* __restrict__ x, const float* __restrict__ tcwT,
                                              const float* __restrict__ pe, float* __restrict__ h, int L){
  int row = blockIdx.x; int l = row % L, b = row / L;
  __shared__ float xs[21];
  int t = threadIdx.x;
  if (t < 21){
    int c = t % 7, kk = t / 7;
    int ls = l + kk - 1; ls = (ls < 0) ? ls + L : (ls >= L ? ls - L : ls);
    xs[t] = x[((size_t)b*L + ls)*7 + c];
  }
  __syncthreads();
  for (int d = t; d < DM; d += 256){
    float acc = 0.f;
#pragma unroll
    for (int j=0;j<21;j++) acc += xs[j]*tcwT[j*DM + d];
    h[(size_t)row*DM + d] = acc + pe[(size_t)l*DM + d];
  }
}

// ---------------- fp32 -> bf16 conversion (weights) ----------------
__global__ __launch_bounds__(256) void f2b_vec(const float* __restrict__ src, unsigned short* __restrict__ dst, int n4){
  int i = blockIdx.x*256 + threadIdx.x;
  if (i >= n4) return;
  float4 v = ((const float4*)src)[i];
  ushort4 o; o.x = f2b(v.x); o.y = f2b(v.y); o.z = f2b(v.z); o.w = f2b(v.w);
  ((ushort4*)dst)[i] = o;
}

// ---------------- pack conv weights along K: wtapK[n][tap*512+c] = dcw[n][c][tap] ----------------
__global__ __launch_bounds__(256) void packconv(const float* __restrict__ dcw, unsigned short* __restrict__ wtapK){
  int i = blockIdx.x*256 + threadIdx.x;
  if (i >= 3*DM*DM) return;
  int n = i / (3*DM); int rem = i % (3*DM); int tap = rem / DM; int c = rem % DM;
  wtapK[(size_t)n*(3*DM) + tap*DM + c] = f2b(dcw[((size_t)n*DM + c)*3 + tap]);
}

// ---------------- concat qkv bias ----------------
__global__ __launch_bounds__(256) void catb_kernel(const float* __restrict__ a, const float* __restrict__ b,
    const float* __restrict__ c, float* __restrict__ o){
  int i = blockIdx.x*256 + threadIdx.x;
  if (i >= 1536) return;
  o[i] = (i < 512) ? a[i] : (i < 1024 ? b[i-512] : c[i-1024]);
}

// =======================================================================
// bgemm2: bf16 MFMA GEMM, 128xTN tile, BK=64, single-buffered staging.
// A32: fp32 A staged via VGPR convert. swz: XCD-aware L2-locality remap.
// convmode: K=1536 = 3 taps with circular row shift. qkv: route 512-col
// groups to consecutive bufstride-spaced buffers. act: tanh-GELU.
// =======================================================================
template<int TN, int A32>
__global__ __launch_bounds__(256) void bgemm2(const void* __restrict__ Ain,
    const unsigned short* __restrict__ Wb, const float* __restrict__ bias, void* __restrict__ C,
    int N, int K, int L, int convmode, int act, int outbf, int qkv, size_t bufstride, int swz){
  constexpr int NJ = TN/32;
  constexpr int BR = TN/32;
  __shared__ unsigned short As[128*64];
  __shared__ unsigned short Bs[TN*64];
  int tid = threadIdx.x;
  int w = tid >> 6, ln = tid & 63;

  int bx = blockIdx.x, by = blockIdx.y;
  if (swz){
    int XT = gridDim.x, YT = gridDim.y;
    int lid = by*XT + bx;
    int xcd = lid & 7, s = lid >> 3;
    int ych = YT >> 3;
    int CHv = ych < 16 ? ych : 16;
    int yloc = s % CHv;
    int t2 = s / CHv;
    int xx = t2 % XT;
    int chunk = t2 / XT;
    by = xcd*ych + chunk*CHv + yloc;
    bx = xx;
  }
  int row0 = by*128, col0 = bx*TN;
  int KA = convmode ? 512 : K;

  long aBase[4], dPrev[4], dNext[4]; int aCol[4];
#pragma unroll
  for (int g=0; g<4; g++){
    int ch = g*256 + tid;
    int r = ch >> 3, c = ch & 7;
    int gc = c ^ (r & 7);
    int gr = row0 + r;
    aCol[g] = gc*8;
    aBase[g] = (long)gr * KA;
    if (convmode){
      int l = gr % L;
      dPrev[g] = (l==0)   ? (long)(L-1)*KA : -(long)KA;
      dNext[g] = (l==L-1) ? -(long)(L-1)*KA : (long)KA;
    } else { dPrev[g]=0; dNext[g]=0; }
  }
  long bBase[BR];
#pragma unroll
  for (int g=0; g<BR; g++){
    int ch = g*256 + tid;
    int r = ch >> 3, c = ch & 7;
    int gc = c ^ (r & 7);
    bBase[g] = (long)(col0 + r)*K + gc*8;
  }
  int raBase[4], rbBase[NJ];
#pragma unroll
  for (int i=0;i<4;i++)  raBase[i] = ((w&1)*64 + i*16 + (ln&15))*8;
#pragma unroll
  for (int j=0;j<NJ;j++) rbBase[j] = ((w>>1)*(TN/2) + j*16 + (ln&15))*8;

  float4v acc[4][NJ] = {};
  int nIter = K/64;
  const unsigned short* A16 = (const unsigned short*)Ain;
  const float* Af = (const float*)Ain;

  for (int it=0; it<nIter; it++){
    int k0 = it*64;
    int kk = convmode ? (k0 & 511) : k0;
    int seg = convmode ? (k0 >> 9) : 1;
    if (A32){
#pragma unroll
      for (int g=0; g<4; g++){
        long d = convmode ? ((seg==0) ? dPrev[g] : (seg==2 ? dNext[g] : 0)) : 0;
        const float* src = Af + aBase[g] + d + kk + aCol[g];
        float4 v0 = *(const float4*)src;
        float4 v1 = *(const float4*)(src+4);
        short8 pk;
        pk[0]=(short)f2b(v0.x); pk[1]=(short)f2b(v0.y); pk[2]=(short)f2b(v0.z); pk[3]=(short)f2b(v0.w);
        pk[4]=(short)f2b(v1.x); pk[5]=(short)f2b(v1.y); pk[6]=(short)f2b(v1.z); pk[7]=(short)f2b(v1.w);
        *(short8*)((char*)As + g*4096 + tid*16) = pk;
      }
    } else {
#pragma unroll
      for (int g=0; g<4; g++){
        long d = convmode ? ((seg==0) ? dPrev[g] : (seg==2 ? dNext[g] : 0)) : 0;
        GLL(A16 + aBase[g] + d + kk + aCol[g], (char*)As + g*4096 + w*1024);
      }
    }
#pragma unroll
    for (int g=0; g<BR; g++)
      GLL(Wb + bBase[g] + k0, (char*)Bs + g*4096 + w*1024);
    __syncthreads();
    const char* ab = (const char*)As;
    const char* bb = (const char*)Bs;
#pragma unroll
    for (int s=0;s<2;s++){
      int xs = (s*4 + (ln>>4)) ^ (ln&7);
      short8 af[4], bf[NJ];
#pragma unroll
      for (int i=0;i<4;i++)  af[i] = *(const short8*)(ab + (raBase[i] + xs)*16);
#pragma unroll
      for (int j=0;j<NJ;j++) bf[j] = *(const short8*)(bb + (rbBase[j] + xs)*16);
#pragma unroll
      for (int i=0;i<4;i++)
#pragma unroll
        for (int j=0;j<NJ;j++)
          acc[i][j] = __builtin_amdgcn_mfma_f32_16x16x32_bf16(af[i], bf[j], acc[i][j], 0, 0, 0);
    }
    __syncthreads();
  }

  float* Cf = (float*)C;
  unsigned short* Cb = (unsigned short*)C;
  int colb0 = col0 + (w>>1)*(TN/2) + (ln & 15);
#pragma unroll
  for (int i=0;i<4;i++){
#pragma unroll
    for (int r=0;r<4;r++){
      int grow = row0 + (w&1)*64 + i*16 + (ln>>4)*4 + r;
#pragma unroll
      for (int j=0;j<NJ;j++){
        int colb = colb0 + j*16;
        float v = acc[i][j][r];
        if (bias) v += bias[colb];
        if (act){
          // tanh-form GELU, NaN-safe: v*(1 - 1/(e^{2z}+1)), z = 0.79788456*(v + 0.044715 v^3)
          float z = 0.7978845608f * v * (1.f + 0.044715f*v*v);
          float e = __expf(2.f*z);
          v = v * (1.f - 1.f/(e + 1.f));
        }
        if (outbf){
          if (qkv){
            int bsel = colb >> 9;
            Cb[(size_t)bsel*bufstride + (size_t)grow*512 + (colb & 511)] = f2b(v);
          } else {
            Cb[(size_t)grow*N + colb] = f2b(v);
          }
        } else {
          Cf[(size_t)grow*N + colb] = v;
        }
      }
    }
  }
}

// ---------------- sample_m2: one wave per (b,l), all 8 heads; 16B/lane loads ----------------
__global__ __launch_bounds__(256) void sample_m2(const unsigned short* __restrict__ q,
    const unsigned short* __restrict__ k, const int* __restrict__ idx, float* __restrict__ m, int L, int u){
  int w = (blockIdx.x*256 + threadIdx.x) >> 6;
  int lane = threadIdx.x & 63;
  int l = w % L; int b = w / L;
  const unsigned short* qrow = q + (size_t)w*DM + lane*8;
  uint4 qq = *(const uint4*)qrow;
  float qv[8];
  qv[0]=b2f((unsigned short)(qq.x&0xffff)); qv[1]=b2f((unsigned short)(qq.x>>16));
  qv[2]=b2f((unsigned short)(qq.y&0xffff)); qv[3]=b2f((unsigned short)(qq.y>>16));
  qv[4]=b2f((unsigned short)(qq.z&0xffff)); qv[5]=b2f((unsigned short)(qq.z>>16));
  qv[6]=b2f((unsigned short)(qq.w&0xffff)); qv[7]=b2f((unsigned short)(qq.w>>16));
  const unsigned short* kb = k + (size_t)b*L*DM + lane*8;
  const int* ip = idx + (size_t)l*u;
  float mx = -1e30f, sum = 0.f;
  for (int s=0; s<u; s++){
    int kp = ip[s];
    uint4 kk = *(const uint4*)(kb + (size_t)kp*DM);
    float p;
    p  = qv[0]*b2f((unsigned short)(kk.x&0xffff)) + qv[1]*b2f((unsigned short)(kk.x>>16));
    p += qv[2]*b2f((unsigned short)(kk.y&0xffff)) + qv[3]*b2f((unsigned short)(kk.y>>16));
    p += qv[4]*b2f((unsigned short)(kk.z&0xffff)) + qv[5]*b2f((unsigned short)(kk.z>>16));
    p += qv[6]*b2f((unsigned short)(kk.w&0xffff)) + qv[7]*b2f((unsigned short)(kk.w>>16));
    p += __shfl_xor(p, 1); p += __shfl_xor(p, 2); p += __shfl_xor(p, 4);
    mx = fmaxf(mx, p); sum += p;
  }
  if ((lane & 7) == 0){
    int hh = lane >> 3;
    m[((size_t)b*8 + hh)*L + l] = mx - sum/(float)u;
  }
}

// ---------------- iterative top-u argmax per (b,h), min-index tie-break ----------------
__global__ __launch_bounds__(256) void topk_kernel(const float* __restrict__ m, int* __restrict__ top, int L, int u){
  int bh = blockIdx.x;
  const float* mm = m + (size_t)bh*L;
  __shared__ float vals[2048];
  __shared__ float rv[256];
  __shared__ int   ri[256];
  for (int i=threadIdx.x; i<L; i+=256) vals[i] = mm[i];
  __syncthreads();
  for (int it=0; it<u; it++){
    float bv = -1e30f; int bi = 0x7fffffff;
    for (int i=threadIdx.x; i<L; i+=256){
      float v = vals[i];
      if (v > bv || (v == bv && i < bi)) { bv = v; bi = i; }
    }
    rv[threadIdx.x] = bv; ri[threadIdx.x] = bi;
    __syncthreads();
    for (int s=128; s; s>>=1){
      if (threadIdx.x < s){
        float v = rv[threadIdx.x+s]; int i2 = ri[threadIdx.x+s];
        if (v > rv[threadIdx.x] || (v == rv[threadIdx.x] && i2 < ri[threadIdx.x])){
          rv[threadIdx.x] = v; ri[threadIdx.x] = i2;
        }
      }
      __syncthreads();
    }
    if (threadIdx.x == 0){ top[bh*u + it] = ri[0]; vals[ri[0]] = -1e31f; }
    __syncthreads();
  }
}

// ---------------- column mean, two-stage ----------------
#define CMC 32
__global__ __launch_bounds__(256) void colmean1(const float* __restrict__ src, float* __restrict__ part, int L){
  int b = blockIdx.x, ch = blockIdx.y;
  int rpb = L / CMC;
  int t = threadIdx.x;
  const float* p = src + ((size_t)b*L + (size_t)ch*rpb)*DM;
  float s0 = 0.f, s1 = 0.f;
  for (int r=0; r<rpb; r++){ s0 += p[(size_t)r*DM + t]; s1 += p[(size_t)r*DM + t + 256]; }
  float* o = part + ((size_t)b*CMC + ch)*DM;
  o[t] = s0; o[t+256] = s1;
}
__global__ __launch_bounds__(256) void colmean2(const float* __restrict__ part, float* __restrict__ dst, int L){
  int i = blockIdx.x*256 + threadIdx.x;
  int d = i % DM, b = i / DM;
  float s = 0.f;
  for (int c=0; c<CMC; c++) s += part[((size_t)b*CMC + c)*DM + d];
  dst[i] = s / (float)L;
}

// ---------------- tiny fp32 GEMM: one block per row ----------------
__global__ __launch_bounds__(256) void tiny_gemm(const float* __restrict__ A, const float* __restrict__ W,
    const float* __restrict__ bias, float* __restrict__ C, int N, int K){
  int row = blockIdx.x;
  const float* ar = A + (size_t)row*K;
  __shared__ float as[DM];
  for (int k=threadIdx.x; k<K; k+=256) as[k] = ar[k];
  __syncthreads();
  for (int n = threadIdx.x; n < N; n += 256){
    float acc = bias ? bias[n] : 0.f;
    const float* wr = W + (size_t)n*K;
    for (int k=0; k<K; k++) acc += as[k]*wr[k];
    C[(size_t)row*N + n] = acc;
  }
}

// ---------------- gather q rows for top queries (bf16 q -> fp32 qred) ----------------
__global__ __launch_bounds__(256) void qred_kernel(const unsigned short* __restrict__ q, const int* __restrict__ top,
    float* __restrict__ qred, int L, int u, int n){
  int i = blockIdx.x*256 + threadIdx.x;
  if (i >= n) return;
  int d = i & 63; int rest = i >> 6; int j = rest % u; int bh = rest / u;
  int hh = bh & 7; int b = bh >> 3;
  int pos = top[bh*u + j];
  qred[i] = b2f(q[((size_t)b*L + pos)*DM + hh*DH + d]);
}

// =======================================================================
// flash_attn: fused QK^T -> online softmax -> PV, key-split partials.
// grid (KS, nbh); block 256. Per block: u queries x (L/KS) keys.
// K tile in LDS with xor-chunk swizzle (conflict-free score reads);
// V tile natural (lane=dim, conflict-free). No S materialization.
// =======================================================================
#define FKT 128
__global__ __launch_bounds__(256) void flash_attn(const float* __restrict__ qred,
    const unsigned short* __restrict__ kbuf, const unsigned short* __restrict__ vbuf,
    float* __restrict__ partM, float* __restrict__ partL, float* __restrict__ partA,
    int L, int u, int KS){
  int ks = blockIdx.x, bh = blockIdx.y; int b = bh >> 3, h = bh & 7;
  int t = threadIdx.x;
  __shared__ float Qs[38*64];              // 9.7 KB
  __shared__ unsigned short Ks[FKT*64];    // 16 KB (xor-swizzled chunks)
  __shared__ unsigned short Vs[FKT*64];    // 16 KB (natural)
  __shared__ float Ss[38*FKT];             // 19.4 KB
  for (int i=t;i<u*64;i+=256) Qs[i] = qred[(size_t)bh*u*64 + i];
  int lane = t & 63, w = t >> 6;
  float rm[10], rl[10], racc[10];
#pragma unroll
  for (int j=0;j<10;j++){ rm[j]=-1e30f; rl[j]=0.f; racc[j]=0.f; }
  int nk = L / KS;
  int kbase = ks*nk;
  int key = t & 127, rh = t >> 7;
  for (int kt = 0; kt < nk; kt += FKT){
    __syncthreads();
    for (int e = t; e < FKT*8; e += 256){   // chunk id: k=e>>3, c=e&7 (16B chunks)
      int k = e >> 3, c = e & 7;
      size_t gidx = ((size_t)(b*L + kbase + kt + k))*DM + h*DH + c*8;
      *(uint4*)((char*)Ks + (size_t)(k*8 + (c ^ (k&7)))*16) = *(const uint4*)(kbuf + gidx);
      *(uint4*)((char*)Vs + (size_t)e*16) = *(const uint4*)(vbuf + gidx);
    }
    __syncthreads();
    // scores: thread (key, rh) computes rows rh, rh+2, ...
    for (int r = rh; r < u; r += 2){
      const float4* q4 = (const float4*)(Qs + r*64);
      float acc = 0.f;
#pragma unroll
      for (int c=0;c<8;c++){
        short8 kk = *(const short8*)((char*)Ks + (size_t)(key*8 + (c ^ (key&7)))*16);
        float4 qa = q4[c*2], qb = q4[c*2+1];
        acc += qa.x*b2f((unsigned short)kk[0]) + qa.y*b2f((unsigned short)kk[1])
             + qa.z*b2f((unsigned short)kk[2]) + qa.w*b2f((unsigned short)kk[3]);
        acc += qb.x*b2f((unsigned short)kk[4]) + qb.y*b2f((unsigned short)kk[5])
             + qb.z*b2f((unsigned short)kk[6]) + qb.w*b2f((unsigned short)kk[7]);
      }
      Ss[r*FKT + key] = acc * 0.125f;
    }
    __syncthreads();
    // online softmax + PV: wave w owns rows w, w+4, ... (lane = output dim)
    int j = 0;
    for (int r = w; r < u; r += 4, j++){
      float s0 = Ss[r*FKT + lane], s1 = Ss[r*FKT + 64 + lane];
      float mx = fmaxf(s0, s1);
#pragma unroll
      for (int off=32; off; off>>=1) mx = fmaxf(mx, __shfl_xor(mx, off));
      float newm = fmaxf(rm[j], mx);
      float scale = expf(rm[j] - newm);
      float p0 = expf(s0 - newm), p1 = expf(s1 - newm);
      float ps = p0 + p1;
#pragma unroll
      for (int off=32; off; off>>=1) ps += __shfl_xor(ps, off);
      rl[j] = rl[j]*scale + ps;
      rm[j] = newm;
      Ss[r*FKT + lane] = p0; Ss[r*FKT + 64 + lane] = p1;
      float a = racc[j]*scale;
      for (int k=0;k<FKT;k+=4){
        float pa = Ss[r*FKT+k], pb = Ss[r*FKT+k+1], pc = Ss[r*FKT+k+2], pd = Ss[r*FKT+k+3];
        a += pa*b2f(Vs[(k+0)*64+lane]) + pb*b2f(Vs[(k+1)*64+lane])
           + pc*b2f(Vs[(k+2)*64+lane]) + pd*b2f(Vs[(k+3)*64+lane]);
      }
      racc[j] = a;
    }
  }
  int j = 0;
  for (int r = w; r < u; r += 4, j++){
    size_t base = ((size_t)bh*KS + ks)*u + r;
    if (lane == 0){ partM[base] = rm[j]; partL[base] = rl[j]; }
    partA[base*64 + lane] = racc[j];
  }
}

// ---------------- merge key-split partials -> ctxt ----------------
__global__ __launch_bounds__(256) void flash_merge(const float* __restrict__ partM, const float* __restrict__ partL,
    const float* __restrict__ partA, float* __restrict__ ctxt, int u, int KS, int n){
  int i = blockIdx.x*256 + threadIdx.x;
  if (i >= n) return;
  int nn = i & 63; int rest = i >> 6; int r = rest % u; int bhl = rest / u;
  size_t base0 = ((size_t)bhl*KS)*u + r;
  float gm = -1e30f;
  for (int s=0;s<KS;s++) gm = fmaxf(gm, partM[base0 + (size_t)s*u]);
  float lt = 0.f, at = 0.f;
  for (int s=0;s<KS;s++){
    float e = expf(partM[base0 + (size_t)s*u] - gm);
    lt += partL[base0 + (size_t)s*u]*e;
    at += partA[(base0 + (size_t)s*u)*64 + nn]*e;
  }
  ctxt[i] = at / lt;
}

// ---------------- sparse correction: h[b,pos] += (ctxt - vmean_slice)@wo_slice^T ----------------
__global__ __launch_bounds__(256) void scatter_delta(const float* __restrict__ ctxt, const float* __restrict__ vmean,
    const float* __restrict__ wo, const int* __restrict__ top, float* __restrict__ h, int L, int u){
  int bid = blockIdx.x;
  int j = bid % u; int bh = bid / u; int hh = bh & 7; int b = bh >> 3;
  int pos = top[bh*u + j];
  __shared__ float delta[DH];
  int t = threadIdx.x;
  if (t < DH) delta[t] = ctxt[(size_t)(bh*u + j)*DH + t] - vmean[b*DM + hh*DH + t];
  __syncthreads();
  float* hrow = h + ((size_t)b*L + pos)*DM;
  const float* wbase = wo + hh*DH;
  for (int n = t; n < DM; n += 256){
    float acc = 0.f;
    const float* wr = wbase + (size_t)n*DM;
#pragma unroll
    for (int dd=0; dd<DH; dd++) acc += delta[dd] * wr[dd];
    atomicAdd(&hrow[n], acc);
  }
}

// ---------------- LayerNorm D=512; optional +cw[b], +Yadd; out fp32/bf16 ----------------
__global__ __launch_bounds__(256) void ln_kernel(const float* __restrict__ X, const void* __restrict__ Yadd,
    int yb, const float* __restrict__ g, const float* __restrict__ bta, void* __restrict__ Out, int ob,
    const float* __restrict__ cwv, int Lrow, int row0g){
  size_t row = blockIdx.x;
  const float* xr = X + row*DM;
  int t = threadIdx.x;
  float v0 = xr[t], v1 = xr[t+256];
  if (cwv){
    int b = (int)((row0g + (int)row) / Lrow);
    v0 += cwv[b*DM + t]; v1 += cwv[b*DM + t+256];
  }
  if (Yadd){
    if (yb){ const unsigned short* yr = (const unsigned short*)Yadd + row*DM; v0 += b2f(yr[t]); v1 += b2f(yr[t+256]); }
    else   { const float* yr = (const float*)Yadd + row*DM; v0 += yr[t]; v1 += yr[t+256]; }
  }
  float s = v0+v1, q = v0*v0+v1*v1;
#pragma unroll
  for (int off=32; off; off>>=1){ s += __shfl_xor(s,off); q += __shfl_xor(q,off); }
  __shared__ float ss[4], qq[4];
  int w = t >> 6;
  if ((t & 63) == 0){ ss[w] = s; qq[w] = q; }
  __syncthreads();
  s = ss[0]+ss[1]+ss[2]+ss[3]; q = qq[0]+qq[1]+qq[2]+qq[3];
  float mu  = s * (1.0f/DM);
  float var = q * (1.0f/DM) - mu*mu;
  float r = rsqrtf(var + 1e-5f);
  float o0 = (v0 - mu)*r*g[t]     + bta[t];
  float o1 = (v1 - mu)*r*g[t+256] + bta[t+256];
  if (ob){
    unsigned short* Ob = (unsigned short*)Out;
    Ob[row*DM + t] = f2b(o0); Ob[row*DM + t+256] = f2b(o1);
  } else {
    float* Of = (float*)Out;
    Of[row*DM + t] = o0; Of[row*DM + t+256] = o1;
  }
}

// ---------------- BN partial sums over bf16 conv output (grid: 8 x 128) ----------------
__global__ __launch_bounds__(256) void bnstat1(const unsigned short* __restrict__ C, float* __restrict__ partS,
                                               float* __restrict__ partQ, int rpb){
  int chb = blockIdx.x;
  int mb  = blockIdx.y;
  int g = threadIdx.x >> 6, c = threadIdx.x & 63;
  int ch = chb*64 + c;
  float s = 0.f, q = 0.f;
  int r0 = mb * rpb;
  for (int r = r0 + g; r < r0 + rpb; r += 4){
    float v = b2f(C[(size_t)r*DM + ch]); s += v; q += v*v;
  }
  __shared__ float ls[4][64], lq[4][64];
  ls[g][c] = s; lq[g][c] = q;
  __syncthreads();
  if (g == 0){
    s = ls[0][c]+ls[1][c]+ls[2][c]+ls[3][c];
    q = lq[0][c]+lq[1][c]+lq[2][c]+lq[3][c];
    partS[(size_t)mb*DM + ch] = s;
    partQ[(size_t)mb*DM + ch] = q;
  }
}
__global__ __launch_bounds__(256) void bnstat2(const float* __restrict__ partS, const float* __restrict__ partQ,
                                               float* __restrict__ stats, int NB, int M){
  int ch = blockIdx.x*256 + threadIdx.x;
  if (ch >= DM) return;
  float s = 0.f, q = 0.f;
  for (int mb=0; mb<NB; mb++){
    s += partS[(size_t)mb*DM + ch];
    q += partQ[(size_t)mb*DM + ch];
  }
  float mu = s / (float)M;
  stats[ch] = mu;
  stats[DM + ch] = q / (float)M - mu*mu;
}

// ---------------- BN + ELU + maxpool(3,2) over full-M bf16 conv output ----------------
__global__ __launch_bounds__(256) void bnpool(const unsigned short* __restrict__ C, const float* __restrict__ stats,
    const float* __restrict__ g, const float* __restrict__ bta, float* __restrict__ Out,
    int L, int Lo){
  size_t i = (size_t)blockIdx.x*256 + threadIdx.x;
  int ch = (int)(i % DM);
  size_t r = i / DM;
  int lo = (int)(r % Lo);
  int b  = (int)(r / Lo);
  float mu = stats[ch];
  float rstd = rsqrtf(stats[DM+ch] + 1e-5f);
  float gg = g[ch], bb = bta[ch];
  float best = -1e30f;
#pragma unroll
  for (int t=-1; t<=1; t++){
    int li = 2*lo + t;
    if (li >= 0 && li < L){
      float v = (b2f(C[((size_t)b*L + li)*DM + ch]) - mu)*rstd*gg + bb;
      v = v > 0.f ? v : expm1f(v);
      best = fmaxf(best, v);
    }
  }
  Out[((size_t)b*Lo + lo)*DM + ch] = best;
}

// ---------------- final: LN(last row) @ proj^T + proj_b + skip ----------------
__global__ __launch_bounds__(128) void final_kernel(const float* __restrict__ h, const float* __restrict__ x,
    const float* __restrict__ fg, const float* __restrict__ fb, const float* __restrict__ pw,
    const float* __restrict__ pb, const float* __restrict__ sw, const float* __restrict__ sb,
    float* __restrict__ out, int Lf, int L0){
  int b = blockIdx.x;
  const float* row = h + ((size_t)b*Lf + (Lf-1))*DM;
  __shared__ float xn[DM];
  __shared__ float rs[2], rq[2];
  int t = threadIdx.x;
  float v[4]; float s = 0.f, q = 0.f;
#pragma unroll
  for (int i=0;i<4;i++){ v[i] = row[t + i*128]; s += v[i]; q += v[i]*v[i]; }
#pragma unroll
  for (int off=32; off; off>>=1){ s += __shfl_xor(s,off); q += __shfl_xor(q,off); }
  if ((t & 63) == 0){ rs[t>>6] = s; rq[t>>6] = q; }
  __syncthreads();
  s = rs[0]+rs[1]; q = rq[0]+rq[1];
  float mu = s*(1.0f/DM), var = q*(1.0f/DM) - mu*mu;
  float r = rsqrtf(var + 1e-5f);
#pragma unroll
  for (int i=0;i<4;i++){ int d = t + i*128; xn[d] = (v[i]-mu)*r*fg[d] + fb[d]; }
  __syncthreads();
  if (t < 96){
    float acc = pb[t] + sb[t];
    const float* xr = x + ((size_t)b*L0 + (L0-1))*7;
#pragma unroll
    for (int c=0;c<7;c++) acc += xr[c]*sw[t*7+c];
    for (int d=0; d<DM; d++) acc += xn[d]*pw[(size_t)t*DM + d];
    out[b*96 + t] = acc;
  }
}

// =======================================================================
extern "C" void kernel_launch(void* const* d_in, const int* in_sizes, int n_in,
                              void* d_out, int out_size, void* d_ws, size_t ws_size,
                              hipStream_t stream){
  const float* x    = (const float*)d_in[0];
  const float* skw  = (const float*)d_in[1];
  const float* skb  = (const float*)d_in[2];
  const float* tcw  = (const float*)d_in[3];
  const float* wq   = (const float*)d_in[4];
  const float* bq   = (const float*)d_in[5];
  const float* wk   = (const float*)d_in[6];
  const float* bk   = (const float*)d_in[7];
  const float* wv   = (const float*)d_in[8];
  const float* bv   = (const float*)d_in[9];
  const float* wo   = (const float*)d_in[10];
  const float* bo   = (const float*)d_in[11];
  const float* w1   = (const float*)d_in[12];
  const float* b1   = (const float*)d_in[13];
  const float* w2   = (const float*)d_in[14];
  const float* b2   = (const float*)d_in[15];
  const float* ln1g = (const float*)d_in[16];
  const float* ln1b = (const float*)d_in[17];
  const float* ln2g = (const float*)d_in[18];
  const float* ln2b = (const float*)d_in[19];
  const float* dcw  = (const float*)d_in[20];
  const float* dcb  = (const float*)d_in[21];
  const float* bng  = (const float*)d_in[22];
  const float* bnb  = (const float*)d_in[23];
  const float* flg  = (const float*)d_in[24];
  const float* flb  = (const float*)d_in[25];
  const float* pw   = (const float*)d_in[26];
  const float* pb   = (const float*)d_in[27];

  const int B = 32, L0 = 2048, DFF = 2048;
  const int RG = 16384;
  const int RF = 8192;
  char* ws = (char*)d_ws;
  const size_t SZH  = (size_t)B*L0*DM*sizeof(float);
  const size_t SLOT = (size_t)RG*DM*sizeof(unsigned short);

  const size_t WBSZ = (size_t)(3*DM*DM + 2*DFF*DM + 3*DM*DM)*2;
  size_t small_bytes = (size_t)L0*40*4
                     + (size_t)RG*8*4
                     + (size_t)B*8*40*4
                     + (size_t)32*8*40*64*4
                     + (size_t)32*8*40*64*4
                     + 3*(size_t)B*DM*4
                     + 2*(size_t)128*DM*4
                     + (size_t)2*DM*4
                     + (size_t)1536*4
                     + (size_t)B*CMC*DM*4
                     + (size_t)L0*DM*4
                     + (size_t)21*DM*4;
  if (ws_size < SZH + 4*SLOT + WBSZ + small_bytes) return;

  float*          h   = (float*)(ws);
  unsigned short* P0  = (unsigned short*)(ws + SZH);
  unsigned short* P1  = (unsigned short*)(ws + SZH + SLOT);
  unsigned short* P2  = (unsigned short*)(ws + SZH + 2*SLOT);
  unsigned short* P3  = (unsigned short*)(ws + SZH + 3*SLOT);
  unsigned short* wb  = (unsigned short*)(ws + SZH + 4*SLOT);
  unsigned short* wqb = wb;
  unsigned short* w1b = wqb + (size_t)3*DM*DM;
  unsigned short* w2b = w1b + (size_t)DFF*DM;
  unsigned short* wtapK= w2b + (size_t)DM*DFF;
  char* sm = ws + SZH + 4*SLOT + WBSZ;
  int*   idx_buf  = (int*)sm;
  float* m_buf    = (float*)(sm + (size_t)L0*40*4);
  int*   top_all  = (int*)((char*)m_buf + (size_t)RG*8*4);
  float* qred_loc = (float*)((char*)top_all + (size_t)B*8*40*4);
  float* ctxt_all = qred_loc + (size_t)32*8*40*64;
  float* hm       = ctxt_all + (size_t)32*8*40*64;
  float* vmean    = hm + (size_t)B*DM;
  float* cw       = vmean + (size_t)B*DM;
  float* partS    = cw + (size_t)B*DM;
  float* partQ    = partS + (size_t)128*DM;
  float* stats    = partQ + (size_t)128*DM;
  float* bqkv     = stats + (size_t)2*DM;
  float* partC    = bqkv + (size_t)1536;
  float* pe_buf   = partC + (size_t)B*CMC*DM;
  float* tcwT     = pe_buf + (size_t)L0*DM;

  // flash partials live in P0 (free during attention)
  float* fpM = (float*)P0;                       // 256*40
  float* fpL = fpM + (size_t)256*40;             // 256*40
  float* fpA = fpL + (size_t)256*40;             // 256*40*64 (~2.6 MB)

  auto conv_b = [&](const float* src, unsigned short* dst, size_t n){
    f2b_vec<<<(int)((n/4 + 255)/256), 256, 0, stream>>>(src, dst, (int)(n/4));
  };

  pe_kernel<<<(int)(((size_t)L0*DM)/256), 256, 0, stream>>>(pe_buf, L0);
  packtcw<<<(21*DM + 255)/256, 256, 0, stream>>>(tcw, tcwT);
  embed2<<<B*L0, 256, 0, stream>>>(x, tcwT, pe_buf, h, L0);

  int L = L0;
  for (int layer = 0; layer < 3; layer++){
    int M = B * L;
    int u = (int)(5.0 * log((double)L + 1.0));   // 38 / 34 / 31
    int G = RG / L;
    int nG = M / RG;
    int KS = L / 512;                            // 4 / 2 / 1 key-splits
    const float* wv_i = wv + (size_t)layer*DM*DM;  const float* bv_i = bv + (size_t)layer*DM;
    const float* wo_i = wo + (size_t)layer*DM*DM;  const float* bo_i = bo + (size_t)layer*DM;
    const float* b1_i = b1 + (size_t)layer*DFF;
    const float* b2_i = b2 + (size_t)layer*DM;

    conv_b(wq + (size_t)layer*DM*DM, wqb,                    (size_t)DM*DM);
    conv_b(wk + (size_t)layer*DM*DM, wqb + (size_t)DM*DM,    (size_t)DM*DM);
    conv_b(wv_i,                     wqb + (size_t)2*DM*DM,  (size_t)DM*DM);
    conv_b(w1 + (size_t)layer*DFF*DM, w1b, (size_t)DFF*DM);
    conv_b(w2 + (size_t)layer*DM*DFF, w2b, (size_t)DM*DFF);
    catb_kernel<<<6, 256, 0, stream>>>(bq + (size_t)layer*DM, bk + (size_t)layer*DM, bv_i, bqkv);
    if (layer < 2)
      packconv<<<(3*DM*DM + 255)/256, 256, 0, stream>>>(dcw + (size_t)layer*DM*DM*3, wtapK);

    unsigned ka = 0u, kb2 = (unsigned)layer;
    tf2x32(0u, 42u, ka, kb2);
    unsigned a0 = 0u, a1 = 2u;  tf2x32(ka, kb2, a0, a1);
    unsigned c0 = 1u, c1 = 3u;  tf2x32(ka, kb2, c0, c1);
    int S2 = L * u / 2;
    idx_kernel<<<(S2 + 255)/256, 256, 0, stream>>>(idx_buf, a1, c1, S2, L-1);

    for (int g = 0; g < nG; g++){
      const float* hg = h + (size_t)g*RG*DM;
      bgemm2<128,1><<<dim3(12, RG/128), 256, 0, stream>>>(hg, wqb, bqkv, P1,
          1536, 512, L, 0, 0, 1, 1, (size_t)RG*DM, 1);
      sample_m2<<<RG/4, 256, 0, stream>>>(P1, P2, idx_buf, m_buf, L, u);
      int* top_g = top_all + (size_t)g*G*8*u;
      topk_kernel<<<G*8, 256, 0, stream>>>(m_buf, top_g, L, u);
      int nqr = G*8*u*DH;
      qred_kernel<<<(nqr + 255)/256, 256, 0, stream>>>(P1, top_g, qred_loc, L, u, nqr);

      flash_attn<<<dim3(KS, G*8), 256, 0, stream>>>(qred_loc, P2, P3, fpM, fpL, fpA, L, u, KS);
      int nmg = G*8*u*64;
      flash_merge<<<(nmg + 255)/256, 256, 0, stream>>>(fpM, fpL, fpA,
          ctxt_all + (size_t)g*G*8*u*64, u, KS, nmg);
    }

    // vmean = (mean_L h)@wv^T + bv ; cw = vmean@wo^T + bo (exact fp32 identity)
    colmean1<<<dim3(B, CMC), 256, 0, stream>>>(h, partC, L);
    colmean2<<<B*DM/256, 256, 0, stream>>>(partC, hm, L);
    tiny_gemm<<<B, 256, 0, stream>>>(hm, wv_i, bv_i, vmean, DM, DM);
    tiny_gemm<<<B, 256, 0, stream>>>(vmean, wo_i, bo_i, cw, DM, DM);

    scatter_delta<<<B*8*u, 256, 0, stream>>>(ctxt_all, vmean, wo_i, top_all, h, L, u);

    unsigned short* ybuf = P0;
    unsigned short* mid  = P1;
    unsigned short* y2b  = P0 + (size_t)RF*DM;
    const float* l1g = ln1g + (size_t)layer*DM; const float* l1b = ln1b + (size_t)layer*DM;
    const float* l2g = ln2g + (size_t)layer*DM; const float* l2b = ln2b + (size_t)layer*DM;
    for (int r0 = 0; r0 < M; r0 += RF){
      ln_kernel<<<RF, 256, 0, stream>>>(h + (size_t)r0*DM, nullptr, 0, l1g, l1b, ybuf, 1, cw, L, r0);
      bgemm2<128,0><<<dim3(16, RF/128), 256, 0, stream>>>(ybuf, w1b, b1_i, mid,
          2048, 512, L, 0, 1, 1, 0, 0, 1);
      bgemm2<64,0><<<dim3(8, RF/128), 256, 0, stream>>>(mid, w2b, b2_i, y2b,
          512, 2048, L, 0, 0, 1, 0, 0, 1);
      ln_kernel<<<RF, 256, 0, stream>>>(h + (size_t)r0*DM, y2b, 1, l2g, l2b, h + (size_t)r0*DM, 0, cw, L, r0);
    }

    if (layer < 2){
      const float* db = dcb + (size_t)layer*DM;
      unsigned short* convb = P0;
      bgemm2<64,1><<<dim3(8, M/128), 256, 0, stream>>>(h, wtapK, db, convb,
          512, 1536, L, 1, 0, 1, 0, 0, 1);
      bnstat1<<<dim3(8, 128), 256, 0, stream>>>(convb, partS, partQ, M/128);
      bnstat2<<<2, 256, 0, stream>>>(partS, partQ, stats, 128, M);
      int Lo = L/2;
      bnpool<<<(int)(((size_t)B*Lo*DM)/256), 256, 0, stream>>>(convb, stats,
          bng + (size_t)layer*DM, bnb + (size_t)layer*DM, h, L, Lo);
      L = Lo;
    }
  }

  final_kernel<<<B, 128, 0, stream>>>(h, x, flg, flb, pw, pb, skw, skb, (float*)d_out, L, L0);
}